// Round 9
// baseline (721.203 us; speedup 1.0000x reference)
//
#include <hip/hip_runtime.h>
#include <cstdint>

#define N_GRAPHS 20000
#define SCAN_CHUNK 2048
#define NBLK 512  // blocks for bucket hist/scatter

// ---------------- prefix scan (exclusive) of in[M] -> out[M+1] ----------------
__global__ __launch_bounds__(256) void scan1(const int* __restrict__ in, int* __restrict__ out,
                                             int* __restrict__ bsum, int M) {
  __shared__ int lds[256];
  int t = threadIdx.x;
  int base = blockIdx.x * SCAN_CHUNK + t * 8;
  int v[8];
  int s = 0;
#pragma unroll
  for (int i = 0; i < 8; ++i) {
    v[i] = (base + i < M) ? in[base + i] : 0;
    s += v[i];
  }
  lds[t] = s;
  __syncthreads();
  for (int off = 1; off < 256; off <<= 1) {
    int x = (t >= off) ? lds[t - off] : 0;
    __syncthreads();
    lds[t] += x;
    __syncthreads();
  }
  if (t == 255) bsum[blockIdx.x] = lds[255];
  int run = (t > 0) ? lds[t - 1] : 0;
#pragma unroll
  for (int i = 0; i < 8; ++i) {
    if (base + i <= M) out[base + i] = run;
    run += v[i];
  }
}

__global__ __launch_bounds__(256) void scan2(int* __restrict__ bsum, int nb) {
  __shared__ int lds[256];
  int t = threadIdx.x;
  lds[t] = (t < nb) ? bsum[t] : 0;
  __syncthreads();
  for (int off = 1; off < 256; off <<= 1) {
    int x = (t >= off) ? lds[t - off] : 0;
    __syncthreads();
    lds[t] += x;
    __syncthreads();
  }
  if (t < nb) bsum[t] = (t > 0) ? lds[t - 1] : 0;  // exclusive
}

__global__ void scan3(int* __restrict__ out, const int* __restrict__ bsum, int Mp1) {
  int i = blockIdx.x * blockDim.x + threadIdx.x;
  if (i < Mp1) out[i] += bsum[i / SCAN_CHUNK];
}

// ---------------- P1: per-block bucket histogram (bucket = dst >> 10) ----------------
__global__ __launch_bounds__(256) void bucket_hist(const int* __restrict__ dst,
                                                   int* __restrict__ bcnt, int E, int nbuck) {
  __shared__ int h[512];
  for (int i = threadIdx.x; i < 512; i += 256) h[i] = 0;
  __syncthreads();
  int per = (E + NBLK - 1) / NBLK;
  int s = blockIdx.x * per;
  int e = min(s + per, E);
  for (int i = s + threadIdx.x; i < e; i += 256) atomicAdd(&h[dst[i] >> 10], 1);
  __syncthreads();
  for (int b = threadIdx.x; b < nbuck; b += 256) bcnt[(long)b * NBLK + blockIdx.x] = h[b];
}

// ---------------- P2: scatter edges into bucket-ordered arrays ----------------
__global__ __launch_bounds__(256) void bucket_scatter(const int* __restrict__ src,
                                                      const int* __restrict__ dst,
                                                      const int* __restrict__ bbase,
                                                      int* __restrict__ sdst,
                                                      int* __restrict__ ssrc, int E, int nbuck) {
  __shared__ int h[512];
  for (int b = threadIdx.x; b < nbuck; b += 256) h[b] = bbase[(long)b * NBLK + blockIdx.x];
  __syncthreads();
  int per = (E + NBLK - 1) / NBLK;
  int s = blockIdx.x * per;
  int e = min(s + per, E);
  for (int i = s + threadIdx.x; i < e; i += 256) {
    int d = dst[i];
    int pos = atomicAdd(&h[d >> 10], 1);
    sdst[pos] = d;
    ssrc[pos] = src[i];
  }
}

// ------- P3a fused: per-bucket node histogram -> rs (bucket base + LDS scan) + isq -------
__global__ __launch_bounds__(256) void node_hist_rs(const int* __restrict__ sdst,
                                                    const int* __restrict__ bbase,
                                                    int* __restrict__ rs, float* __restrict__ isq,
                                                    int E, int nbuck, int N) {
  __shared__ int h[1024];
  __shared__ int ws[256];
  int b = blockIdx.x;
  int n0 = b << 10;
  int nn = min(1024, N - n0);
  int t = threadIdx.x;
  for (int i = t; i < 1024; i += 256) h[i] = 0;
  __syncthreads();
  int s = bbase[(long)b * NBLK];
  int e = (b + 1 < nbuck) ? bbase[(long)(b + 1) * NBLK] : E;
  for (int i = s + t; i < e; i += 256) atomicAdd(&h[sdst[i] - n0], 1);
  __syncthreads();
  int v0 = h[4 * t], v1 = h[4 * t + 1], v2 = h[4 * t + 2], v3 = h[4 * t + 3];
  ws[t] = v0 + v1 + v2 + v3;
  __syncthreads();
  for (int off = 1; off < 256; off <<= 1) {
    int x = (t >= off) ? ws[t - off] : 0;
    __syncthreads();
    ws[t] += x;
    __syncthreads();
  }
  int run = s + ((t > 0) ? ws[t - 1] : 0);
  int i0 = 4 * t;
  if (i0 < nn) { rs[n0 + i0] = run; isq[n0 + i0] = rsqrtf((float)(v0 + 1)); }
  run += v0;
  if (i0 + 1 < nn) { rs[n0 + i0 + 1] = run; isq[n0 + i0 + 1] = rsqrtf((float)(v1 + 1)); }
  run += v1;
  if (i0 + 2 < nn) { rs[n0 + i0 + 2] = run; isq[n0 + i0 + 2] = rsqrtf((float)(v2 + 1)); }
  run += v2;
  if (i0 + 3 < nn) { rs[n0 + i0 + 3] = run; isq[n0 + i0 + 3] = rsqrtf((float)(v3 + 1)); }
  if (b == nbuck - 1 && t == 255) rs[N] = E;
}

// ---------------- P3c: per-bucket CSR write (LDS ranks, contiguous csr region) ----------------
__global__ __launch_bounds__(256) void csr_write(const int* __restrict__ sdst,
                                                 const int* __restrict__ ssrc,
                                                 const int* __restrict__ bbase,
                                                 const int* __restrict__ rs,
                                                 int* __restrict__ csr, int E, int nbuck, int N) {
  __shared__ int h[1024];
  int b = blockIdx.x;
  int n0 = b << 10;
  int nn = min(1024, N - n0);
  for (int i = threadIdx.x; i < nn; i += 256) h[i] = rs[n0 + i];
  __syncthreads();
  int s = bbase[(long)b * NBLK];
  int e = (b + 1 < nbuck) ? bbase[(long)(b + 1) * NBLK] : E;
  for (int i = s + threadIdx.x; i < e; i += 256) {
    int d = sdst[i];
    int pos = atomicAdd(&h[d - n0], 1);
    csr[pos] = ssrc[i];
  }
}

// ---------------- node GEMM + row scale: out[r,:] = (in[r,:] @ W) * isq[r] ----------------
__global__ __launch_bounds__(256) void gemm_n64(const float* __restrict__ in,
                                                const float* __restrict__ W,
                                                const float* __restrict__ isq,
                                                float* __restrict__ out, int N) {
  __shared__ float Wl[64 * 64];
  __shared__ float Rl[64 * 65];
  int tid = threadIdx.x;
#pragma unroll
  for (int v = 0; v < 4; ++v) {
    int u = tid + v * 256;
    *(float4*)&Wl[u * 4] = *(const float4*)&W[u * 4];
  }
  long base_row = (long)blockIdx.x * 64;
#pragma unroll
  for (int v = 0; v < 4; ++v) {
    int u = tid + v * 256;
    int r = u >> 4;
    int k = (u & 15) * 4;
    long row = base_row + r;
    float4 val = make_float4(0.f, 0.f, 0.f, 0.f);
    if (row < N) val = *(const float4*)&in[row * 64 + k];
    *(float4*)&Rl[r * 65 + k] = val;
  }
  __syncthreads();
  int r = tid >> 2;
  int c0 = (tid & 3) * 16;
  float acc[16];
#pragma unroll
  for (int j = 0; j < 16; ++j) acc[j] = 0.f;
#pragma unroll 4
  for (int k = 0; k < 64; ++k) {
    float a = Rl[r * 65 + k];
#pragma unroll
    for (int j = 0; j < 16; ++j) acc[j] += a * Wl[k * 64 + c0 + j];
  }
  long row = base_row + r;
  if (row < N) {
    float sc = isq[row];
#pragma unroll
    for (int v = 0; v < 4; ++v) {
      *(float4*)&out[row * 64 + c0 + v * 4] =
          make_float4(acc[v * 4] * sc, acc[v * 4 + 1] * sc, acc[v * 4 + 2] * sc,
                      acc[v * 4 + 3] * sc);
    }
  }
}

// ------- gather conv: out[d] = relu(isq[d]*(sum_{s in N(d)} hp[s] + hp[d]) + b) -------
__global__ __launch_bounds__(256) void gather_conv(const float* __restrict__ hp,
                                                   const int* __restrict__ csr,
                                                   const int* __restrict__ rs,
                                                   const float* __restrict__ isq,
                                                   const float* __restrict__ bias,
                                                   float* __restrict__ out, int N) {
  int lane = threadIdx.x & 63;
  int sub = lane & 15;   // channel quad within row
  int grp = lane >> 4;   // dst group within wave
  int wid = (blockIdx.x * blockDim.x + threadIdx.x) >> 6;
  float4 bv = *(const float4*)&bias[sub * 4];
  long d0 = (long)wid * 4;
  if (d0 >= N) return;
  int d = (int)d0 + grp;
  bool vd = d < N;
  int dd = vd ? d : N - 1;
  int jj = rs[dd];
  int je = vd ? rs[dd + 1] : jj;
  float4 ac = make_float4(0.f, 0.f, 0.f, 0.f);
  if (vd) ac = *(const float4*)&hp[(long)dd * 64 + sub * 4];
  while (__any(jj < je)) {
    bool a0 = jj < je;
    bool a1 = jj + 1 < je;
    bool a2 = jj + 2 < je;
    bool a3 = jj + 3 < je;
    int s0 = csr[jj];
    int s1 = csr[jj + 1];
    int s2 = csr[jj + 2];
    int s3 = csr[jj + 3];
    float4 v0 = make_float4(0.f, 0.f, 0.f, 0.f);
    float4 v1 = make_float4(0.f, 0.f, 0.f, 0.f);
    float4 v2 = make_float4(0.f, 0.f, 0.f, 0.f);
    float4 v3 = make_float4(0.f, 0.f, 0.f, 0.f);
    if (a0) v0 = *(const float4*)&hp[(long)s0 * 64 + sub * 4];
    if (a1) v1 = *(const float4*)&hp[(long)s1 * 64 + sub * 4];
    if (a2) v2 = *(const float4*)&hp[(long)s2 * 64 + sub * 4];
    if (a3) v3 = *(const float4*)&hp[(long)s3 * 64 + sub * 4];
    ac.x += (v0.x + v1.x) + (v2.x + v3.x);
    ac.y += (v0.y + v1.y) + (v2.y + v3.y);
    ac.z += (v0.z + v1.z) + (v2.z + v3.z);
    ac.w += (v0.w + v1.w) + (v2.w + v3.w);
    jj += 4;
  }
  if (vd) {
    float id = isq[d];
    float4 r;
    r.x = fmaxf(fmaf(ac.x, id, bv.x), 0.f);
    r.y = fmaxf(fmaf(ac.y, id, bv.y), 0.f);
    r.z = fmaxf(fmaf(ac.z, id, bv.z), 0.f);
    r.w = fmaxf(fmaf(ac.w, id, bv.w), 0.f);
    *(float4*)&out[(long)d * 64 + sub * 4] = r;
  }
}

// ------- gather conv2 + pooling: LDS per-block graph partials -> atomics into ge sums -------
__global__ __launch_bounds__(256) void gather_pool(const float* __restrict__ hp,
                                                   const int* __restrict__ csr,
                                                   const int* __restrict__ rs,
                                                   const float* __restrict__ isq,
                                                   const float* __restrict__ bias,
                                                   const int* __restrict__ batch,
                                                   float* __restrict__ ge, int N) {
  __shared__ float acc[16][64];
  __shared__ int bg[16];
  __shared__ int slot_of[16];
  __shared__ int gid[16];
  __shared__ int nslots_s;
  int tid = threadIdx.x;
  for (int i = tid; i < 16 * 64; i += 256) ((float*)acc)[i] = 0.f;
  long nd0 = (long)blockIdx.x * 16;
  if (tid < 16) {
    long d = nd0 + tid;
    bg[tid] = (d < N) ? batch[d] : -1;
  }
  __syncthreads();
  if (tid == 0) {
    int ns = 0;
    int prev = -2;
    for (int i = 0; i < 16; ++i) {
      if (bg[i] < 0) { slot_of[i] = 0; continue; }
      if (bg[i] != prev) { gid[ns] = bg[i]; prev = bg[i]; ns++; }
      slot_of[i] = ns - 1;
    }
    nslots_s = ns;
  }
  __syncthreads();
  int lane = tid & 63;
  int sub = lane & 15;
  int grp = lane >> 4;
  int wv = tid >> 6;
  int li = wv * 4 + grp;  // local node idx 0..15
  int d = (int)nd0 + li;
  bool vd = d < N;
  int dd = vd ? d : N - 1;
  int jj = rs[dd];
  int je = vd ? rs[dd + 1] : jj;
  float4 bv = *(const float4*)&bias[sub * 4];
  float4 ac = make_float4(0.f, 0.f, 0.f, 0.f);
  if (vd) ac = *(const float4*)&hp[(long)dd * 64 + sub * 4];
  while (__any(jj < je)) {
    bool a0 = jj < je;
    bool a1 = jj + 1 < je;
    bool a2 = jj + 2 < je;
    bool a3 = jj + 3 < je;
    int s0 = csr[jj];
    int s1 = csr[jj + 1];
    int s2 = csr[jj + 2];
    int s3 = csr[jj + 3];
    float4 v0 = make_float4(0.f, 0.f, 0.f, 0.f);
    float4 v1 = make_float4(0.f, 0.f, 0.f, 0.f);
    float4 v2 = make_float4(0.f, 0.f, 0.f, 0.f);
    float4 v3 = make_float4(0.f, 0.f, 0.f, 0.f);
    if (a0) v0 = *(const float4*)&hp[(long)s0 * 64 + sub * 4];
    if (a1) v1 = *(const float4*)&hp[(long)s1 * 64 + sub * 4];
    if (a2) v2 = *(const float4*)&hp[(long)s2 * 64 + sub * 4];
    if (a3) v3 = *(const float4*)&hp[(long)s3 * 64 + sub * 4];
    ac.x += (v0.x + v1.x) + (v2.x + v3.x);
    ac.y += (v0.y + v1.y) + (v2.y + v3.y);
    ac.z += (v0.z + v1.z) + (v2.z + v3.z);
    ac.w += (v0.w + v1.w) + (v2.w + v3.w);
    jj += 4;
  }
  if (vd) {
    float id = isq[d];
    float rx = fmaxf(fmaf(ac.x, id, bv.x), 0.f);
    float ry = fmaxf(fmaf(ac.y, id, bv.y), 0.f);
    float rz = fmaxf(fmaf(ac.z, id, bv.z), 0.f);
    float rw = fmaxf(fmaf(ac.w, id, bv.w), 0.f);
    int sl = slot_of[li];
    atomicAdd(&acc[sl][sub * 4 + 0], rx);
    atomicAdd(&acc[sl][sub * 4 + 1], ry);
    atomicAdd(&acc[sl][sub * 4 + 2], rz);
    atomicAdd(&acc[sl][sub * 4 + 3], rw);
  }
  __syncthreads();
  int ns = nslots_s;
  for (int sb = 0; sb < ns; sb += 4) {
    int s = sb + (tid >> 6);
    int c = tid & 63;
    if (s < ns) atomicAdd(&ge[(long)gid[s] * 64 + c], acc[s][c]);
  }
}

// ---------------- graph segment offsets from sorted batch_idx ----------------
__global__ void seg_offsets(const int* __restrict__ batch, int* __restrict__ off, int N, int G) {
  int i = blockIdx.x * blockDim.x + threadIdx.x;
  if (i >= N) return;
  int b = batch[i];
  if (i == 0) {
    for (int g = 0; g <= b; ++g) off[g] = 0;
  } else {
    int pb = batch[i - 1];
    for (int g = pb + 1; g <= b; ++g) off[g] = i;
  }
  if (i == N - 1) {
    for (int g = b + 1; g <= G; ++g) off[g] = N;
  }
}

// ---------------- divide graph sums by counts -> means ----------------
__global__ void ge_div(float* __restrict__ ge, const int* __restrict__ goff, int G) {
  int i = blockIdx.x * blockDim.x + threadIdx.x;
  if (i >= G * 64) return;
  int g = i >> 6;
  float c = (float)(goff[g + 1] - goff[g]);
  ge[i] *= 1.f / fmaxf(c, 1.f);
}

// ---------------- pair MLP ----------------
#define PPB 16
__global__ __launch_bounds__(256) void pair_mlp(const float* __restrict__ ge,
                                                const int* __restrict__ dp,
                                                const float* __restrict__ Wr1,
                                                const float* __restrict__ br1,
                                                const float* __restrict__ Wr2,
                                                const float* __restrict__ br2,
                                                float* __restrict__ out, int P) {
  __shared__ float feat[PPB][128];
  __shared__ int pidx[2][PPB];
  __shared__ float red[4][PPB];
  int tid = threadIdx.x;
  int base = blockIdx.x * PPB;
  if (tid < PPB) {
    int p = base + tid;
    pidx[0][tid] = (p < P) ? dp[p] : 0;
    pidx[1][tid] = (p < P) ? dp[P + p] : 0;
  }
  __syncthreads();
#pragma unroll
  for (int i = 0; i < 8; ++i) {
    int f = tid + i * 256;
    int p = f >> 7;
    int k = f & 127;
    int g = (k < 64) ? pidx[0][p] : pidx[1][p];
    feat[p][k] = ge[(long)g * 64 + (k & 63)];
  }
  __syncthreads();
  int j = tid;
  float w2 = Wr2[j];
  float b1v = br1[j];
  float acc[PPB];
#pragma unroll
  for (int p = 0; p < PPB; ++p) acc[p] = 0.f;
  for (int k4 = 0; k4 < 128; k4 += 4) {
    float w0 = Wr1[(k4 + 0) * 256 + j];
    float w1 = Wr1[(k4 + 1) * 256 + j];
    float wv2 = Wr1[(k4 + 2) * 256 + j];
    float w3 = Wr1[(k4 + 3) * 256 + j];
#pragma unroll
    for (int p = 0; p < PPB; ++p) {
      float4 f = *(const float4*)&feat[p][k4];
      acc[p] = fmaf(f.x, w0, acc[p]);
      acc[p] = fmaf(f.y, w1, acc[p]);
      acc[p] = fmaf(f.z, wv2, acc[p]);
      acc[p] = fmaf(f.w, w3, acc[p]);
    }
  }
  int wv = tid >> 6;
#pragma unroll
  for (int p = 0; p < PPB; ++p) {
    float hid = fmaxf(acc[p] + b1v, 0.f);
    float v = hid * w2;
    for (int o = 32; o > 0; o >>= 1) v += __shfl_down(v, o, 64);
    if ((tid & 63) == 0) red[wv][p] = v;
  }
  __syncthreads();
  if (tid < PPB) {
    int p = base + tid;
    if (p < P) out[p] = red[0][tid] + red[1][tid] + red[2][tid] + red[3][tid] + br2[0];
  }
}

extern "C" void kernel_launch(void* const* d_in, const int* in_sizes, int n_in,
                              void* d_out, int out_size, void* d_ws, size_t ws_size,
                              hipStream_t stream) {
  const float* x = (const float*)d_in[0];
  const int* ei = (const int*)d_in[1];
  const int* batch = (const int*)d_in[2];
  const int* dp = (const int*)d_in[3];
  const float* W1 = (const float*)d_in[4];
  const float* b1 = (const float*)d_in[5];
  const float* W2 = (const float*)d_in[6];
  const float* b2 = (const float*)d_in[7];
  const float* Wr1 = (const float*)d_in[8];
  const float* br1 = (const float*)d_in[9];
  const float* Wr2 = (const float*)d_in[10];
  const float* br2 = (const float*)d_in[11];
  float* out = (float*)d_out;

  int N = in_sizes[0] / 64;
  int E = in_sizes[1] / 2;
  int P = in_sizes[3] / 2;
  int G = N_GRAPHS;
  const int* src = ei;
  const int* dstp = ei + E;

  int nbuck = (N + 1023) >> 10;  // <= 512
  long M = (long)nbuck * NBLK;

  char* ws = (char*)d_ws;
  size_t o = 0;
  auto alloc = [&](size_t bytes) {
    void* p = ws + o;
    o += (bytes + 255) & ~(size_t)255;
    return p;
  };
  float* isq = (float*)alloc((size_t)N * 4);
  int* rs = (int*)alloc((size_t)(N + 1) * 4);
  int* bsum = (int*)alloc(1024 * 4);
  int* goff = (int*)alloc((size_t)(G + 1) * 4);
  int* bcnt = (int*)alloc((size_t)(M + 1) * 4);
  int* sdst = (int*)alloc((size_t)E * 4);
  int* ssrc = (int*)alloc((size_t)E * 4);
  int* csr = (int*)alloc((size_t)(E + 32) * 4);  // pad: gather overruns ≤16 ints
  float* hbuf = (float*)alloc((size_t)N * 64 * 4);
  float* abuf = (float*)alloc((size_t)N * 64 * 4);
  float* ge = (float*)alloc((size_t)G * 64 * 4);

  hipMemsetAsync(ge, 0, (size_t)G * 64 * 4, stream);

  // --- CSR build, atomic-free at global scope ---
  bucket_hist<<<NBLK, 256, 0, stream>>>(dstp, bcnt, E, nbuck);
  int nbA = (int)((M + SCAN_CHUNK - 1) / SCAN_CHUNK);
  scan1<<<nbA, 256, 0, stream>>>(bcnt, bcnt, bsum, (int)M);  // in-place exclusive scan
  scan2<<<1, 256, 0, stream>>>(bsum, nbA);
  scan3<<<(int)((M + 1 + 255) / 256), 256, 0, stream>>>(bcnt, bsum, (int)(M + 1));
  bucket_scatter<<<NBLK, 256, 0, stream>>>(src, dstp, bcnt, sdst, ssrc, E, nbuck);
  node_hist_rs<<<nbuck, 256, 0, stream>>>(sdst, bcnt, rs, isq, E, nbuck, N);
  csr_write<<<nbuck, 256, 0, stream>>>(sdst, ssrc, bcnt, rs, csr, E, nbuck, N);
  seg_offsets<<<(N + 255) / 256, 256, 0, stream>>>(batch, goff, N, G);

  int tiles = (N + 63) / 64;
  int gblocks = (N + 15) / 16;  // 4 waves/block, 4 dst/wave (one per 16-lane group)
  // conv1
  gemm_n64<<<tiles, 256, 0, stream>>>(x, W1, isq, hbuf, N);
  gather_conv<<<gblocks, 256, 0, stream>>>(hbuf, csr, rs, isq, b1, abuf, N);
  // conv2 + pooled sums
  gemm_n64<<<tiles, 256, 0, stream>>>(abuf, W2, isq, hbuf, N);
  gather_pool<<<gblocks, 256, 0, stream>>>(hbuf, csr, rs, isq, b2, batch, ge, N);
  // sums -> means
  ge_div<<<(G * 64 + 255) / 256, 256, 0, stream>>>(ge, goff, G);
  // pair MLP
  pair_mlp<<<(P + PPB - 1) / PPB, 256, 0, stream>>>(ge, dp, Wr1, br1, Wr2, br2, out, P);
}

// Round 10
// 532.168 us; speedup vs baseline: 1.3552x; 1.3552x over previous
//
#include <hip/hip_runtime.h>
#include <cstdint>

#define N_GRAPHS 20000
#define SCAN_CHUNK 2048
#define NBLK 512  // blocks for bucket hist/scatter

typedef _Float16 half_t;
typedef __attribute__((ext_vector_type(4))) _Float16 half4;

// ---------------- prefix scan (exclusive) of in[M] -> out[M+1] ----------------
__global__ __launch_bounds__(256) void scan1(const int* __restrict__ in, int* __restrict__ out,
                                             int* __restrict__ bsum, int M) {
  __shared__ int lds[256];
  int t = threadIdx.x;
  int base = blockIdx.x * SCAN_CHUNK + t * 8;
  int v[8];
  int s = 0;
#pragma unroll
  for (int i = 0; i < 8; ++i) {
    v[i] = (base + i < M) ? in[base + i] : 0;
    s += v[i];
  }
  lds[t] = s;
  __syncthreads();
  for (int off = 1; off < 256; off <<= 1) {
    int x = (t >= off) ? lds[t - off] : 0;
    __syncthreads();
    lds[t] += x;
    __syncthreads();
  }
  if (t == 255) bsum[blockIdx.x] = lds[255];
  int run = (t > 0) ? lds[t - 1] : 0;
#pragma unroll
  for (int i = 0; i < 8; ++i) {
    if (base + i <= M) out[base + i] = run;
    run += v[i];
  }
}

__global__ __launch_bounds__(256) void scan2(int* __restrict__ bsum, int nb) {
  __shared__ int lds[256];
  int t = threadIdx.x;
  lds[t] = (t < nb) ? bsum[t] : 0;
  __syncthreads();
  for (int off = 1; off < 256; off <<= 1) {
    int x = (t >= off) ? lds[t - off] : 0;
    __syncthreads();
    lds[t] += x;
    __syncthreads();
  }
  if (t < nb) bsum[t] = (t > 0) ? lds[t - 1] : 0;  // exclusive
}

__global__ void scan3(int* __restrict__ out, const int* __restrict__ bsum, int Mp1) {
  int i = blockIdx.x * blockDim.x + threadIdx.x;
  if (i < Mp1) out[i] += bsum[i / SCAN_CHUNK];
}

// ---------------- P1: per-block bucket histogram (bucket = dst >> 10) ----------------
__global__ __launch_bounds__(256) void bucket_hist(const int* __restrict__ dst,
                                                   int* __restrict__ bcnt, int E, int nbuck) {
  __shared__ int h[512];
  for (int i = threadIdx.x; i < 512; i += 256) h[i] = 0;
  __syncthreads();
  int per = (E + NBLK - 1) / NBLK;
  int s = blockIdx.x * per;
  int e = min(s + per, E);
  for (int i = s + threadIdx.x; i < e; i += 256) atomicAdd(&h[dst[i] >> 10], 1);
  __syncthreads();
  for (int b = threadIdx.x; b < nbuck; b += 256) bcnt[(long)b * NBLK + blockIdx.x] = h[b];
}

// ---------------- P2: scatter edges into bucket-ordered arrays ----------------
__global__ __launch_bounds__(256) void bucket_scatter(const int* __restrict__ src,
                                                      const int* __restrict__ dst,
                                                      const int* __restrict__ bbase,
                                                      int* __restrict__ sdst,
                                                      int* __restrict__ ssrc, int E, int nbuck) {
  __shared__ int h[512];
  for (int b = threadIdx.x; b < nbuck; b += 256) h[b] = bbase[(long)b * NBLK + blockIdx.x];
  __syncthreads();
  int per = (E + NBLK - 1) / NBLK;
  int s = blockIdx.x * per;
  int e = min(s + per, E);
  for (int i = s + threadIdx.x; i < e; i += 256) {
    int d = dst[i];
    int pos = atomicAdd(&h[d >> 10], 1);
    sdst[pos] = d;
    ssrc[pos] = src[i];
  }
}

// ------- P3a fused: per-bucket node histogram -> rs (bucket base + LDS scan) + isq -------
__global__ __launch_bounds__(256) void node_hist_rs(const int* __restrict__ sdst,
                                                    const int* __restrict__ bbase,
                                                    int* __restrict__ rs, float* __restrict__ isq,
                                                    int E, int nbuck, int N) {
  __shared__ int h[1024];
  __shared__ int ws[256];
  int b = blockIdx.x;
  int n0 = b << 10;
  int nn = min(1024, N - n0);
  int t = threadIdx.x;
  for (int i = t; i < 1024; i += 256) h[i] = 0;
  __syncthreads();
  int s = bbase[(long)b * NBLK];
  int e = (b + 1 < nbuck) ? bbase[(long)(b + 1) * NBLK] : E;
  for (int i = s + t; i < e; i += 256) atomicAdd(&h[sdst[i] - n0], 1);
  __syncthreads();
  int v0 = h[4 * t], v1 = h[4 * t + 1], v2 = h[4 * t + 2], v3 = h[4 * t + 3];
  ws[t] = v0 + v1 + v2 + v3;
  __syncthreads();
  for (int off = 1; off < 256; off <<= 1) {
    int x = (t >= off) ? ws[t - off] : 0;
    __syncthreads();
    ws[t] += x;
    __syncthreads();
  }
  int run = s + ((t > 0) ? ws[t - 1] : 0);
  int i0 = 4 * t;
  if (i0 < nn) { rs[n0 + i0] = run; isq[n0 + i0] = rsqrtf((float)(v0 + 1)); }
  run += v0;
  if (i0 + 1 < nn) { rs[n0 + i0 + 1] = run; isq[n0 + i0 + 1] = rsqrtf((float)(v1 + 1)); }
  run += v1;
  if (i0 + 2 < nn) { rs[n0 + i0 + 2] = run; isq[n0 + i0 + 2] = rsqrtf((float)(v2 + 1)); }
  run += v2;
  if (i0 + 3 < nn) { rs[n0 + i0 + 3] = run; isq[n0 + i0 + 3] = rsqrtf((float)(v3 + 1)); }
  if (b == nbuck - 1 && t == 255) rs[N] = E;
}

// ---------------- P3c: per-bucket CSR write (LDS ranks, contiguous csr region) ----------------
__global__ __launch_bounds__(256) void csr_write(const int* __restrict__ sdst,
                                                 const int* __restrict__ ssrc,
                                                 const int* __restrict__ bbase,
                                                 const int* __restrict__ rs,
                                                 int* __restrict__ csr, int E, int nbuck, int N) {
  __shared__ int h[1024];
  int b = blockIdx.x;
  int n0 = b << 10;
  int nn = min(1024, N - n0);
  for (int i = threadIdx.x; i < nn; i += 256) h[i] = rs[n0 + i];
  __syncthreads();
  int s = bbase[(long)b * NBLK];
  int e = (b + 1 < nbuck) ? bbase[(long)(b + 1) * NBLK] : E;
  for (int i = s + threadIdx.x; i < e; i += 256) {
    int d = sdst[i];
    int pos = atomicAdd(&h[d - n0], 1);
    csr[pos] = ssrc[i];
  }
}

// ------ node GEMM + row scale, fp16 out: out[r,:] = half((in[r,:] @ W) * isq[r]) ------
__global__ __launch_bounds__(256) void gemm_n64(const float* __restrict__ in,
                                                const float* __restrict__ W,
                                                const float* __restrict__ isq,
                                                half_t* __restrict__ out, int N) {
  __shared__ float Wl[64 * 64];
  __shared__ float Rl[64 * 65];
  int tid = threadIdx.x;
#pragma unroll
  for (int v = 0; v < 4; ++v) {
    int u = tid + v * 256;
    *(float4*)&Wl[u * 4] = *(const float4*)&W[u * 4];
  }
  long base_row = (long)blockIdx.x * 64;
#pragma unroll
  for (int v = 0; v < 4; ++v) {
    int u = tid + v * 256;
    int r = u >> 4;
    int k = (u & 15) * 4;
    long row = base_row + r;
    float4 val = make_float4(0.f, 0.f, 0.f, 0.f);
    if (row < N) val = *(const float4*)&in[row * 64 + k];
    *(float4*)&Rl[r * 65 + k] = val;
  }
  __syncthreads();
  int r = tid >> 2;
  int c0 = (tid & 3) * 16;
  float acc[16];
#pragma unroll
  for (int j = 0; j < 16; ++j) acc[j] = 0.f;
#pragma unroll 4
  for (int k = 0; k < 64; ++k) {
    float a = Rl[r * 65 + k];
#pragma unroll
    for (int j = 0; j < 16; ++j) acc[j] += a * Wl[k * 64 + c0 + j];
  }
  long row = base_row + r;
  if (row < N) {
    float sc = isq[row];
#pragma unroll
    for (int v = 0; v < 4; ++v) {
      half4 hv;
      hv[0] = (half_t)(acc[v * 4 + 0] * sc);
      hv[1] = (half_t)(acc[v * 4 + 1] * sc);
      hv[2] = (half_t)(acc[v * 4 + 2] * sc);
      hv[3] = (half_t)(acc[v * 4 + 3] * sc);
      *(half4*)&out[row * 64 + c0 + v * 4] = hv;
    }
  }
}

// ------- gather conv: out[d] = relu(isq[d]*(sum_{s in N(d)} hp[s] + hp[d]) + b) -------
// hp fp16 rows (128B). Wave = 4 lane-groups of 16, 4-edge batching.
__global__ __launch_bounds__(256) void gather_conv(const half_t* __restrict__ hp,
                                                   const int* __restrict__ csr,
                                                   const int* __restrict__ rs,
                                                   const float* __restrict__ isq,
                                                   const float* __restrict__ bias,
                                                   float* __restrict__ out, int N) {
  int lane = threadIdx.x & 63;
  int sub = lane & 15;   // channel quad within row
  int grp = lane >> 4;   // dst group within wave
  int wid = (blockIdx.x * blockDim.x + threadIdx.x) >> 6;
  float4 bv = *(const float4*)&bias[sub * 4];
  long d0 = (long)wid * 4;
  if (d0 >= N) return;
  int d = (int)d0 + grp;
  bool vd = d < N;
  int dd = vd ? d : N - 1;
  int jj = rs[dd];
  int je = vd ? rs[dd + 1] : jj;
  float4 ac = make_float4(0.f, 0.f, 0.f, 0.f);
  if (vd) {
    half4 sv = *(const half4*)&hp[(long)dd * 64 + sub * 4];
    ac.x = (float)sv[0]; ac.y = (float)sv[1]; ac.z = (float)sv[2]; ac.w = (float)sv[3];
  }
  const half4 hz = {(half_t)0, (half_t)0, (half_t)0, (half_t)0};
  while (__any(jj < je)) {
    bool a0 = jj < je;
    bool a1 = jj + 1 < je;
    bool a2 = jj + 2 < je;
    bool a3 = jj + 3 < je;
    int s0 = csr[jj];
    int s1 = csr[jj + 1];
    int s2 = csr[jj + 2];
    int s3 = csr[jj + 3];
    half4 v0 = hz, v1 = hz, v2 = hz, v3 = hz;
    if (a0) v0 = *(const half4*)&hp[(long)s0 * 64 + sub * 4];
    if (a1) v1 = *(const half4*)&hp[(long)s1 * 64 + sub * 4];
    if (a2) v2 = *(const half4*)&hp[(long)s2 * 64 + sub * 4];
    if (a3) v3 = *(const half4*)&hp[(long)s3 * 64 + sub * 4];
    ac.x += ((float)v0[0] + (float)v1[0]) + ((float)v2[0] + (float)v3[0]);
    ac.y += ((float)v0[1] + (float)v1[1]) + ((float)v2[1] + (float)v3[1]);
    ac.z += ((float)v0[2] + (float)v1[2]) + ((float)v2[2] + (float)v3[2]);
    ac.w += ((float)v0[3] + (float)v1[3]) + ((float)v2[3] + (float)v3[3]);
    jj += 4;
  }
  if (vd) {
    float id = isq[d];
    float4 r;
    r.x = fmaxf(fmaf(ac.x, id, bv.x), 0.f);
    r.y = fmaxf(fmaf(ac.y, id, bv.y), 0.f);
    r.z = fmaxf(fmaf(ac.z, id, bv.z), 0.f);
    r.w = fmaxf(fmaf(ac.w, id, bv.w), 0.f);
    *(float4*)&out[(long)d * 64 + sub * 4] = r;
  }
}

// ---------------- graph segment offsets from sorted batch_idx ----------------
__global__ void seg_offsets(const int* __restrict__ batch, int* __restrict__ off, int N, int G) {
  int i = blockIdx.x * blockDim.x + threadIdx.x;
  if (i >= N) return;
  int b = batch[i];
  if (i == 0) {
    for (int g = 0; g <= b; ++g) off[g] = 0;
  } else {
    int pb = batch[i - 1];
    for (int g = pb + 1; g <= b; ++g) off[g] = i;
  }
  if (i == N - 1) {
    for (int g = b + 1; g <= G; ++g) off[g] = N;
  }
}

// ---------------- mean pool: wave per graph, 4 independent partial sums ----------------
__global__ void pool_mean(const float* __restrict__ e2, const int* __restrict__ off,
                          float* __restrict__ ge, int G) {
  int lane = threadIdx.x & 63;
  int wid = (blockIdx.x * blockDim.x + threadIdx.x) >> 6;
  int nw = (gridDim.x * blockDim.x) >> 6;
  for (int g = wid; g < G; g += nw) {
    int s = off[g];
    int e = off[g + 1];
    float s0 = 0.f, s1 = 0.f, s2 = 0.f, s3 = 0.f;
    int n = s;
    for (; n + 3 < e; n += 4) {
      s0 += e2[(long)n * 64 + lane];
      s1 += e2[(long)(n + 1) * 64 + lane];
      s2 += e2[(long)(n + 2) * 64 + lane];
      s3 += e2[(long)(n + 3) * 64 + lane];
    }
    for (; n < e; ++n) s0 += e2[(long)n * 64 + lane];
    float sum = (s0 + s1) + (s2 + s3);
    ge[(long)g * 64 + lane] = sum / fmaxf((float)(e - s), 1.f);
  }
}

// ---------------- pair MLP ----------------
#define PPB 16
__global__ __launch_bounds__(256) void pair_mlp(const float* __restrict__ ge,
                                                const int* __restrict__ dp,
                                                const float* __restrict__ Wr1,
                                                const float* __restrict__ br1,
                                                const float* __restrict__ Wr2,
                                                const float* __restrict__ br2,
                                                float* __restrict__ out, int P) {
  __shared__ float feat[PPB][128];
  __shared__ int pidx[2][PPB];
  __shared__ float red[4][PPB];
  int tid = threadIdx.x;
  int base = blockIdx.x * PPB;
  if (tid < PPB) {
    int p = base + tid;
    pidx[0][tid] = (p < P) ? dp[p] : 0;
    pidx[1][tid] = (p < P) ? dp[P + p] : 0;
  }
  __syncthreads();
#pragma unroll
  for (int i = 0; i < 8; ++i) {
    int f = tid + i * 256;
    int p = f >> 7;
    int k = f & 127;
    int g = (k < 64) ? pidx[0][p] : pidx[1][p];
    feat[p][k] = ge[(long)g * 64 + (k & 63)];
  }
  __syncthreads();
  int j = tid;
  float w2 = Wr2[j];
  float b1v = br1[j];
  float acc[PPB];
#pragma unroll
  for (int p = 0; p < PPB; ++p) acc[p] = 0.f;
  for (int k4 = 0; k4 < 128; k4 += 4) {
    float w0 = Wr1[(k4 + 0) * 256 + j];
    float w1 = Wr1[(k4 + 1) * 256 + j];
    float wv2 = Wr1[(k4 + 2) * 256 + j];
    float w3 = Wr1[(k4 + 3) * 256 + j];
#pragma unroll
    for (int p = 0; p < PPB; ++p) {
      float4 f = *(const float4*)&feat[p][k4];
      acc[p] = fmaf(f.x, w0, acc[p]);
      acc[p] = fmaf(f.y, w1, acc[p]);
      acc[p] = fmaf(f.z, wv2, acc[p]);
      acc[p] = fmaf(f.w, w3, acc[p]);
    }
  }
  int wv = tid >> 6;
#pragma unroll
  for (int p = 0; p < PPB; ++p) {
    float hid = fmaxf(acc[p] + b1v, 0.f);
    float v = hid * w2;
    for (int o = 32; o > 0; o >>= 1) v += __shfl_down(v, o, 64);
    if ((tid & 63) == 0) red[wv][p] = v;
  }
  __syncthreads();
  if (tid < PPB) {
    int p = base + tid;
    if (p < P) out[p] = red[0][tid] + red[1][tid] + red[2][tid] + red[3][tid] + br2[0];
  }
}

extern "C" void kernel_launch(void* const* d_in, const int* in_sizes, int n_in,
                              void* d_out, int out_size, void* d_ws, size_t ws_size,
                              hipStream_t stream) {
  const float* x = (const float*)d_in[0];
  const int* ei = (const int*)d_in[1];
  const int* batch = (const int*)d_in[2];
  const int* dp = (const int*)d_in[3];
  const float* W1 = (const float*)d_in[4];
  const float* b1 = (const float*)d_in[5];
  const float* W2 = (const float*)d_in[6];
  const float* b2 = (const float*)d_in[7];
  const float* Wr1 = (const float*)d_in[8];
  const float* br1 = (const float*)d_in[9];
  const float* Wr2 = (const float*)d_in[10];
  const float* br2 = (const float*)d_in[11];
  float* out = (float*)d_out;

  int N = in_sizes[0] / 64;
  int E = in_sizes[1] / 2;
  int P = in_sizes[3] / 2;
  int G = N_GRAPHS;
  const int* src = ei;
  const int* dstp = ei + E;

  int nbuck = (N + 1023) >> 10;  // <= 512
  long M = (long)nbuck * NBLK;

  char* ws = (char*)d_ws;
  size_t o = 0;
  auto alloc = [&](size_t bytes) {
    void* p = ws + o;
    o += (bytes + 255) & ~(size_t)255;
    return p;
  };
  float* isq = (float*)alloc((size_t)N * 4);
  int* rs = (int*)alloc((size_t)(N + 1) * 4);
  int* bsum = (int*)alloc(1024 * 4);
  int* goff = (int*)alloc((size_t)(G + 1) * 4);
  int* bcnt = (int*)alloc((size_t)(M + 1) * 4);
  int* sdst = (int*)alloc((size_t)E * 4);
  int* ssrc = (int*)alloc((size_t)E * 4);
  int* csr = (int*)alloc((size_t)(E + 32) * 4);  // pad: gather overruns ≤16 ints
  half_t* hbuf = (half_t*)alloc((size_t)N * 64 * 2);
  float* abuf = (float*)alloc((size_t)N * 64 * 4);
  float* ge = (float*)alloc((size_t)G * 64 * 4);

  // --- CSR build, atomic-free at global scope ---
  bucket_hist<<<NBLK, 256, 0, stream>>>(dstp, bcnt, E, nbuck);
  int nbA = (int)((M + SCAN_CHUNK - 1) / SCAN_CHUNK);
  scan1<<<nbA, 256, 0, stream>>>(bcnt, bcnt, bsum, (int)M);  // in-place exclusive scan
  scan2<<<1, 256, 0, stream>>>(bsum, nbA);
  scan3<<<(int)((M + 1 + 255) / 256), 256, 0, stream>>>(bcnt, bsum, (int)(M + 1));
  bucket_scatter<<<NBLK, 256, 0, stream>>>(src, dstp, bcnt, sdst, ssrc, E, nbuck);
  node_hist_rs<<<nbuck, 256, 0, stream>>>(sdst, bcnt, rs, isq, E, nbuck, N);
  csr_write<<<nbuck, 256, 0, stream>>>(sdst, ssrc, bcnt, rs, csr, E, nbuck, N);
  seg_offsets<<<(N + 255) / 256, 256, 0, stream>>>(batch, goff, N, G);

  int tiles = (N + 63) / 64;
  int gblocks = (N + 15) / 16;  // 4 waves/block, 4 dst/wave (one per 16-lane group)
  // conv1
  gemm_n64<<<tiles, 256, 0, stream>>>(x, W1, isq, hbuf, N);
  gather_conv<<<gblocks, 256, 0, stream>>>(hbuf, csr, rs, isq, b1, abuf, N);
  // conv2
  gemm_n64<<<tiles, 256, 0, stream>>>(abuf, W2, isq, hbuf, N);
  gather_conv<<<gblocks, 256, 0, stream>>>(hbuf, csr, rs, isq, b2, abuf, N);
  // pool
  pool_mean<<<2048, 256, 0, stream>>>(abuf, goff, ge, G);
  // pair MLP
  pair_mlp<<<(P + PPB - 1) / PPB, 256, 0, stream>>>(ge, dp, Wr1, br1, Wr2, br2, out, P);
}

// Round 11
// 520.431 us; speedup vs baseline: 1.3858x; 1.0226x over previous
//
#include <hip/hip_runtime.h>
#include <cstdint>

#define N_GRAPHS 20000
#define SCAN_CHUNK 2048
#define NBLK 512  // blocks for bucket hist/scatter

typedef _Float16 half_t;
typedef __attribute__((ext_vector_type(4))) _Float16 half4;

// ---------------- prefix scan (exclusive) of in[M] -> out[M+1] ----------------
__global__ __launch_bounds__(256) void scan1(const int* __restrict__ in, int* __restrict__ out,
                                             int* __restrict__ bsum, int M) {
  __shared__ int lds[256];
  int t = threadIdx.x;
  int base = blockIdx.x * SCAN_CHUNK + t * 8;
  int v[8];
  int s = 0;
#pragma unroll
  for (int i = 0; i < 8; ++i) {
    v[i] = (base + i < M) ? in[base + i] : 0;
    s += v[i];
  }
  lds[t] = s;
  __syncthreads();
  for (int off = 1; off < 256; off <<= 1) {
    int x = (t >= off) ? lds[t - off] : 0;
    __syncthreads();
    lds[t] += x;
    __syncthreads();
  }
  if (t == 255) bsum[blockIdx.x] = lds[255];
  int run = (t > 0) ? lds[t - 1] : 0;
#pragma unroll
  for (int i = 0; i < 8; ++i) {
    if (base + i <= M) out[base + i] = run;
    run += v[i];
  }
}

__global__ __launch_bounds__(256) void scan2(int* __restrict__ bsum, int nb) {
  __shared__ int lds[256];
  int t = threadIdx.x;
  lds[t] = (t < nb) ? bsum[t] : 0;
  __syncthreads();
  for (int off = 1; off < 256; off <<= 1) {
    int x = (t >= off) ? lds[t - off] : 0;
    __syncthreads();
    lds[t] += x;
    __syncthreads();
  }
  if (t < nb) bsum[t] = (t > 0) ? lds[t - 1] : 0;  // exclusive
}

__global__ void scan3(int* __restrict__ out, const int* __restrict__ bsum, int Mp1) {
  int i = blockIdx.x * blockDim.x + threadIdx.x;
  if (i < Mp1) out[i] += bsum[i / SCAN_CHUNK];
}

// ---------------- P1: per-block bucket histogram (bucket = dst >> 10) ----------------
__global__ __launch_bounds__(256) void bucket_hist(const int* __restrict__ dst,
                                                   int* __restrict__ bcnt, int E, int nbuck) {
  __shared__ int h[512];
  for (int i = threadIdx.x; i < 512; i += 256) h[i] = 0;
  __syncthreads();
  int per = (E + NBLK - 1) / NBLK;
  int s = blockIdx.x * per;
  int e = min(s + per, E);
  for (int i = s + threadIdx.x; i < e; i += 256) atomicAdd(&h[dst[i] >> 10], 1);
  __syncthreads();
  for (int b = threadIdx.x; b < nbuck; b += 256) bcnt[(long)b * NBLK + blockIdx.x] = h[b];
}

// ---------------- P2: scatter edges into bucket-ordered arrays ----------------
__global__ __launch_bounds__(256) void bucket_scatter(const int* __restrict__ src,
                                                      const int* __restrict__ dst,
                                                      const int* __restrict__ bbase,
                                                      int* __restrict__ sdst,
                                                      int* __restrict__ ssrc, int E, int nbuck) {
  __shared__ int h[512];
  for (int b = threadIdx.x; b < nbuck; b += 256) h[b] = bbase[(long)b * NBLK + blockIdx.x];
  __syncthreads();
  int per = (E + NBLK - 1) / NBLK;
  int s = blockIdx.x * per;
  int e = min(s + per, E);
  for (int i = s + threadIdx.x; i < e; i += 256) {
    int d = dst[i];
    int pos = atomicAdd(&h[d >> 10], 1);
    sdst[pos] = d;
    ssrc[pos] = src[i];
  }
}

// ------- P3a fused: per-bucket node histogram -> rs (bucket base + LDS scan) + isq -------
__global__ __launch_bounds__(256) void node_hist_rs(const int* __restrict__ sdst,
                                                    const int* __restrict__ bbase,
                                                    int* __restrict__ rs, float* __restrict__ isq,
                                                    int E, int nbuck, int N) {
  __shared__ int h[1024];
  __shared__ int ws[256];
  int b = blockIdx.x;
  int n0 = b << 10;
  int nn = min(1024, N - n0);
  int t = threadIdx.x;
  for (int i = t; i < 1024; i += 256) h[i] = 0;
  __syncthreads();
  int s = bbase[(long)b * NBLK];
  int e = (b + 1 < nbuck) ? bbase[(long)(b + 1) * NBLK] : E;
  for (int i = s + t; i < e; i += 256) atomicAdd(&h[sdst[i] - n0], 1);
  __syncthreads();
  int v0 = h[4 * t], v1 = h[4 * t + 1], v2 = h[4 * t + 2], v3 = h[4 * t + 3];
  ws[t] = v0 + v1 + v2 + v3;
  __syncthreads();
  for (int off = 1; off < 256; off <<= 1) {
    int x = (t >= off) ? ws[t - off] : 0;
    __syncthreads();
    ws[t] += x;
    __syncthreads();
  }
  int run = s + ((t > 0) ? ws[t - 1] : 0);
  int i0 = 4 * t;
  if (i0 < nn) { rs[n0 + i0] = run; isq[n0 + i0] = rsqrtf((float)(v0 + 1)); }
  run += v0;
  if (i0 + 1 < nn) { rs[n0 + i0 + 1] = run; isq[n0 + i0 + 1] = rsqrtf((float)(v1 + 1)); }
  run += v1;
  if (i0 + 2 < nn) { rs[n0 + i0 + 2] = run; isq[n0 + i0 + 2] = rsqrtf((float)(v2 + 1)); }
  run += v2;
  if (i0 + 3 < nn) { rs[n0 + i0 + 3] = run; isq[n0 + i0 + 3] = rsqrtf((float)(v3 + 1)); }
  if (b == nbuck - 1 && t == 255) rs[N] = E;
}

// ---------------- P3c: per-bucket CSR write (LDS ranks, contiguous csr region) ----------------
__global__ __launch_bounds__(256) void csr_write(const int* __restrict__ sdst,
                                                 const int* __restrict__ ssrc,
                                                 const int* __restrict__ bbase,
                                                 const int* __restrict__ rs,
                                                 int* __restrict__ csr, int E, int nbuck, int N) {
  __shared__ int h[1024];
  int b = blockIdx.x;
  int n0 = b << 10;
  int nn = min(1024, N - n0);
  for (int i = threadIdx.x; i < nn; i += 256) h[i] = rs[n0 + i];
  __syncthreads();
  int s = bbase[(long)b * NBLK];
  int e = (b + 1 < nbuck) ? bbase[(long)(b + 1) * NBLK] : E;
  for (int i = s + threadIdx.x; i < e; i += 256) {
    int d = sdst[i];
    int pos = atomicAdd(&h[d - n0], 1);
    csr[pos] = ssrc[i];
  }
}

// ------ node GEMM + row scale, fp16 out: out[r,:] = half((in[r,:] @ W) * isq[r]) ------
// Register-tiled: thread = 4 rows x 4 cols, k-unroll 4, all LDS reads b128.
__global__ __launch_bounds__(256) void gemm_n64(const float* __restrict__ in,
                                                const float* __restrict__ W,
                                                const float* __restrict__ isq,
                                                half_t* __restrict__ out, int N) {
  __shared__ float Wl[64 * 64];   // [k][c]
  __shared__ float Rl[64 * 68];   // [r][k], pad 68: 272B row stride (16B aligned, 2-way max)
  int tid = threadIdx.x;
#pragma unroll
  for (int v = 0; v < 4; ++v) {
    int u = tid + v * 256;
    *(float4*)&Wl[u * 4] = *(const float4*)&W[u * 4];
  }
  long base_row = (long)blockIdx.x * 64;
#pragma unroll
  for (int v = 0; v < 4; ++v) {
    int u = tid + v * 256;
    int r = u >> 4;
    int k = (u & 15) * 4;
    long row = base_row + r;
    float4 val = make_float4(0.f, 0.f, 0.f, 0.f);
    if (row < N) val = *(const float4*)&in[row * 64 + k];
    *(float4*)&Rl[r * 68 + k] = val;
  }
  __syncthreads();
  int cq = tid & 15;   // col quad: cols cq*4..cq*4+3
  int rq = tid >> 4;   // row quad: rows rq*4..rq*4+3
  float acc[4][4];
#pragma unroll
  for (int i = 0; i < 4; ++i)
#pragma unroll
    for (int j = 0; j < 4; ++j) acc[i][j] = 0.f;
#pragma unroll 4
  for (int k4 = 0; k4 < 16; ++k4) {
    float a[4][4], w[4][4];
#pragma unroll
    for (int i = 0; i < 4; ++i)
      *(float4*)&a[i][0] = *(const float4*)&Rl[(rq * 4 + i) * 68 + k4 * 4];
#pragma unroll
    for (int kk = 0; kk < 4; ++kk)
      *(float4*)&w[kk][0] = *(const float4*)&Wl[(k4 * 4 + kk) * 64 + cq * 4];
#pragma unroll
    for (int i = 0; i < 4; ++i)
#pragma unroll
      for (int kk = 0; kk < 4; ++kk)
#pragma unroll
        for (int j = 0; j < 4; ++j) acc[i][j] = fmaf(a[i][kk], w[kk][j], acc[i][j]);
  }
#pragma unroll
  for (int i = 0; i < 4; ++i) {
    long row = base_row + rq * 4 + i;
    if (row < N) {
      float sc = isq[row];
      half4 hv;
      hv[0] = (half_t)(acc[i][0] * sc);
      hv[1] = (half_t)(acc[i][1] * sc);
      hv[2] = (half_t)(acc[i][2] * sc);
      hv[3] = (half_t)(acc[i][3] * sc);
      *(half4*)&out[row * 64 + cq * 4] = hv;
    }
  }
}

// ------- gather conv: out[d] = relu(isq[d]*(sum_{s in N(d)} hp[s] + hp[d]) + b) -------
// hp fp16 rows (128B). Wave = 4 lane-groups of 16, 4-edge batching.
__global__ __launch_bounds__(256) void gather_conv(const half_t* __restrict__ hp,
                                                   const int* __restrict__ csr,
                                                   const int* __restrict__ rs,
                                                   const float* __restrict__ isq,
                                                   const float* __restrict__ bias,
                                                   float* __restrict__ out, int N) {
  int lane = threadIdx.x & 63;
  int sub = lane & 15;   // channel quad within row
  int grp = lane >> 4;   // dst group within wave
  int wid = (blockIdx.x * blockDim.x + threadIdx.x) >> 6;
  float4 bv = *(const float4*)&bias[sub * 4];
  long d0 = (long)wid * 4;
  if (d0 >= N) return;
  int d = (int)d0 + grp;
  bool vd = d < N;
  int dd = vd ? d : N - 1;
  int jj = rs[dd];
  int je = vd ? rs[dd + 1] : jj;
  float4 ac = make_float4(0.f, 0.f, 0.f, 0.f);
  if (vd) {
    half4 sv = *(const half4*)&hp[(long)dd * 64 + sub * 4];
    ac.x = (float)sv[0]; ac.y = (float)sv[1]; ac.z = (float)sv[2]; ac.w = (float)sv[3];
  }
  const half4 hz = {(half_t)0, (half_t)0, (half_t)0, (half_t)0};
  while (__any(jj < je)) {
    bool a0 = jj < je;
    bool a1 = jj + 1 < je;
    bool a2 = jj + 2 < je;
    bool a3 = jj + 3 < je;
    int s0 = csr[jj];
    int s1 = csr[jj + 1];
    int s2 = csr[jj + 2];
    int s3 = csr[jj + 3];
    half4 v0 = hz, v1 = hz, v2 = hz, v3 = hz;
    if (a0) v0 = *(const half4*)&hp[(long)s0 * 64 + sub * 4];
    if (a1) v1 = *(const half4*)&hp[(long)s1 * 64 + sub * 4];
    if (a2) v2 = *(const half4*)&hp[(long)s2 * 64 + sub * 4];
    if (a3) v3 = *(const half4*)&hp[(long)s3 * 64 + sub * 4];
    ac.x += ((float)v0[0] + (float)v1[0]) + ((float)v2[0] + (float)v3[0]);
    ac.y += ((float)v0[1] + (float)v1[1]) + ((float)v2[1] + (float)v3[1]);
    ac.z += ((float)v0[2] + (float)v1[2]) + ((float)v2[2] + (float)v3[2]);
    ac.w += ((float)v0[3] + (float)v1[3]) + ((float)v2[3] + (float)v3[3]);
    jj += 4;
  }
  if (vd) {
    float id = isq[d];
    float4 r;
    r.x = fmaxf(fmaf(ac.x, id, bv.x), 0.f);
    r.y = fmaxf(fmaf(ac.y, id, bv.y), 0.f);
    r.z = fmaxf(fmaf(ac.z, id, bv.z), 0.f);
    r.w = fmaxf(fmaf(ac.w, id, bv.w), 0.f);
    *(float4*)&out[(long)d * 64 + sub * 4] = r;
  }
}

// ---------------- graph segment offsets from sorted batch_idx ----------------
__global__ void seg_offsets(const int* __restrict__ batch, int* __restrict__ off, int N, int G) {
  int i = blockIdx.x * blockDim.x + threadIdx.x;
  if (i >= N) return;
  int b = batch[i];
  if (i == 0) {
    for (int g = 0; g <= b; ++g) off[g] = 0;
  } else {
    int pb = batch[i - 1];
    for (int g = pb + 1; g <= b; ++g) off[g] = i;
  }
  if (i == N - 1) {
    for (int g = b + 1; g <= G; ++g) off[g] = N;
  }
}

// ---------------- mean pool: wave per graph, 4 independent partial sums ----------------
__global__ void pool_mean(const float* __restrict__ e2, const int* __restrict__ off,
                          float* __restrict__ ge, int G) {
  int lane = threadIdx.x & 63;
  int wid = (blockIdx.x * blockDim.x + threadIdx.x) >> 6;
  int nw = (gridDim.x * blockDim.x) >> 6;
  for (int g = wid; g < G; g += nw) {
    int s = off[g];
    int e = off[g + 1];
    float s0 = 0.f, s1 = 0.f, s2 = 0.f, s3 = 0.f;
    int n = s;
    for (; n + 3 < e; n += 4) {
      s0 += e2[(long)n * 64 + lane];
      s1 += e2[(long)(n + 1) * 64 + lane];
      s2 += e2[(long)(n + 2) * 64 + lane];
      s3 += e2[(long)(n + 3) * 64 + lane];
    }
    for (; n < e; ++n) s0 += e2[(long)n * 64 + lane];
    float sum = (s0 + s1) + (s2 + s3);
    ge[(long)g * 64 + lane] = sum / fmaxf((float)(e - s), 1.f);
  }
}

// ---------------- pair MLP ----------------
#define PPB 16
__global__ __launch_bounds__(256) void pair_mlp(const float* __restrict__ ge,
                                                const int* __restrict__ dp,
                                                const float* __restrict__ Wr1,
                                                const float* __restrict__ br1,
                                                const float* __restrict__ Wr2,
                                                const float* __restrict__ br2,
                                                float* __restrict__ out, int P) {
  __shared__ float feat[PPB][128];
  __shared__ int pidx[2][PPB];
  __shared__ float red[4][PPB];
  int tid = threadIdx.x;
  int base = blockIdx.x * PPB;
  if (tid < PPB) {
    int p = base + tid;
    pidx[0][tid] = (p < P) ? dp[p] : 0;
    pidx[1][tid] = (p < P) ? dp[P + p] : 0;
  }
  __syncthreads();
#pragma unroll
  for (int i = 0; i < 8; ++i) {
    int f = tid + i * 256;
    int p = f >> 7;
    int k = f & 127;
    int g = (k < 64) ? pidx[0][p] : pidx[1][p];
    feat[p][k] = ge[(long)g * 64 + (k & 63)];
  }
  __syncthreads();
  int j = tid;
  float w2 = Wr2[j];
  float b1v = br1[j];
  float acc[PPB];
#pragma unroll
  for (int p = 0; p < PPB; ++p) acc[p] = 0.f;
  for (int k4 = 0; k4 < 128; k4 += 4) {
    float w0 = Wr1[(k4 + 0) * 256 + j];
    float w1 = Wr1[(k4 + 1) * 256 + j];
    float wv2 = Wr1[(k4 + 2) * 256 + j];
    float w3 = Wr1[(k4 + 3) * 256 + j];
#pragma unroll
    for (int p = 0; p < PPB; ++p) {
      float4 f = *(const float4*)&feat[p][k4];
      acc[p] = fmaf(f.x, w0, acc[p]);
      acc[p] = fmaf(f.y, w1, acc[p]);
      acc[p] = fmaf(f.z, wv2, acc[p]);
      acc[p] = fmaf(f.w, w3, acc[p]);
    }
  }
  int wv = tid >> 6;
#pragma unroll
  for (int p = 0; p < PPB; ++p) {
    float hid = fmaxf(acc[p] + b1v, 0.f);
    float v = hid * w2;
    for (int o = 32; o > 0; o >>= 1) v += __shfl_down(v, o, 64);
    if ((tid & 63) == 0) red[wv][p] = v;
  }
  __syncthreads();
  if (tid < PPB) {
    int p = base + tid;
    if (p < P) out[p] = red[0][tid] + red[1][tid] + red[2][tid] + red[3][tid] + br2[0];
  }
}

extern "C" void kernel_launch(void* const* d_in, const int* in_sizes, int n_in,
                              void* d_out, int out_size, void* d_ws, size_t ws_size,
                              hipStream_t stream) {
  const float* x = (const float*)d_in[0];
  const int* ei = (const int*)d_in[1];
  const int* batch = (const int*)d_in[2];
  const int* dp = (const int*)d_in[3];
  const float* W1 = (const float*)d_in[4];
  const float* b1 = (const float*)d_in[5];
  const float* W2 = (const float*)d_in[6];
  const float* b2 = (const float*)d_in[7];
  const float* Wr1 = (const float*)d_in[8];
  const float* br1 = (const float*)d_in[9];
  const float* Wr2 = (const float*)d_in[10];
  const float* br2 = (const float*)d_in[11];
  float* out = (float*)d_out;

  int N = in_sizes[0] / 64;
  int E = in_sizes[1] / 2;
  int P = in_sizes[3] / 2;
  int G = N_GRAPHS;
  const int* src = ei;
  const int* dstp = ei + E;

  int nbuck = (N + 1023) >> 10;  // <= 512
  long M = (long)nbuck * NBLK;

  char* ws = (char*)d_ws;
  size_t o = 0;
  auto alloc = [&](size_t bytes) {
    void* p = ws + o;
    o += (bytes + 255) & ~(size_t)255;
    return p;
  };
  float* isq = (float*)alloc((size_t)N * 4);
  int* rs = (int*)alloc((size_t)(N + 1) * 4);
  int* bsum = (int*)alloc(1024 * 4);
  int* goff = (int*)alloc((size_t)(G + 1) * 4);
  int* bcnt = (int*)alloc((size_t)(M + 1) * 4);
  int* sdst = (int*)alloc((size_t)E * 4);
  int* ssrc = (int*)alloc((size_t)E * 4);
  int* csr = (int*)alloc((size_t)(E + 32) * 4);  // pad: gather overruns ≤16 ints
  half_t* hbuf = (half_t*)alloc((size_t)N * 64 * 2);
  float* abuf = (float*)alloc((size_t)N * 64 * 4);
  float* ge = (float*)alloc((size_t)G * 64 * 4);

  // --- CSR build, atomic-free at global scope ---
  bucket_hist<<<NBLK, 256, 0, stream>>>(dstp, bcnt, E, nbuck);
  int nbA = (int)((M + SCAN_CHUNK - 1) / SCAN_CHUNK);
  scan1<<<nbA, 256, 0, stream>>>(bcnt, bcnt, bsum, (int)M);  // in-place exclusive scan
  scan2<<<1, 256, 0, stream>>>(bsum, nbA);
  scan3<<<(int)((M + 1 + 255) / 256), 256, 0, stream>>>(bcnt, bsum, (int)(M + 1));
  bucket_scatter<<<NBLK, 256, 0, stream>>>(src, dstp, bcnt, sdst, ssrc, E, nbuck);
  node_hist_rs<<<nbuck, 256, 0, stream>>>(sdst, bcnt, rs, isq, E, nbuck, N);
  csr_write<<<nbuck, 256, 0, stream>>>(sdst, ssrc, bcnt, rs, csr, E, nbuck, N);
  seg_offsets<<<(N + 255) / 256, 256, 0, stream>>>(batch, goff, N, G);

  int tiles = (N + 63) / 64;
  int gblocks = (N + 15) / 16;  // 4 waves/block, 4 dst/wave (one per 16-lane group)
  // conv1
  gemm_n64<<<tiles, 256, 0, stream>>>(x, W1, isq, hbuf, N);
  gather_conv<<<gblocks, 256, 0, stream>>>(hbuf, csr, rs, isq, b1, abuf, N);
  // conv2
  gemm_n64<<<tiles, 256, 0, stream>>>(abuf, W2, isq, hbuf, N);
  gather_conv<<<gblocks, 256, 0, stream>>>(hbuf, csr, rs, isq, b2, abuf, N);
  // pool
  pool_mean<<<2048, 256, 0, stream>>>(abuf, goff, ge, G);
  // pair MLP
  pair_mlp<<<(P + PPB - 1) / PPB, 256, 0, stream>>>(ge, dp, Wr1, br1, Wr2, br2, out, P);
}

// Round 12
// 502.630 us; speedup vs baseline: 1.4349x; 1.0354x over previous
//
#include <hip/hip_runtime.h>
#include <cstdint>

#define N_GRAPHS 20000
#define SCAN_CHUNK 2048
#define NBLK 512  // blocks for bucket hist/scatter

typedef _Float16 half_t;
typedef __attribute__((ext_vector_type(4))) _Float16 half4;

// ---------------- prefix scan (exclusive) of in[M] -> out[M+1] ----------------
__global__ __launch_bounds__(256) void scan1(const int* __restrict__ in, int* __restrict__ out,
                                             int* __restrict__ bsum, int M) {
  __shared__ int lds[256];
  int t = threadIdx.x;
  int base = blockIdx.x * SCAN_CHUNK + t * 8;
  int v[8];
  int s = 0;
#pragma unroll
  for (int i = 0; i < 8; ++i) {
    v[i] = (base + i < M) ? in[base + i] : 0;
    s += v[i];
  }
  lds[t] = s;
  __syncthreads();
  for (int off = 1; off < 256; off <<= 1) {
    int x = (t >= off) ? lds[t - off] : 0;
    __syncthreads();
    lds[t] += x;
    __syncthreads();
  }
  if (t == 255) bsum[blockIdx.x] = lds[255];
  int run = (t > 0) ? lds[t - 1] : 0;
#pragma unroll
  for (int i = 0; i < 8; ++i) {
    if (base + i <= M) out[base + i] = run;
    run += v[i];
  }
}

__global__ __launch_bounds__(256) void scan2(int* __restrict__ bsum, int nb) {
  __shared__ int lds[256];
  int t = threadIdx.x;
  lds[t] = (t < nb) ? bsum[t] : 0;
  __syncthreads();
  for (int off = 1; off < 256; off <<= 1) {
    int x = (t >= off) ? lds[t - off] : 0;
    __syncthreads();
    lds[t] += x;
    __syncthreads();
  }
  if (t < nb) bsum[t] = (t > 0) ? lds[t - 1] : 0;  // exclusive
}

__global__ void scan3(int* __restrict__ out, const int* __restrict__ bsum, int Mp1) {
  int i = blockIdx.x * blockDim.x + threadIdx.x;
  if (i < Mp1) out[i] += bsum[i / SCAN_CHUNK];
}

// ---------------- P1: per-block bucket histogram (bucket = dst >> 10) ----------------
__global__ __launch_bounds__(256) void bucket_hist(const int* __restrict__ dst,
                                                   int* __restrict__ bcnt, int E, int nbuck) {
  __shared__ int h[512];
  for (int i = threadIdx.x; i < 512; i += 256) h[i] = 0;
  __syncthreads();
  int per = (E + NBLK - 1) / NBLK;
  int s = blockIdx.x * per;
  int e = min(s + per, E);
  for (int i = s + threadIdx.x; i < e; i += 256) atomicAdd(&h[dst[i] >> 10], 1);
  __syncthreads();
  for (int b = threadIdx.x; b < nbuck; b += 256) bcnt[(long)b * NBLK + blockIdx.x] = h[b];
}

// ---------------- P2: scatter edges into bucket-ordered arrays ----------------
__global__ __launch_bounds__(256) void bucket_scatter(const int* __restrict__ src,
                                                      const int* __restrict__ dst,
                                                      const int* __restrict__ bbase,
                                                      int* __restrict__ sdst,
                                                      int* __restrict__ ssrc, int E, int nbuck) {
  __shared__ int h[512];
  for (int b = threadIdx.x; b < nbuck; b += 256) h[b] = bbase[(long)b * NBLK + blockIdx.x];
  __syncthreads();
  int per = (E + NBLK - 1) / NBLK;
  int s = blockIdx.x * per;
  int e = min(s + per, E);
  for (int i = s + threadIdx.x; i < e; i += 256) {
    int d = dst[i];
    int pos = atomicAdd(&h[d >> 10], 1);
    sdst[pos] = d;
    ssrc[pos] = src[i];
  }
}

// ------- P3a fused: per-bucket node histogram -> rs (bucket base + LDS scan) + isq -------
__global__ __launch_bounds__(256) void node_hist_rs(const int* __restrict__ sdst,
                                                    const int* __restrict__ bbase,
                                                    int* __restrict__ rs, float* __restrict__ isq,
                                                    int E, int nbuck, int N) {
  __shared__ int h[1024];
  __shared__ int ws[256];
  int b = blockIdx.x;
  int n0 = b << 10;
  int nn = min(1024, N - n0);
  int t = threadIdx.x;
  for (int i = t; i < 1024; i += 256) h[i] = 0;
  __syncthreads();
  int s = bbase[(long)b * NBLK];
  int e = (b + 1 < nbuck) ? bbase[(long)(b + 1) * NBLK] : E;
  for (int i = s + t; i < e; i += 256) atomicAdd(&h[sdst[i] - n0], 1);
  __syncthreads();
  int v0 = h[4 * t], v1 = h[4 * t + 1], v2 = h[4 * t + 2], v3 = h[4 * t + 3];
  ws[t] = v0 + v1 + v2 + v3;
  __syncthreads();
  for (int off = 1; off < 256; off <<= 1) {
    int x = (t >= off) ? ws[t - off] : 0;
    __syncthreads();
    ws[t] += x;
    __syncthreads();
  }
  int run = s + ((t > 0) ? ws[t - 1] : 0);
  int i0 = 4 * t;
  if (i0 < nn) { rs[n0 + i0] = run; isq[n0 + i0] = rsqrtf((float)(v0 + 1)); }
  run += v0;
  if (i0 + 1 < nn) { rs[n0 + i0 + 1] = run; isq[n0 + i0 + 1] = rsqrtf((float)(v1 + 1)); }
  run += v1;
  if (i0 + 2 < nn) { rs[n0 + i0 + 2] = run; isq[n0 + i0 + 2] = rsqrtf((float)(v2 + 1)); }
  run += v2;
  if (i0 + 3 < nn) { rs[n0 + i0 + 3] = run; isq[n0 + i0 + 3] = rsqrtf((float)(v3 + 1)); }
  if (b == nbuck - 1 && t == 255) rs[N] = E;
}

// ---------------- P3c: per-bucket CSR write (LDS ranks, contiguous csr region) ----------------
__global__ __launch_bounds__(256) void csr_write(const int* __restrict__ sdst,
                                                 const int* __restrict__ ssrc,
                                                 const int* __restrict__ bbase,
                                                 const int* __restrict__ rs,
                                                 int* __restrict__ csr, int E, int nbuck, int N) {
  __shared__ int h[1024];
  int b = blockIdx.x;
  int n0 = b << 10;
  int nn = min(1024, N - n0);
  for (int i = threadIdx.x; i < nn; i += 256) h[i] = rs[n0 + i];
  __syncthreads();
  int s = bbase[(long)b * NBLK];
  int e = (b + 1 < nbuck) ? bbase[(long)(b + 1) * NBLK] : E;
  for (int i = s + threadIdx.x; i < e; i += 256) {
    int d = sdst[i];
    int pos = atomicAdd(&h[d - n0], 1);
    csr[pos] = ssrc[i];
  }
}

// ------ node GEMM + row scale, fp16 out: out[r,:] = half((in[r,:] @ W) * isq[r]) ------
// Register-tiled: thread = 4 rows x 4 cols, k-unroll 4, all LDS reads b128.
__global__ __launch_bounds__(256) void gemm_n64(const float* __restrict__ in,
                                                const float* __restrict__ W,
                                                const float* __restrict__ isq,
                                                half_t* __restrict__ out, int N) {
  __shared__ float Wl[64 * 64];   // [k][c]
  __shared__ float Rl[64 * 68];   // [r][k], pad 68
  int tid = threadIdx.x;
#pragma unroll
  for (int v = 0; v < 4; ++v) {
    int u = tid + v * 256;
    *(float4*)&Wl[u * 4] = *(const float4*)&W[u * 4];
  }
  long base_row = (long)blockIdx.x * 64;
#pragma unroll
  for (int v = 0; v < 4; ++v) {
    int u = tid + v * 256;
    int r = u >> 4;
    int k = (u & 15) * 4;
    long row = base_row + r;
    float4 val = make_float4(0.f, 0.f, 0.f, 0.f);
    if (row < N) val = *(const float4*)&in[row * 64 + k];
    *(float4*)&Rl[r * 68 + k] = val;
  }
  __syncthreads();
  int cq = tid & 15;   // col quad
  int rq = tid >> 4;   // row quad
  float acc[4][4];
#pragma unroll
  for (int i = 0; i < 4; ++i)
#pragma unroll
    for (int j = 0; j < 4; ++j) acc[i][j] = 0.f;
#pragma unroll 4
  for (int k4 = 0; k4 < 16; ++k4) {
    float a[4][4], w[4][4];
#pragma unroll
    for (int i = 0; i < 4; ++i)
      *(float4*)&a[i][0] = *(const float4*)&Rl[(rq * 4 + i) * 68 + k4 * 4];
#pragma unroll
    for (int kk = 0; kk < 4; ++kk)
      *(float4*)&w[kk][0] = *(const float4*)&Wl[(k4 * 4 + kk) * 64 + cq * 4];
#pragma unroll
    for (int i = 0; i < 4; ++i)
#pragma unroll
      for (int kk = 0; kk < 4; ++kk)
#pragma unroll
        for (int j = 0; j < 4; ++j) acc[i][j] = fmaf(a[i][kk], w[kk][j], acc[i][j]);
  }
#pragma unroll
  for (int i = 0; i < 4; ++i) {
    long row = base_row + rq * 4 + i;
    if (row < N) {
      float sc = isq[row];
      half4 hv;
      hv[0] = (half_t)(acc[i][0] * sc);
      hv[1] = (half_t)(acc[i][1] * sc);
      hv[2] = (half_t)(acc[i][2] * sc);
      hv[3] = (half_t)(acc[i][3] * sc);
      *(half4*)&out[row * 64 + cq * 4] = hv;
    }
  }
}

// ------- gather conv1 + fused W2 GEMM epilogue -------
// relu1[d] = relu(isq[d]*(sum hp[s] + hp[d]) + b1)   (f32, in LDS, wave-local)
// out2[d]  = half( (relu1[d] @ W2) * isq[d] )        (fp16, input for conv2 gather)
__global__ __launch_bounds__(256) void gather_conv_w2(const half_t* __restrict__ hp,
                                                      const int* __restrict__ csr,
                                                      const int* __restrict__ rs,
                                                      const float* __restrict__ isq,
                                                      const float* __restrict__ bias,
                                                      const float* __restrict__ W2,
                                                      half_t* __restrict__ out2, int N) {
  __shared__ float W2l[64 * 64];     // [k][c]
  __shared__ float relu_s[16][68];   // per-block 16 nodes' relu vecs (pad 68)
  int tid = threadIdx.x;
#pragma unroll
  for (int v = 0; v < 4; ++v) {
    int u = tid + v * 256;
    *(float4*)&W2l[u * 4] = *(const float4*)&W2[u * 4];
  }
  __syncthreads();  // single barrier; every wave reaches this before any divergence

  int lane = tid & 63;
  int sub = lane & 15;   // channel quad within row
  int grp = lane >> 4;   // dst group within wave
  int li = tid >> 4;     // local node index 0..15
  int wid = (blockIdx.x * blockDim.x + tid) >> 6;
  float4 bv = *(const float4*)&bias[sub * 4];
  long d0 = (long)wid * 4;
  if (d0 >= N) return;
  int d = (int)d0 + grp;
  bool vd = d < N;
  int dd = vd ? d : N - 1;
  int jj = rs[dd];
  int je = vd ? rs[dd + 1] : jj;
  float id = isq[dd];
  float4 ac = make_float4(0.f, 0.f, 0.f, 0.f);
  {
    half4 sv = *(const half4*)&hp[(long)dd * 64 + sub * 4];
    ac.x = (float)sv[0]; ac.y = (float)sv[1]; ac.z = (float)sv[2]; ac.w = (float)sv[3];
  }
  const half4 hz = {(half_t)0, (half_t)0, (half_t)0, (half_t)0};
  while (__any(jj < je)) {
    bool a0 = jj < je;
    bool a1 = jj + 1 < je;
    bool a2 = jj + 2 < je;
    bool a3 = jj + 3 < je;
    int s0 = csr[jj];
    int s1 = csr[jj + 1];
    int s2 = csr[jj + 2];
    int s3 = csr[jj + 3];
    half4 v0 = hz, v1 = hz, v2 = hz, v3 = hz;
    if (a0) v0 = *(const half4*)&hp[(long)s0 * 64 + sub * 4];
    if (a1) v1 = *(const half4*)&hp[(long)s1 * 64 + sub * 4];
    if (a2) v2 = *(const half4*)&hp[(long)s2 * 64 + sub * 4];
    if (a3) v3 = *(const half4*)&hp[(long)s3 * 64 + sub * 4];
    ac.x += ((float)v0[0] + (float)v1[0]) + ((float)v2[0] + (float)v3[0]);
    ac.y += ((float)v0[1] + (float)v1[1]) + ((float)v2[1] + (float)v3[1]);
    ac.z += ((float)v0[2] + (float)v1[2]) + ((float)v2[2] + (float)v3[2]);
    ac.w += ((float)v0[3] + (float)v1[3]) + ((float)v2[3] + (float)v3[3]);
    jj += 4;
  }
  // relu1 (f32) -> wave-local LDS exchange (same wave writes & reads; no barrier)
  float4 r;
  r.x = fmaxf(fmaf(ac.x, id, bv.x), 0.f);
  r.y = fmaxf(fmaf(ac.y, id, bv.y), 0.f);
  r.z = fmaxf(fmaf(ac.z, id, bv.z), 0.f);
  r.w = fmaxf(fmaf(ac.w, id, bv.w), 0.f);
  *(float4*)&relu_s[li][sub * 4] = r;
  // W2 multiply: each lane computes its 4 output channels for its group's node
  float a2v[4] = {0.f, 0.f, 0.f, 0.f};
#pragma unroll
  for (int k4 = 0; k4 < 16; ++k4) {
    float4 rv = *(const float4*)&relu_s[li][k4 * 4];
#pragma unroll
    for (int kk = 0; kk < 4; ++kk) {
      float4 w = *(const float4*)&W2l[(k4 * 4 + kk) * 64 + sub * 4];
      float a = (&rv.x)[kk];
      a2v[0] = fmaf(a, w.x, a2v[0]);
      a2v[1] = fmaf(a, w.y, a2v[1]);
      a2v[2] = fmaf(a, w.z, a2v[2]);
      a2v[3] = fmaf(a, w.w, a2v[3]);
    }
  }
  if (vd) {
    half4 hv;
    hv[0] = (half_t)(a2v[0] * id);
    hv[1] = (half_t)(a2v[1] * id);
    hv[2] = (half_t)(a2v[2] * id);
    hv[3] = (half_t)(a2v[3] * id);
    *(half4*)&out2[(long)d * 64 + sub * 4] = hv;
  }
}

// ------- gather conv2: out[d] = relu(isq[d]*(sum hp2[s] + hp2[d]) + b2)  (f32 out) -------
__global__ __launch_bounds__(256) void gather_conv(const half_t* __restrict__ hp,
                                                   const int* __restrict__ csr,
                                                   const int* __restrict__ rs,
                                                   const float* __restrict__ isq,
                                                   const float* __restrict__ bias,
                                                   float* __restrict__ out, int N) {
  int lane = threadIdx.x & 63;
  int sub = lane & 15;
  int grp = lane >> 4;
  int wid = (blockIdx.x * blockDim.x + threadIdx.x) >> 6;
  float4 bv = *(const float4*)&bias[sub * 4];
  long d0 = (long)wid * 4;
  if (d0 >= N) return;
  int d = (int)d0 + grp;
  bool vd = d < N;
  int dd = vd ? d : N - 1;
  int jj = rs[dd];
  int je = vd ? rs[dd + 1] : jj;
  float4 ac = make_float4(0.f, 0.f, 0.f, 0.f);
  if (vd) {
    half4 sv = *(const half4*)&hp[(long)dd * 64 + sub * 4];
    ac.x = (float)sv[0]; ac.y = (float)sv[1]; ac.z = (float)sv[2]; ac.w = (float)sv[3];
  }
  const half4 hz = {(half_t)0, (half_t)0, (half_t)0, (half_t)0};
  while (__any(jj < je)) {
    bool a0 = jj < je;
    bool a1 = jj + 1 < je;
    bool a2 = jj + 2 < je;
    bool a3 = jj + 3 < je;
    int s0 = csr[jj];
    int s1 = csr[jj + 1];
    int s2 = csr[jj + 2];
    int s3 = csr[jj + 3];
    half4 v0 = hz, v1 = hz, v2 = hz, v3 = hz;
    if (a0) v0 = *(const half4*)&hp[(long)s0 * 64 + sub * 4];
    if (a1) v1 = *(const half4*)&hp[(long)s1 * 64 + sub * 4];
    if (a2) v2 = *(const half4*)&hp[(long)s2 * 64 + sub * 4];
    if (a3) v3 = *(const half4*)&hp[(long)s3 * 64 + sub * 4];
    ac.x += ((float)v0[0] + (float)v1[0]) + ((float)v2[0] + (float)v3[0]);
    ac.y += ((float)v0[1] + (float)v1[1]) + ((float)v2[1] + (float)v3[1]);
    ac.z += ((float)v0[2] + (float)v1[2]) + ((float)v2[2] + (float)v3[2]);
    ac.w += ((float)v0[3] + (float)v1[3]) + ((float)v2[3] + (float)v3[3]);
    jj += 4;
  }
  if (vd) {
    float id = isq[d];
    float4 r;
    r.x = fmaxf(fmaf(ac.x, id, bv.x), 0.f);
    r.y = fmaxf(fmaf(ac.y, id, bv.y), 0.f);
    r.z = fmaxf(fmaf(ac.z, id, bv.z), 0.f);
    r.w = fmaxf(fmaf(ac.w, id, bv.w), 0.f);
    *(float4*)&out[(long)d * 64 + sub * 4] = r;
  }
}

// ---------------- graph segment offsets from sorted batch_idx ----------------
__global__ void seg_offsets(const int* __restrict__ batch, int* __restrict__ off, int N, int G) {
  int i = blockIdx.x * blockDim.x + threadIdx.x;
  if (i >= N) return;
  int b = batch[i];
  if (i == 0) {
    for (int g = 0; g <= b; ++g) off[g] = 0;
  } else {
    int pb = batch[i - 1];
    for (int g = pb + 1; g <= b; ++g) off[g] = i;
  }
  if (i == N - 1) {
    for (int g = b + 1; g <= G; ++g) off[g] = N;
  }
}

// ---------------- mean pool: wave per graph, 4 independent partial sums ----------------
__global__ void pool_mean(const float* __restrict__ e2, const int* __restrict__ off,
                          float* __restrict__ ge, int G) {
  int lane = threadIdx.x & 63;
  int wid = (blockIdx.x * blockDim.x + threadIdx.x) >> 6;
  int nw = (gridDim.x * blockDim.x) >> 6;
  for (int g = wid; g < G; g += nw) {
    int s = off[g];
    int e = off[g + 1];
    float s0 = 0.f, s1 = 0.f, s2 = 0.f, s3 = 0.f;
    int n = s;
    for (; n + 3 < e; n += 4) {
      s0 += e2[(long)n * 64 + lane];
      s1 += e2[(long)(n + 1) * 64 + lane];
      s2 += e2[(long)(n + 2) * 64 + lane];
      s3 += e2[(long)(n + 3) * 64 + lane];
    }
    for (; n < e; ++n) s0 += e2[(long)n * 64 + lane];
    float sum = (s0 + s1) + (s2 + s3);
    ge[(long)g * 64 + lane] = sum / fmaxf((float)(e - s), 1.f);
  }
}

// ---------------- pair MLP ----------------
#define PPB 16
__global__ __launch_bounds__(256) void pair_mlp(const float* __restrict__ ge,
                                                const int* __restrict__ dp,
                                                const float* __restrict__ Wr1,
                                                const float* __restrict__ br1,
                                                const float* __restrict__ Wr2,
                                                const float* __restrict__ br2,
                                                float* __restrict__ out, int P) {
  __shared__ float feat[PPB][128];
  __shared__ int pidx[2][PPB];
  __shared__ float red[4][PPB];
  int tid = threadIdx.x;
  int base = blockIdx.x * PPB;
  if (tid < PPB) {
    int p = base + tid;
    pidx[0][tid] = (p < P) ? dp[p] : 0;
    pidx[1][tid] = (p < P) ? dp[P + p] : 0;
  }
  __syncthreads();
#pragma unroll
  for (int i = 0; i < 8; ++i) {
    int f = tid + i * 256;
    int p = f >> 7;
    int k = f & 127;
    int g = (k < 64) ? pidx[0][p] : pidx[1][p];
    feat[p][k] = ge[(long)g * 64 + (k & 63)];
  }
  __syncthreads();
  int j = tid;
  float w2 = Wr2[j];
  float b1v = br1[j];
  float acc[PPB];
#pragma unroll
  for (int p = 0; p < PPB; ++p) acc[p] = 0.f;
  for (int k4 = 0; k4 < 128; k4 += 4) {
    float w0 = Wr1[(k4 + 0) * 256 + j];
    float w1 = Wr1[(k4 + 1) * 256 + j];
    float wv2 = Wr1[(k4 + 2) * 256 + j];
    float w3 = Wr1[(k4 + 3) * 256 + j];
#pragma unroll
    for (int p = 0; p < PPB; ++p) {
      float4 f = *(const float4*)&feat[p][k4];
      acc[p] = fmaf(f.x, w0, acc[p]);
      acc[p] = fmaf(f.y, w1, acc[p]);
      acc[p] = fmaf(f.z, wv2, acc[p]);
      acc[p] = fmaf(f.w, w3, acc[p]);
    }
  }
  int wv = tid >> 6;
#pragma unroll
  for (int p = 0; p < PPB; ++p) {
    float hid = fmaxf(acc[p] + b1v, 0.f);
    float v = hid * w2;
    for (int o = 32; o > 0; o >>= 1) v += __shfl_down(v, o, 64);
    if ((tid & 63) == 0) red[wv][p] = v;
  }
  __syncthreads();
  if (tid < PPB) {
    int p = base + tid;
    if (p < P) out[p] = red[0][tid] + red[1][tid] + red[2][tid] + red[3][tid] + br2[0];
  }
}

extern "C" void kernel_launch(void* const* d_in, const int* in_sizes, int n_in,
                              void* d_out, int out_size, void* d_ws, size_t ws_size,
                              hipStream_t stream) {
  const float* x = (const float*)d_in[0];
  const int* ei = (const int*)d_in[1];
  const int* batch = (const int*)d_in[2];
  const int* dp = (const int*)d_in[3];
  const float* W1 = (const float*)d_in[4];
  const float* b1 = (const float*)d_in[5];
  const float* W2 = (const float*)d_in[6];
  const float* b2 = (const float*)d_in[7];
  const float* Wr1 = (const float*)d_in[8];
  const float* br1 = (const float*)d_in[9];
  const float* Wr2 = (const float*)d_in[10];
  const float* br2 = (const float*)d_in[11];
  float* out = (float*)d_out;

  int N = in_sizes[0] / 64;
  int E = in_sizes[1] / 2;
  int P = in_sizes[3] / 2;
  int G = N_GRAPHS;
  const int* src = ei;
  const int* dstp = ei + E;

  int nbuck = (N + 1023) >> 10;  // <= 512
  long M = (long)nbuck * NBLK;

  char* ws = (char*)d_ws;
  size_t o = 0;
  auto alloc = [&](size_t bytes) {
    void* p = ws + o;
    o += (bytes + 255) & ~(size_t)255;
    return p;
  };
  float* isq = (float*)alloc((size_t)N * 4);
  int* rs = (int*)alloc((size_t)(N + 1) * 4);
  int* bsum = (int*)alloc(1024 * 4);
  int* goff = (int*)alloc((size_t)(G + 1) * 4);
  int* bcnt = (int*)alloc((size_t)(M + 1) * 4);
  int* sdst = (int*)alloc((size_t)E * 4);
  int* ssrc = (int*)alloc((size_t)E * 4);
  int* csr = (int*)alloc((size_t)(E + 32) * 4);  // pad: gather overruns ≤16 ints
  half_t* hbuf1 = (half_t*)alloc((size_t)N * 64 * 2);
  half_t* hbuf2 = (half_t*)alloc((size_t)N * 64 * 2);
  float* abuf = (float*)alloc((size_t)N * 64 * 4);
  float* ge = (float*)alloc((size_t)G * 64 * 4);

  // --- CSR build, atomic-free at global scope ---
  bucket_hist<<<NBLK, 256, 0, stream>>>(dstp, bcnt, E, nbuck);
  int nbA = (int)((M + SCAN_CHUNK - 1) / SCAN_CHUNK);
  scan1<<<nbA, 256, 0, stream>>>(bcnt, bcnt, bsum, (int)M);  // in-place exclusive scan
  scan2<<<1, 256, 0, stream>>>(bsum, nbA);
  scan3<<<(int)((M + 1 + 255) / 256), 256, 0, stream>>>(bcnt, bsum, (int)(M + 1));
  bucket_scatter<<<NBLK, 256, 0, stream>>>(src, dstp, bcnt, sdst, ssrc, E, nbuck);
  node_hist_rs<<<nbuck, 256, 0, stream>>>(sdst, bcnt, rs, isq, E, nbuck, N);
  csr_write<<<nbuck, 256, 0, stream>>>(sdst, ssrc, bcnt, rs, csr, E, nbuck, N);
  seg_offsets<<<(N + 255) / 256, 256, 0, stream>>>(batch, goff, N, G);

  int tiles = (N + 63) / 64;
  int gblocks = (N + 15) / 16;
  // conv1 GEMM
  gemm_n64<<<tiles, 256, 0, stream>>>(x, W1, isq, hbuf1, N);
  // conv1 gather + fused W2 GEMM -> hp2 (fp16)
  gather_conv_w2<<<gblocks, 256, 0, stream>>>(hbuf1, csr, rs, isq, b1, W2, hbuf2, N);
  // conv2 gather
  gather_conv<<<gblocks, 256, 0, stream>>>(hbuf2, csr, rs, isq, b2, abuf, N);
  // pool
  pool_mean<<<2048, 256, 0, stream>>>(abuf, goff, ge, G);
  // pair MLP
  pair_mlp<<<(P + PPB - 1) / PPB, 256, 0, stream>>>(ge, dp, Wr1, br1, Wr2, br2, out, P);
}

// Round 13
// 484.138 us; speedup vs baseline: 1.4897x; 1.0382x over previous
//
#include <hip/hip_runtime.h>
#include <cstdint>

#define N_GRAPHS 20000
#define SCAN_CHUNK 2048
#define NBLK 512  // blocks for bucket hist/scatter

typedef _Float16 half_t;
typedef __attribute__((ext_vector_type(4))) _Float16 half4;
typedef __attribute__((ext_vector_type(2))) _Float16 half2v;

// ---------------- prefix scan (exclusive) of in[M] -> out[M+1] ----------------
__global__ __launch_bounds__(256) void scan1(const int* __restrict__ in, int* __restrict__ out,
                                             int* __restrict__ bsum, int M) {
  __shared__ int lds[256];
  int t = threadIdx.x;
  int base = blockIdx.x * SCAN_CHUNK + t * 8;
  int v[8];
  int s = 0;
#pragma unroll
  for (int i = 0; i < 8; ++i) {
    v[i] = (base + i < M) ? in[base + i] : 0;
    s += v[i];
  }
  lds[t] = s;
  __syncthreads();
  for (int off = 1; off < 256; off <<= 1) {
    int x = (t >= off) ? lds[t - off] : 0;
    __syncthreads();
    lds[t] += x;
    __syncthreads();
  }
  if (t == 255) bsum[blockIdx.x] = lds[255];
  int run = (t > 0) ? lds[t - 1] : 0;
#pragma unroll
  for (int i = 0; i < 8; ++i) {
    if (base + i <= M) out[base + i] = run;
    run += v[i];
  }
}

__global__ __launch_bounds__(256) void scan2(int* __restrict__ bsum, int nb) {
  __shared__ int lds[256];
  int t = threadIdx.x;
  lds[t] = (t < nb) ? bsum[t] : 0;
  __syncthreads();
  for (int off = 1; off < 256; off <<= 1) {
    int x = (t >= off) ? lds[t - off] : 0;
    __syncthreads();
    lds[t] += x;
    __syncthreads();
  }
  if (t < nb) bsum[t] = (t > 0) ? lds[t - 1] : 0;  // exclusive
}

__global__ void scan3(int* __restrict__ out, const int* __restrict__ bsum, int Mp1) {
  int i = blockIdx.x * blockDim.x + threadIdx.x;
  if (i < Mp1) out[i] += bsum[i / SCAN_CHUNK];
}

// ---------------- P1: per-block bucket histogram (bucket = dst >> 10) ----------------
__global__ __launch_bounds__(256) void bucket_hist(const int* __restrict__ dst,
                                                   int* __restrict__ bcnt, int E, int nbuck) {
  __shared__ int h[512];
  for (int i = threadIdx.x; i < 512; i += 256) h[i] = 0;
  __syncthreads();
  int per = (E + NBLK - 1) / NBLK;
  int s = blockIdx.x * per;
  int e = min(s + per, E);
  for (int i = s + threadIdx.x; i < e; i += 256) atomicAdd(&h[dst[i] >> 10], 1);
  __syncthreads();
  for (int b = threadIdx.x; b < nbuck; b += 256) bcnt[(long)b * NBLK + blockIdx.x] = h[b];
}

// ---------------- P2: scatter edges into bucket-ordered arrays ----------------
__global__ __launch_bounds__(256) void bucket_scatter(const int* __restrict__ src,
                                                      const int* __restrict__ dst,
                                                      const int* __restrict__ bbase,
                                                      int* __restrict__ sdst,
                                                      int* __restrict__ ssrc, int E, int nbuck) {
  __shared__ int h[512];
  for (int b = threadIdx.x; b < nbuck; b += 256) h[b] = bbase[(long)b * NBLK + blockIdx.x];
  __syncthreads();
  int per = (E + NBLK - 1) / NBLK;
  int s = blockIdx.x * per;
  int e = min(s + per, E);
  for (int i = s + threadIdx.x; i < e; i += 256) {
    int d = dst[i];
    int pos = atomicAdd(&h[d >> 10], 1);
    sdst[pos] = d;
    ssrc[pos] = src[i];
  }
}

// ------- P3a fused: per-bucket node histogram -> rs (bucket base + LDS scan) + isq -------
__global__ __launch_bounds__(256) void node_hist_rs(const int* __restrict__ sdst,
                                                    const int* __restrict__ bbase,
                                                    int* __restrict__ rs, float* __restrict__ isq,
                                                    int E, int nbuck, int N) {
  __shared__ int h[1024];
  __shared__ int ws[256];
  int b = blockIdx.x;
  int n0 = b << 10;
  int nn = min(1024, N - n0);
  int t = threadIdx.x;
  for (int i = t; i < 1024; i += 256) h[i] = 0;
  __syncthreads();
  int s = bbase[(long)b * NBLK];
  int e = (b + 1 < nbuck) ? bbase[(long)(b + 1) * NBLK] : E;
  for (int i = s + t; i < e; i += 256) atomicAdd(&h[sdst[i] - n0], 1);
  __syncthreads();
  int v0 = h[4 * t], v1 = h[4 * t + 1], v2 = h[4 * t + 2], v3 = h[4 * t + 3];
  ws[t] = v0 + v1 + v2 + v3;
  __syncthreads();
  for (int off = 1; off < 256; off <<= 1) {
    int x = (t >= off) ? ws[t - off] : 0;
    __syncthreads();
    ws[t] += x;
    __syncthreads();
  }
  int run = s + ((t > 0) ? ws[t - 1] : 0);
  int i0 = 4 * t;
  if (i0 < nn) { rs[n0 + i0] = run; isq[n0 + i0] = rsqrtf((float)(v0 + 1)); }
  run += v0;
  if (i0 + 1 < nn) { rs[n0 + i0 + 1] = run; isq[n0 + i0 + 1] = rsqrtf((float)(v1 + 1)); }
  run += v1;
  if (i0 + 2 < nn) { rs[n0 + i0 + 2] = run; isq[n0 + i0 + 2] = rsqrtf((float)(v2 + 1)); }
  run += v2;
  if (i0 + 3 < nn) { rs[n0 + i0 + 3] = run; isq[n0 + i0 + 3] = rsqrtf((float)(v3 + 1)); }
  if (b == nbuck - 1 && t == 255) rs[N] = E;
}

// ---------------- P3c: per-bucket CSR write (LDS ranks, contiguous csr region) ----------------
__global__ __launch_bounds__(256) void csr_write(const int* __restrict__ sdst,
                                                 const int* __restrict__ ssrc,
                                                 const int* __restrict__ bbase,
                                                 const int* __restrict__ rs,
                                                 int* __restrict__ csr, int E, int nbuck, int N) {
  __shared__ int h[1024];
  int b = blockIdx.x;
  int n0 = b << 10;
  int nn = min(1024, N - n0);
  for (int i = threadIdx.x; i < nn; i += 256) h[i] = rs[n0 + i];
  __syncthreads();
  int s = bbase[(long)b * NBLK];
  int e = (b + 1 < nbuck) ? bbase[(long)(b + 1) * NBLK] : E;
  for (int i = s + threadIdx.x; i < e; i += 256) {
    int d = sdst[i];
    int pos = atomicAdd(&h[d - n0], 1);
    csr[pos] = ssrc[i];
  }
}

// ---------------- scale+cast: xs[n,:] = half(x[n,:] * isq[n]) ----------------
__global__ __launch_bounds__(256) void scale_cast(const float* __restrict__ x,
                                                  const float* __restrict__ isq,
                                                  half_t* __restrict__ xs, long nquads) {
  long i = (long)blockIdx.x * 256 + threadIdx.x;
  if (i >= nquads) return;
  int node = (int)(i >> 4);
  float s = isq[node];
  float4 v = ((const float4*)x)[i];
  half4 h;
  h[0] = (half_t)(v.x * s);
  h[1] = (half_t)(v.y * s);
  h[2] = (half_t)(v.z * s);
  h[3] = (half_t)(v.w * s);
  ((half4*)xs)[i] = h;
}

// ------- fused gather conv: agg = sum_{s in N(d)} xs[s] + xs[d]; y = agg @ W;
//         r = relu(y*isq[d] + b); out = half(scale_out ? r*isq[d] : r) -------
// xs fp16 rows (128B). Wave = 4 lane-groups of 16, 4-edge batching. One 64x64
// f32 weight staged in LDS; agg exchanged via wave-local LDS tile (no barrier).
__global__ __launch_bounds__(256) void gather_fused(const half_t* __restrict__ xs,
                                                    const int* __restrict__ csr,
                                                    const int* __restrict__ rs,
                                                    const float* __restrict__ isq,
                                                    const float* __restrict__ W,
                                                    const float* __restrict__ bias,
                                                    half_t* __restrict__ out, int N,
                                                    int scale_out) {
  __shared__ float Wl[64 * 64];   // [k][c]
  __shared__ float ex[16][68];    // per-block 16 nodes' agg vecs (pad 68)
  int tid = threadIdx.x;
#pragma unroll
  for (int v = 0; v < 4; ++v) {
    int u = tid + v * 256;
    *(float4*)&Wl[u * 4] = *(const float4*)&W[u * 4];
  }
  __syncthreads();  // all waves reach this before any divergence/return

  int lane = tid & 63;
  int sub = lane & 15;   // channel quad within row
  int grp = lane >> 4;   // dst group within wave
  int li = tid >> 4;     // local node index 0..15
  int wid = (blockIdx.x * blockDim.x + tid) >> 6;
  float4 bv = *(const float4*)&bias[sub * 4];
  long d0 = (long)wid * 4;
  if (d0 >= N) return;
  int d = (int)d0 + grp;
  bool vd = d < N;
  int dd = vd ? d : N - 1;
  int jj = rs[dd];
  int je = vd ? rs[dd + 1] : jj;
  float id = isq[dd];
  float4 ac;
  {
    half4 sv = *(const half4*)&xs[(long)dd * 64 + sub * 4];
    ac.x = (float)sv[0]; ac.y = (float)sv[1]; ac.z = (float)sv[2]; ac.w = (float)sv[3];
  }
  const half4 hz = {(half_t)0, (half_t)0, (half_t)0, (half_t)0};
  while (__any(jj < je)) {
    bool a0 = jj < je;
    bool a1 = jj + 1 < je;
    bool a2 = jj + 2 < je;
    bool a3 = jj + 3 < je;
    int s0 = csr[jj];
    int s1 = csr[jj + 1];
    int s2 = csr[jj + 2];
    int s3 = csr[jj + 3];
    half4 v0 = hz, v1 = hz, v2 = hz, v3 = hz;
    if (a0) v0 = *(const half4*)&xs[(long)s0 * 64 + sub * 4];
    if (a1) v1 = *(const half4*)&xs[(long)s1 * 64 + sub * 4];
    if (a2) v2 = *(const half4*)&xs[(long)s2 * 64 + sub * 4];
    if (a3) v3 = *(const half4*)&xs[(long)s3 * 64 + sub * 4];
    ac.x += ((float)v0[0] + (float)v1[0]) + ((float)v2[0] + (float)v3[0]);
    ac.y += ((float)v0[1] + (float)v1[1]) + ((float)v2[1] + (float)v3[1]);
    ac.z += ((float)v0[2] + (float)v1[2]) + ((float)v2[2] + (float)v3[2]);
    ac.w += ((float)v0[3] + (float)v1[3]) + ((float)v2[3] + (float)v3[3]);
    jj += 4;
  }
  // agg -> wave-local LDS exchange (same wave writes & reads; no barrier)
  *(float4*)&ex[li][sub * 4] = ac;
  // y = agg @ W: each lane computes channels sub*4..sub*4+3 for its group's node
  float y0 = 0.f, y1 = 0.f, y2 = 0.f, y3 = 0.f;
#pragma unroll
  for (int k4 = 0; k4 < 16; ++k4) {
    float4 rv = *(const float4*)&ex[li][k4 * 4];
#pragma unroll
    for (int kk = 0; kk < 4; ++kk) {
      float4 w = *(const float4*)&Wl[(k4 * 4 + kk) * 64 + sub * 4];
      float a = (&rv.x)[kk];
      y0 = fmaf(a, w.x, y0);
      y1 = fmaf(a, w.y, y1);
      y2 = fmaf(a, w.z, y2);
      y3 = fmaf(a, w.w, y3);
    }
  }
  if (vd) {
    float r0 = fmaxf(fmaf(y0, id, bv.x), 0.f);
    float r1 = fmaxf(fmaf(y1, id, bv.y), 0.f);
    float r2 = fmaxf(fmaf(y2, id, bv.z), 0.f);
    float r3 = fmaxf(fmaf(y3, id, bv.w), 0.f);
    float m = scale_out ? id : 1.f;
    half4 hv;
    hv[0] = (half_t)(r0 * m);
    hv[1] = (half_t)(r1 * m);
    hv[2] = (half_t)(r2 * m);
    hv[3] = (half_t)(r3 * m);
    *(half4*)&out[(long)d * 64 + sub * 4] = hv;
  }
}

// ---------------- graph segment offsets from sorted batch_idx ----------------
__global__ void seg_offsets(const int* __restrict__ batch, int* __restrict__ off, int N, int G) {
  int i = blockIdx.x * blockDim.x + threadIdx.x;
  if (i >= N) return;
  int b = batch[i];
  if (i == 0) {
    for (int g = 0; g <= b; ++g) off[g] = 0;
  } else {
    int pb = batch[i - 1];
    for (int g = pb + 1; g <= b; ++g) off[g] = i;
  }
  if (i == N - 1) {
    for (int g = b + 1; g <= G; ++g) off[g] = N;
  }
}

// ------- mean pool over fp16 rows: lane = half2 channel pair, 2 row-parities/wave -------
__global__ void pool_mean(const half_t* __restrict__ e2, const int* __restrict__ off,
                          float* __restrict__ ge, int G) {
  int lane = threadIdx.x & 63;
  int wid = (blockIdx.x * blockDim.x + threadIdx.x) >> 6;
  int nw = (gridDim.x * blockDim.x) >> 6;
  int c2 = lane & 31;   // half2 index (channels c2*2, c2*2+1)
  int rp = lane >> 5;   // row parity
  for (int g = wid; g < G; g += nw) {
    int s = off[g];
    int e = off[g + 1];
    float p0a = 0.f, p1a = 0.f, p0b = 0.f, p1b = 0.f;
    int n = s + rp;
    for (; n + 2 < e; n += 4) {
      half2v va = *(const half2v*)&e2[(long)n * 64 + c2 * 2];
      half2v vb = *(const half2v*)&e2[(long)(n + 2) * 64 + c2 * 2];
      p0a += (float)va[0]; p1a += (float)va[1];
      p0b += (float)vb[0]; p1b += (float)vb[1];
    }
    for (; n < e; n += 2) {
      half2v va = *(const half2v*)&e2[(long)n * 64 + c2 * 2];
      p0a += (float)va[0]; p1a += (float)va[1];
    }
    float p0 = p0a + p0b;
    float p1 = p1a + p1b;
    p0 += __shfl_xor(p0, 32, 64);
    p1 += __shfl_xor(p1, 32, 64);
    if (rp == 0) {
      float inv = 1.f / fmaxf((float)(e - s), 1.f);
      *(float2*)&ge[(long)g * 64 + c2 * 2] = make_float2(p0 * inv, p1 * inv);
    }
  }
}

// ---------------- pair MLP ----------------
#define PPB 16
__global__ __launch_bounds__(256) void pair_mlp(const float* __restrict__ ge,
                                                const int* __restrict__ dp,
                                                const float* __restrict__ Wr1,
                                                const float* __restrict__ br1,
                                                const float* __restrict__ Wr2,
                                                const float* __restrict__ br2,
                                                float* __restrict__ out, int P) {
  __shared__ float feat[PPB][128];
  __shared__ int pidx[2][PPB];
  __shared__ float red[4][PPB];
  int tid = threadIdx.x;
  int base = blockIdx.x * PPB;
  if (tid < PPB) {
    int p = base + tid;
    pidx[0][tid] = (p < P) ? dp[p] : 0;
    pidx[1][tid] = (p < P) ? dp[P + p] : 0;
  }
  __syncthreads();
#pragma unroll
  for (int i = 0; i < 8; ++i) {
    int f = tid + i * 256;
    int p = f >> 7;
    int k = f & 127;
    int g = (k < 64) ? pidx[0][p] : pidx[1][p];
    feat[p][k] = ge[(long)g * 64 + (k & 63)];
  }
  __syncthreads();
  int j = tid;
  float w2 = Wr2[j];
  float b1v = br1[j];
  float acc[PPB];
#pragma unroll
  for (int p = 0; p < PPB; ++p) acc[p] = 0.f;
  for (int k4 = 0; k4 < 128; k4 += 4) {
    float w0 = Wr1[(k4 + 0) * 256 + j];
    float w1 = Wr1[(k4 + 1) * 256 + j];
    float wv2 = Wr1[(k4 + 2) * 256 + j];
    float w3 = Wr1[(k4 + 3) * 256 + j];
#pragma unroll
    for (int p = 0; p < PPB; ++p) {
      float4 f = *(const float4*)&feat[p][k4];
      acc[p] = fmaf(f.x, w0, acc[p]);
      acc[p] = fmaf(f.y, w1, acc[p]);
      acc[p] = fmaf(f.z, wv2, acc[p]);
      acc[p] = fmaf(f.w, w3, acc[p]);
    }
  }
  int wv = tid >> 6;
#pragma unroll
  for (int p = 0; p < PPB; ++p) {
    float hid = fmaxf(acc[p] + b1v, 0.f);
    float v = hid * w2;
    for (int o = 32; o > 0; o >>= 1) v += __shfl_down(v, o, 64);
    if ((tid & 63) == 0) red[wv][p] = v;
  }
  __syncthreads();
  if (tid < PPB) {
    int p = base + tid;
    if (p < P) out[p] = red[0][tid] + red[1][tid] + red[2][tid] + red[3][tid] + br2[0];
  }
}

extern "C" void kernel_launch(void* const* d_in, const int* in_sizes, int n_in,
                              void* d_out, int out_size, void* d_ws, size_t ws_size,
                              hipStream_t stream) {
  const float* x = (const float*)d_in[0];
  const int* ei = (const int*)d_in[1];
  const int* batch = (const int*)d_in[2];
  const int* dp = (const int*)d_in[3];
  const float* W1 = (const float*)d_in[4];
  const float* b1 = (const float*)d_in[5];
  const float* W2 = (const float*)d_in[6];
  const float* b2 = (const float*)d_in[7];
  const float* Wr1 = (const float*)d_in[8];
  const float* br1 = (const float*)d_in[9];
  const float* Wr2 = (const float*)d_in[10];
  const float* br2 = (const float*)d_in[11];
  float* out = (float*)d_out;

  int N = in_sizes[0] / 64;
  int E = in_sizes[1] / 2;
  int P = in_sizes[3] / 2;
  int G = N_GRAPHS;
  const int* src = ei;
  const int* dstp = ei + E;

  int nbuck = (N + 1023) >> 10;  // <= 512
  long M = (long)nbuck * NBLK;

  char* ws = (char*)d_ws;
  size_t o = 0;
  auto alloc = [&](size_t bytes) {
    void* p = ws + o;
    o += (bytes + 255) & ~(size_t)255;
    return p;
  };
  float* isq = (float*)alloc((size_t)N * 4);
  int* rs = (int*)alloc((size_t)(N + 1) * 4);
  int* bsum = (int*)alloc(1024 * 4);
  int* goff = (int*)alloc((size_t)(G + 1) * 4);
  int* bcnt = (int*)alloc((size_t)(M + 1) * 4);
  int* sdst = (int*)alloc((size_t)E * 4);
  int* ssrc = (int*)alloc((size_t)E * 4);
  int* csr = (int*)alloc((size_t)(E + 32) * 4);  // pad: gather overruns ≤16 ints
  half_t* xs1 = (half_t*)alloc((size_t)N * 64 * 2);
  half_t* xs2 = (half_t*)alloc((size_t)N * 64 * 2);
  half_t* abuf = (half_t*)alloc((size_t)N * 64 * 2);
  float* ge = (float*)alloc((size_t)G * 64 * 4);

  // --- CSR build, atomic-free at global scope ---
  bucket_hist<<<NBLK, 256, 0, stream>>>(dstp, bcnt, E, nbuck);
  int nbA = (int)((M + SCAN_CHUNK - 1) / SCAN_CHUNK);
  scan1<<<nbA, 256, 0, stream>>>(bcnt, bcnt, bsum, (int)M);  // in-place exclusive scan
  scan2<<<1, 256, 0, stream>>>(bsum, nbA);
  scan3<<<(int)((M + 1 + 255) / 256), 256, 0, stream>>>(bcnt, bsum, (int)(M + 1));
  bucket_scatter<<<NBLK, 256, 0, stream>>>(src, dstp, bcnt, sdst, ssrc, E, nbuck);
  node_hist_rs<<<nbuck, 256, 0, stream>>>(sdst, bcnt, rs, isq, E, nbuck, N);
  csr_write<<<nbuck, 256, 0, stream>>>(sdst, ssrc, bcnt, rs, csr, E, nbuck, N);
  seg_offsets<<<(N + 255) / 256, 256, 0, stream>>>(batch, goff, N, G);

  long nquads = (long)N * 16;
  int gblocks = (N + 15) / 16;
  // xs1 = x * isq (fp16)
  scale_cast<<<(int)((nquads + 255) / 256), 256, 0, stream>>>(x, isq, xs1, nquads);
  // conv1: gather xs1, @W1 epilogue, out xs2 = relu1*isq (fp16)
  gather_fused<<<gblocks, 256, 0, stream>>>(xs1, csr, rs, isq, W1, b1, xs2, N, 1);
  // conv2: gather xs2, @W2 epilogue, out abuf = relu2 (fp16)
  gather_fused<<<gblocks, 256, 0, stream>>>(xs2, csr, rs, isq, W2, b2, abuf, N, 0);
  // pool
  pool_mean<<<2048, 256, 0, stream>>>(abuf, goff, ge, G);
  // pair MLP
  pair_mlp<<<(P + PPB - 1) / PPB, 256, 0, stream>>>(ge, dp, Wr1, br1, Wr2, br2, out, P);
}

// Round 14
// 393.619 us; speedup vs baseline: 1.8322x; 1.2300x over previous
//
#include <hip/hip_runtime.h>
#include <cstdint>

#define N_GRAPHS 20000
#define SCAN_CHUNK 2048
#define NBLK 512  // blocks for bucket hist/scatter

typedef _Float16 half_t;
typedef __attribute__((ext_vector_type(4))) _Float16 half4;
typedef __attribute__((ext_vector_type(8))) _Float16 half8;

// ---------------- prefix scan (exclusive) of in[M] -> out[M+1] ----------------
__global__ __launch_bounds__(256) void scan1(const int* __restrict__ in, int* __restrict__ out,
                                             int* __restrict__ bsum, int M) {
  __shared__ int lds[256];
  int t = threadIdx.x;
  int base = blockIdx.x * SCAN_CHUNK + t * 8;
  int v[8];
  int s = 0;
#pragma unroll
  for (int i = 0; i < 8; ++i) {
    v[i] = (base + i < M) ? in[base + i] : 0;
    s += v[i];
  }
  lds[t] = s;
  __syncthreads();
  for (int off = 1; off < 256; off <<= 1) {
    int x = (t >= off) ? lds[t - off] : 0;
    __syncthreads();
    lds[t] += x;
    __syncthreads();
  }
  if (t == 255) bsum[blockIdx.x] = lds[255];
  int run = (t > 0) ? lds[t - 1] : 0;
#pragma unroll
  for (int i = 0; i < 8; ++i) {
    if (base + i <= M) out[base + i] = run;
    run += v[i];
  }
}

__global__ __launch_bounds__(256) void scan2(int* __restrict__ bsum, int nb) {
  __shared__ int lds[256];
  int t = threadIdx.x;
  lds[t] = (t < nb) ? bsum[t] : 0;
  __syncthreads();
  for (int off = 1; off < 256; off <<= 1) {
    int x = (t >= off) ? lds[t - off] : 0;
    __syncthreads();
    lds[t] += x;
    __syncthreads();
  }
  if (t < nb) bsum[t] = (t > 0) ? lds[t - 1] : 0;  // exclusive
}

__global__ void scan3(int* __restrict__ out, const int* __restrict__ bsum, int Mp1) {
  int i = blockIdx.x * blockDim.x + threadIdx.x;
  if (i < Mp1) out[i] += bsum[i / SCAN_CHUNK];
}

// ---------------- P1: per-block bucket histogram (bucket = dst >> 10) ----------------
__global__ __launch_bounds__(256) void bucket_hist(const int* __restrict__ dst,
                                                   int* __restrict__ bcnt, int E, int nbuck) {
  __shared__ int h[512];
  for (int i = threadIdx.x; i < 512; i += 256) h[i] = 0;
  __syncthreads();
  int per = (E + NBLK - 1) / NBLK;
  int s = blockIdx.x * per;
  int e = min(s + per, E);
  for (int i = s + threadIdx.x; i < e; i += 256) atomicAdd(&h[dst[i] >> 10], 1);
  __syncthreads();
  for (int b = threadIdx.x; b < nbuck; b += 256) bcnt[(long)b * NBLK + blockIdx.x] = h[b];
}

// ---------------- P2: scatter edges into bucket-ordered (dst,src) int2 array ----------------
__global__ __launch_bounds__(256) void bucket_scatter(const int* __restrict__ src,
                                                      const int* __restrict__ dst,
                                                      const int* __restrict__ bbase,
                                                      int2* __restrict__ sed, int E, int nbuck) {
  __shared__ int h[512];
  for (int b = threadIdx.x; b < nbuck; b += 256) h[b] = bbase[(long)b * NBLK + blockIdx.x];
  __syncthreads();
  int per = (E + NBLK - 1) / NBLK;
  int s = blockIdx.x * per;
  int e = min(s + per, E);
  for (int i = s + threadIdx.x; i < e; i += 256) {
    int d = dst[i];
    int pos = atomicAdd(&h[d >> 10], 1);
    sed[pos] = make_int2(d, src[i]);
  }
}

// ------- P3a fused: per-bucket node histogram -> rs (bucket base + LDS scan) + isq -------
__global__ __launch_bounds__(256) void node_hist_rs(const int2* __restrict__ sed,
                                                    const int* __restrict__ bbase,
                                                    int* __restrict__ rs, float* __restrict__ isq,
                                                    int E, int nbuck, int N) {
  __shared__ int h[1024];
  __shared__ int ws[256];
  int b = blockIdx.x;
  int n0 = b << 10;
  int nn = min(1024, N - n0);
  int t = threadIdx.x;
  for (int i = t; i < 1024; i += 256) h[i] = 0;
  __syncthreads();
  int s = bbase[(long)b * NBLK];
  int e = (b + 1 < nbuck) ? bbase[(long)(b + 1) * NBLK] : E;
  for (int i = s + t; i < e; i += 256) atomicAdd(&h[sed[i].x - n0], 1);
  __syncthreads();
  int v0 = h[4 * t], v1 = h[4 * t + 1], v2 = h[4 * t + 2], v3 = h[4 * t + 3];
  ws[t] = v0 + v1 + v2 + v3;
  __syncthreads();
  for (int off = 1; off < 256; off <<= 1) {
    int x = (t >= off) ? ws[t - off] : 0;
    __syncthreads();
    ws[t] += x;
    __syncthreads();
  }
  int run = s + ((t > 0) ? ws[t - 1] : 0);
  int i0 = 4 * t;
  if (i0 < nn) { rs[n0 + i0] = run; isq[n0 + i0] = rsqrtf((float)(v0 + 1)); }
  run += v0;
  if (i0 + 1 < nn) { rs[n0 + i0 + 1] = run; isq[n0 + i0 + 1] = rsqrtf((float)(v1 + 1)); }
  run += v1;
  if (i0 + 2 < nn) { rs[n0 + i0 + 2] = run; isq[n0 + i0 + 2] = rsqrtf((float)(v2 + 1)); }
  run += v2;
  if (i0 + 3 < nn) { rs[n0 + i0 + 3] = run; isq[n0 + i0 + 3] = rsqrtf((float)(v3 + 1)); }
  if (b == nbuck - 1 && t == 255) rs[N] = E;
}

// ---------------- P3c: per-bucket CSR write (LDS ranks, contiguous csr region) ----------------
__global__ __launch_bounds__(256) void csr_write(const int2* __restrict__ sed,
                                                 const int* __restrict__ bbase,
                                                 const int* __restrict__ rs,
                                                 int* __restrict__ csr, int E, int nbuck, int N) {
  __shared__ int h[1024];
  int b = blockIdx.x;
  int n0 = b << 10;
  int nn = min(1024, N - n0);
  for (int i = threadIdx.x; i < nn; i += 256) h[i] = rs[n0 + i];
  __syncthreads();
  int s = bbase[(long)b * NBLK];
  int e = (b + 1 < nbuck) ? bbase[(long)(b + 1) * NBLK] : E;
  for (int i = s + threadIdx.x; i < e; i += 256) {
    int2 v = sed[i];
    int pos = atomicAdd(&h[v.x - n0], 1);
    csr[pos] = v.y;
  }
}

// ---------------- scale+cast: xs[n,:] = half(x[n,:] * isq[n]), half8 per thread -------------
__global__ __launch_bounds__(256) void scale_cast(const float* __restrict__ x,
                                                  const float* __restrict__ isq,
                                                  half_t* __restrict__ xs, long nocts) {
  long i = (long)blockIdx.x * 256 + threadIdx.x;
  if (i >= nocts) return;
  int node = (int)(i >> 3);
  float s = isq[node];
  float4 vlo = ((const float4*)x)[i * 2];
  float4 vhi = ((const float4*)x)[i * 2 + 1];
  half8 h;
  h[0] = (half_t)(vlo.x * s);
  h[1] = (half_t)(vlo.y * s);
  h[2] = (half_t)(vlo.z * s);
  h[3] = (half_t)(vlo.w * s);
  h[4] = (half_t)(vhi.x * s);
  h[5] = (half_t)(vhi.y * s);
  h[6] = (half_t)(vhi.z * s);
  h[7] = (half_t)(vhi.w * s);
  ((half8*)xs)[i] = h;
}

// ------- fused gather conv: agg = sum_{s in N(d)} xs[s] + xs[d]; y = agg @ W;
//         r = relu(y*isq[d] + b); out = half(scale_out ? r*isq[d] : r) -------
// xs fp16 rows (128B). Wave = 8 lane-groups of 8; each lane covers 8 channels
// (16B half8 loads). 4-edge batching -> 32 outstanding row-fetches per wave.
__global__ __launch_bounds__(256) void gather_fused(const half_t* __restrict__ xs,
                                                    const int* __restrict__ csr,
                                                    const int* __restrict__ rs,
                                                    const float* __restrict__ isq,
                                                    const float* __restrict__ W,
                                                    const float* __restrict__ bias,
                                                    half_t* __restrict__ out, int N,
                                                    int scale_out) {
  __shared__ float Wl[64 * 64];   // [k][c]
  __shared__ float ex[32][68];    // per-block 32 nodes' agg vecs (pad 68)
  int tid = threadIdx.x;
#pragma unroll
  for (int v = 0; v < 4; ++v) {
    int u = tid + v * 256;
    *(float4*)&Wl[u * 4] = *(const float4*)&W[u * 4];
  }
  __syncthreads();  // all waves reach this before any divergence/return

  int lane = tid & 63;
  int sub = lane & 7;    // channel octet: channels sub*8..sub*8+7
  int grp = lane >> 3;   // dst group within wave (0..7)
  int li = tid >> 3;     // local node index 0..31
  int wid = (blockIdx.x * blockDim.x + tid) >> 6;
  long d0 = (long)wid * 8;
  if (d0 >= N) return;
  int d = (int)d0 + grp;
  bool vd = d < N;
  int dd = vd ? d : N - 1;
  int jj = rs[dd];
  int je = vd ? rs[dd + 1] : jj;
  float id = isq[dd];
  float4 blo = *(const float4*)&bias[sub * 8];
  float4 bhi = *(const float4*)&bias[sub * 8 + 4];
  float ac[8];
  {
    half8 sv = *(const half8*)&xs[(long)dd * 64 + sub * 8];
#pragma unroll
    for (int c = 0; c < 8; ++c) ac[c] = (float)sv[c];
  }
  const half8 hz = {(half_t)0, (half_t)0, (half_t)0, (half_t)0,
                    (half_t)0, (half_t)0, (half_t)0, (half_t)0};
  while (__any(jj < je)) {
    bool a0 = jj < je;
    bool a1 = jj + 1 < je;
    bool a2 = jj + 2 < je;
    bool a3 = jj + 3 < je;
    int s0 = csr[jj];
    int s1 = csr[jj + 1];
    int s2 = csr[jj + 2];
    int s3 = csr[jj + 3];
    half8 v0 = hz, v1 = hz, v2 = hz, v3 = hz;
    if (a0) v0 = *(const half8*)&xs[(long)s0 * 64 + sub * 8];
    if (a1) v1 = *(const half8*)&xs[(long)s1 * 64 + sub * 8];
    if (a2) v2 = *(const half8*)&xs[(long)s2 * 64 + sub * 8];
    if (a3) v3 = *(const half8*)&xs[(long)s3 * 64 + sub * 8];
#pragma unroll
    for (int c = 0; c < 8; ++c)
      ac[c] += ((float)v0[c] + (float)v1[c]) + ((float)v2[c] + (float)v3[c]);
    jj += 4;
  }
  // agg -> wave-local LDS exchange (same wave writes & reads; no barrier)
  *(float4*)&ex[li][sub * 8] = make_float4(ac[0], ac[1], ac[2], ac[3]);
  *(float4*)&ex[li][sub * 8 + 4] = make_float4(ac[4], ac[5], ac[6], ac[7]);
  // y = agg @ W: each lane computes channels sub*8..sub*8+7 for its group's node
  float4 ylo = make_float4(0.f, 0.f, 0.f, 0.f);
  float4 yhi = make_float4(0.f, 0.f, 0.f, 0.f);
#pragma unroll
  for (int k4 = 0; k4 < 16; ++k4) {
    float4 rv = *(const float4*)&ex[li][k4 * 4];
#pragma unroll
    for (int kk = 0; kk < 4; ++kk) {
      float a = (&rv.x)[kk];
      float4 w0 = *(const float4*)&Wl[(k4 * 4 + kk) * 64 + sub * 8];
      float4 w1 = *(const float4*)&Wl[(k4 * 4 + kk) * 64 + sub * 8 + 4];
      ylo.x = fmaf(a, w0.x, ylo.x);
      ylo.y = fmaf(a, w0.y, ylo.y);
      ylo.z = fmaf(a, w0.z, ylo.z);
      ylo.w = fmaf(a, w0.w, ylo.w);
      yhi.x = fmaf(a, w1.x, yhi.x);
      yhi.y = fmaf(a, w1.y, yhi.y);
      yhi.z = fmaf(a, w1.z, yhi.z);
      yhi.w = fmaf(a, w1.w, yhi.w);
    }
  }
  if (vd) {
    float m = scale_out ? id : 1.f;
    half8 hv;
    hv[0] = (half_t)(fmaxf(fmaf(ylo.x, id, blo.x), 0.f) * m);
    hv[1] = (half_t)(fmaxf(fmaf(ylo.y, id, blo.y), 0.f) * m);
    hv[2] = (half_t)(fmaxf(fmaf(ylo.z, id, blo.z), 0.f) * m);
    hv[3] = (half_t)(fmaxf(fmaf(ylo.w, id, blo.w), 0.f) * m);
    hv[4] = (half_t)(fmaxf(fmaf(yhi.x, id, bhi.x), 0.f) * m);
    hv[5] = (half_t)(fmaxf(fmaf(yhi.y, id, bhi.y), 0.f) * m);
    hv[6] = (half_t)(fmaxf(fmaf(yhi.z, id, bhi.z), 0.f) * m);
    hv[7] = (half_t)(fmaxf(fmaf(yhi.w, id, bhi.w), 0.f) * m);
    *(half8*)&out[(long)d * 64 + sub * 8] = hv;
  }
}

// ---------------- graph segment offsets from sorted batch_idx ----------------
__global__ void seg_offsets(const int* __restrict__ batch, int* __restrict__ off, int N, int G) {
  int i = blockIdx.x * blockDim.x + threadIdx.x;
  if (i >= N) return;
  int b = batch[i];
  if (i == 0) {
    for (int g = 0; g <= b; ++g) off[g] = 0;
  } else {
    int pb = batch[i - 1];
    for (int g = pb + 1; g <= b; ++g) off[g] = i;
  }
  if (i == N - 1) {
    for (int g = b + 1; g <= G; ++g) off[g] = N;
  }
}

// ------- mean pool over fp16 rows: lane = half8 (16B), 8 row-parities/wave -------
__global__ void pool_mean(const half_t* __restrict__ e2, const int* __restrict__ off,
                          float* __restrict__ ge, int G) {
  int lane = threadIdx.x & 63;
  int wid = (blockIdx.x * blockDim.x + threadIdx.x) >> 6;
  int nw = (gridDim.x * blockDim.x) >> 6;
  int c8 = lane & 7;   // channel octet
  int rp = lane >> 3;  // row parity 0..7
  for (int g = wid; g < G; g += nw) {
    int s = off[g];
    int e = off[g + 1];
    float acc[8];
#pragma unroll
    for (int c = 0; c < 8; ++c) acc[c] = 0.f;
    for (int n = s + rp; n < e; n += 8) {
      half8 v = *(const half8*)&e2[(long)n * 64 + c8 * 8];
#pragma unroll
      for (int c = 0; c < 8; ++c) acc[c] += (float)v[c];
    }
#pragma unroll
    for (int c = 0; c < 8; ++c) {
      acc[c] += __shfl_xor(acc[c], 8, 64);
      acc[c] += __shfl_xor(acc[c], 16, 64);
      acc[c] += __shfl_xor(acc[c], 32, 64);
    }
    if (rp == 0) {
      float inv = 1.f / fmaxf((float)(e - s), 1.f);
      float4 lo = make_float4(acc[0] * inv, acc[1] * inv, acc[2] * inv, acc[3] * inv);
      float4 hi = make_float4(acc[4] * inv, acc[5] * inv, acc[6] * inv, acc[7] * inv);
      *(float4*)&ge[(long)g * 64 + c8 * 8] = lo;
      *(float4*)&ge[(long)g * 64 + c8 * 8 + 4] = hi;
    }
  }
}

// ---------------- pair MLP ----------------
#define PPB 16
__global__ __launch_bounds__(256) void pair_mlp(const float* __restrict__ ge,
                                                const int* __restrict__ dp,
                                                const float* __restrict__ Wr1,
                                                const float* __restrict__ br1,
                                                const float* __restrict__ Wr2,
                                                const float* __restrict__ br2,
                                                float* __restrict__ out, int P) {
  __shared__ float feat[PPB][128];
  __shared__ int pidx[2][PPB];
  __shared__ float red[4][PPB];
  int tid = threadIdx.x;
  int base = blockIdx.x * PPB;
  if (tid < PPB) {
    int p = base + tid;
    pidx[0][tid] = (p < P) ? dp[p] : 0;
    pidx[1][tid] = (p < P) ? dp[P + p] : 0;
  }
  __syncthreads();
#pragma unroll
  for (int i = 0; i < 8; ++i) {
    int f = tid + i * 256;
    int p = f >> 7;
    int k = f & 127;
    int g = (k < 64) ? pidx[0][p] : pidx[1][p];
    feat[p][k] = ge[(long)g * 64 + (k & 63)];
  }
  __syncthreads();
  int j = tid;
  float w2 = Wr2[j];
  float b1v = br1[j];
  float acc[PPB];
#pragma unroll
  for (int p = 0; p < PPB; ++p) acc[p] = 0.f;
  for (int k4 = 0; k4 < 128; k4 += 4) {
    float w0 = Wr1[(k4 + 0) * 256 + j];
    float w1 = Wr1[(k4 + 1) * 256 + j];
    float wv2 = Wr1[(k4 + 2) * 256 + j];
    float w3 = Wr1[(k4 + 3) * 256 + j];
#pragma unroll
    for (int p = 0; p < PPB; ++p) {
      float4 f = *(const float4*)&feat[p][k4];
      acc[p] = fmaf(f.x, w0, acc[p]);
      acc[p] = fmaf(f.y, w1, acc[p]);
      acc[p] = fmaf(f.z, wv2, acc[p]);
      acc[p] = fmaf(f.w, w3, acc[p]);
    }
  }
  int wv = tid >> 6;
#pragma unroll
  for (int p = 0; p < PPB; ++p) {
    float hid = fmaxf(acc[p] + b1v, 0.f);
    float v = hid * w2;
    for (int o = 32; o > 0; o >>= 1) v += __shfl_down(v, o, 64);
    if ((tid & 63) == 0) red[wv][p] = v;
  }
  __syncthreads();
  if (tid < PPB) {
    int p = base + tid;
    if (p < P) out[p] = red[0][tid] + red[1][tid] + red[2][tid] + red[3][tid] + br2[0];
  }
}

extern "C" void kernel_launch(void* const* d_in, const int* in_sizes, int n_in,
                              void* d_out, int out_size, void* d_ws, size_t ws_size,
                              hipStream_t stream) {
  const float* x = (const float*)d_in[0];
  const int* ei = (const int*)d_in[1];
  const int* batch = (const int*)d_in[2];
  const int* dp = (const int*)d_in[3];
  const float* W1 = (const float*)d_in[4];
  const float* b1 = (const float*)d_in[5];
  const float* W2 = (const float*)d_in[6];
  const float* b2 = (const float*)d_in[7];
  const float* Wr1 = (const float*)d_in[8];
  const float* br1 = (const float*)d_in[9];
  const float* Wr2 = (const float*)d_in[10];
  const float* br2 = (const float*)d_in[11];
  float* out = (float*)d_out;

  int N = in_sizes[0] / 64;
  int E = in_sizes[1] / 2;
  int P = in_sizes[3] / 2;
  int G = N_GRAPHS;
  const int* src = ei;
  const int* dstp = ei + E;

  int nbuck = (N + 1023) >> 10;  // <= 512
  long M = (long)nbuck * NBLK;

  char* ws = (char*)d_ws;
  size_t o = 0;
  auto alloc = [&](size_t bytes) {
    void* p = ws + o;
    o += (bytes + 255) & ~(size_t)255;
    return p;
  };
  float* isq = (float*)alloc((size_t)N * 4);
  int* rs = (int*)alloc((size_t)(N + 1) * 4);
  int* bsum = (int*)alloc(1024 * 4);
  int* goff = (int*)alloc((size_t)(G + 1) * 4);
  int* bcnt = (int*)alloc((size_t)(M + 1) * 4);
  int2* sed = (int2*)alloc((size_t)E * 8);
  int* csr = (int*)alloc((size_t)(E + 32) * 4);  // pad: gather overruns ≤16 ints
  half_t* xs1 = (half_t*)alloc((size_t)N * 64 * 2);
  half_t* xs2 = (half_t*)alloc((size_t)N * 64 * 2);
  half_t* abuf = (half_t*)alloc((size_t)N * 64 * 2);
  float* ge = (float*)alloc((size_t)G * 64 * 4);

  // --- CSR build, atomic-free at global scope ---
  bucket_hist<<<NBLK, 256, 0, stream>>>(dstp, bcnt, E, nbuck);
  int nbA = (int)((M + SCAN_CHUNK - 1) / SCAN_CHUNK);
  scan1<<<nbA, 256, 0, stream>>>(bcnt, bcnt, bsum, (int)M);  // in-place exclusive scan
  scan2<<<1, 256, 0, stream>>>(bsum, nbA);
  scan3<<<(int)((M + 1 + 255) / 256), 256, 0, stream>>>(bcnt, bsum, (int)(M + 1));
  bucket_scatter<<<NBLK, 256, 0, stream>>>(src, dstp, bcnt, sed, E, nbuck);
  node_hist_rs<<<nbuck, 256, 0, stream>>>(sed, bcnt, rs, isq, E, nbuck, N);
  csr_write<<<nbuck, 256, 0, stream>>>(sed, bcnt, rs, csr, E, nbuck, N);
  seg_offsets<<<(N + 255) / 256, 256, 0, stream>>>(batch, goff, N, G);

  long nocts = (long)N * 8;
  int gblocks = (N + 31) / 32;  // 4 waves/block, 8 dst/wave
  // xs1 = x * isq (fp16)
  scale_cast<<<(int)((nocts + 255) / 256), 256, 0, stream>>>(x, isq, xs1, nocts);
  // conv1: gather xs1, @W1 epilogue, out xs2 = relu1*isq (fp16)
  gather_fused<<<gblocks, 256, 0, stream>>>(xs1, csr, rs, isq, W1, b1, xs2, N, 1);
  // conv2: gather xs2, @W2 epilogue, out abuf = relu2 (fp16)
  gather_fused<<<gblocks, 256, 0, stream>>>(xs2, csr, rs, isq, W2, b2, abuf, N, 0);
  // pool
  pool_mean<<<2048, 256, 0, stream>>>(abuf, goff, ge, G);
  // pair MLP
  pair_mlp<<<(P + PPB - 1) / PPB, 256, 0, stream>>>(ge, dp, Wr1, br1, Wr2, br2, out, P);
}

// Round 15
// 368.294 us; speedup vs baseline: 1.9582x; 1.0688x over previous
//
#include <hip/hip_runtime.h>
#include <cstdint>

#define N_GRAPHS 20000
#define SCAN_CHUNK 2048
#define NBLK 512  // blocks for bucket hist/scatter

typedef _Float16 half_t;
typedef __attribute__((ext_vector_type(4))) _Float16 half4;
typedef __attribute__((ext_vector_type(8))) _Float16 half8;

// ---------------- prefix scan (exclusive) of in[M] -> out[M+1] ----------------
__global__ __launch_bounds__(256) void scan1(const int* __restrict__ in, int* __restrict__ out,
                                             int* __restrict__ bsum, int M) {
  __shared__ int lds[256];
  int t = threadIdx.x;
  int base = blockIdx.x * SCAN_CHUNK + t * 8;
  int v[8];
  int s = 0;
#pragma unroll
  for (int i = 0; i < 8; ++i) {
    v[i] = (base + i < M) ? in[base + i] : 0;
    s += v[i];
  }
  lds[t] = s;
  __syncthreads();
  for (int off = 1; off < 256; off <<= 1) {
    int x = (t >= off) ? lds[t - off] : 0;
    __syncthreads();
    lds[t] += x;
    __syncthreads();
  }
  if (t == 255) bsum[blockIdx.x] = lds[255];
  int run = (t > 0) ? lds[t - 1] : 0;
#pragma unroll
  for (int i = 0; i < 8; ++i) {
    if (base + i <= M) out[base + i] = run;
    run += v[i];
  }
}

__global__ __launch_bounds__(256) void scan2(int* __restrict__ bsum, int nb) {
  __shared__ int lds[256];
  int t = threadIdx.x;
  lds[t] = (t < nb) ? bsum[t] : 0;
  __syncthreads();
  for (int off = 1; off < 256; off <<= 1) {
    int x = (t >= off) ? lds[t - off] : 0;
    __syncthreads();
    lds[t] += x;
    __syncthreads();
  }
  if (t < nb) bsum[t] = (t > 0) ? lds[t - 1] : 0;  // exclusive
}

__global__ void scan3(int* __restrict__ out, const int* __restrict__ bsum, int Mp1) {
  int i = blockIdx.x * blockDim.x + threadIdx.x;
  if (i < Mp1) out[i] += bsum[i / SCAN_CHUNK];
}

// ---------------- P1: per-block bucket histogram (bucket = dst >> 10) ----------------
__global__ __launch_bounds__(256) void bucket_hist(const int* __restrict__ dst,
                                                   int* __restrict__ bcnt, int E, int nbuck) {
  __shared__ int h[512];
  for (int i = threadIdx.x; i < 512; i += 256) h[i] = 0;
  __syncthreads();
  int per = (E + NBLK - 1) / NBLK;
  int s = blockIdx.x * per;
  int e = min(s + per, E);
  for (int i = s + threadIdx.x; i < e; i += 256) atomicAdd(&h[dst[i] >> 10], 1);
  __syncthreads();
  for (int b = threadIdx.x; b < nbuck; b += 256) bcnt[(long)b * NBLK + blockIdx.x] = h[b];
}

// ---------------- P2: scatter edges into bucket-ordered (dst,src) int2 array ----------------
__global__ __launch_bounds__(256) void bucket_scatter(const int* __restrict__ src,
                                                      const int* __restrict__ dst,
                                                      const int* __restrict__ bbase,
                                                      int2* __restrict__ sed, int E, int nbuck) {
  __shared__ int h[512];
  for (int b = threadIdx.x; b < nbuck; b += 256) h[b] = bbase[(long)b * NBLK + blockIdx.x];
  __syncthreads();
  int per = (E + NBLK - 1) / NBLK;
  int s = blockIdx.x * per;
  int e = min(s + per, E);
  for (int i = s + threadIdx.x; i < e; i += 256) {
    int d = dst[i];
    int pos = atomicAdd(&h[d >> 10], 1);
    sed[pos] = make_int2(d, src[i]);
  }
}

// ----- P3 fused: per-bucket node hist -> rs + isq, then LDS-rank CSR write -----
__global__ __launch_bounds__(256) void node_csr(const int2* __restrict__ sed,
                                                const int* __restrict__ bbase,
                                                int* __restrict__ rs, float* __restrict__ isq,
                                                int* __restrict__ csr, int E, int nbuck, int N) {
  __shared__ int h[1024];
  __shared__ int ws[256];
  __shared__ int cur[1024];
  int b = blockIdx.x;
  int n0 = b << 10;
  int nn = min(1024, N - n0);
  int t = threadIdx.x;
  for (int i = t; i < 1024; i += 256) h[i] = 0;
  __syncthreads();
  int s = bbase[(long)b * NBLK];
  int e = (b + 1 < nbuck) ? bbase[(long)(b + 1) * NBLK] : E;
  for (int i = s + t; i < e; i += 256) atomicAdd(&h[sed[i].x - n0], 1);
  __syncthreads();
  int v0 = h[4 * t], v1 = h[4 * t + 1], v2 = h[4 * t + 2], v3 = h[4 * t + 3];
  ws[t] = v0 + v1 + v2 + v3;
  __syncthreads();
  for (int off = 1; off < 256; off <<= 1) {
    int x = (t >= off) ? ws[t - off] : 0;
    __syncthreads();
    ws[t] += x;
    __syncthreads();
  }
  int run = s + ((t > 0) ? ws[t - 1] : 0);
  int i0 = 4 * t;
  cur[i0] = run;
  if (i0 < nn) { rs[n0 + i0] = run; isq[n0 + i0] = rsqrtf((float)(v0 + 1)); }
  run += v0;
  cur[i0 + 1] = run;
  if (i0 + 1 < nn) { rs[n0 + i0 + 1] = run; isq[n0 + i0 + 1] = rsqrtf((float)(v1 + 1)); }
  run += v1;
  cur[i0 + 2] = run;
  if (i0 + 2 < nn) { rs[n0 + i0 + 2] = run; isq[n0 + i0 + 2] = rsqrtf((float)(v2 + 1)); }
  run += v2;
  cur[i0 + 3] = run;
  if (i0 + 3 < nn) { rs[n0 + i0 + 3] = run; isq[n0 + i0 + 3] = rsqrtf((float)(v3 + 1)); }
  if (b == nbuck - 1 && t == 255) rs[N] = E;
  __syncthreads();
  // rank + write csr (contiguous region [s,e))
  for (int i = s + t; i < e; i += 256) {
    int2 v = sed[i];
    int pos = atomicAdd(&cur[v.x - n0], 1);
    csr[pos] = v.y;
  }
}

// ---------------- scale+cast: xs[n,:] = half(x[n,:] * isq[n]), half8 per thread -------------
__global__ __launch_bounds__(256) void scale_cast(const float* __restrict__ x,
                                                  const float* __restrict__ isq,
                                                  half_t* __restrict__ xs, long nocts) {
  long i = (long)blockIdx.x * 256 + threadIdx.x;
  if (i >= nocts) return;
  int node = (int)(i >> 3);
  float s = isq[node];
  float4 vlo = ((const float4*)x)[i * 2];
  float4 vhi = ((const float4*)x)[i * 2 + 1];
  half8 h;
  h[0] = (half_t)(vlo.x * s);
  h[1] = (half_t)(vlo.y * s);
  h[2] = (half_t)(vlo.z * s);
  h[3] = (half_t)(vlo.w * s);
  h[4] = (half_t)(vhi.x * s);
  h[5] = (half_t)(vhi.y * s);
  h[6] = (half_t)(vhi.z * s);
  h[7] = (half_t)(vhi.w * s);
  ((half8*)xs)[i] = h;
}

// ------- fused gather conv: agg = sum_{s in N(d)} xs[s] + xs[d]; y = agg @ W;
//         r = relu(y*isq[d] + b); out = half(scale_out ? r*isq[d] : r) -------
// Wave = 8 lane-groups of 8; lane covers 8 channels (16B half8 loads).
// 4-edge batching; pairwise fp16 pre-add (v_pk_add_f16) before f32 accumulate.
__global__ __launch_bounds__(256) void gather_fused(const half_t* __restrict__ xs,
                                                    const int* __restrict__ csr,
                                                    const int* __restrict__ rs,
                                                    const float* __restrict__ isq,
                                                    const float* __restrict__ W,
                                                    const float* __restrict__ bias,
                                                    half_t* __restrict__ out, int N,
                                                    int scale_out) {
  __shared__ float Wl[64 * 64];   // [k][c]
  __shared__ float ex[32][68];    // per-block 32 nodes' agg vecs (pad 68)
  int tid = threadIdx.x;
#pragma unroll
  for (int v = 0; v < 4; ++v) {
    int u = tid + v * 256;
    *(float4*)&Wl[u * 4] = *(const float4*)&W[u * 4];
  }
  __syncthreads();  // all waves reach this before any divergence/return

  int lane = tid & 63;
  int sub = lane & 7;    // channel octet: channels sub*8..sub*8+7
  int grp = lane >> 3;   // dst group within wave (0..7)
  int li = tid >> 3;     // local node index 0..31
  int wid = (blockIdx.x * blockDim.x + tid) >> 6;
  long d0 = (long)wid * 8;
  if (d0 >= N) return;
  int d = (int)d0 + grp;
  bool vd = d < N;
  int dd = vd ? d : N - 1;
  int jj = rs[dd];
  int je = vd ? rs[dd + 1] : jj;
  float id = isq[dd];
  float4 blo = *(const float4*)&bias[sub * 8];
  float4 bhi = *(const float4*)&bias[sub * 8 + 4];
  float ac[8];
  {
    half8 sv = *(const half8*)&xs[(long)dd * 64 + sub * 8];
#pragma unroll
    for (int c = 0; c < 8; ++c) ac[c] = (float)sv[c];
  }
  const half8 hz = {(half_t)0, (half_t)0, (half_t)0, (half_t)0,
                    (half_t)0, (half_t)0, (half_t)0, (half_t)0};
  while (__any(jj < je)) {
    bool a0 = jj < je;
    bool a1 = jj + 1 < je;
    bool a2 = jj + 2 < je;
    bool a3 = jj + 3 < je;
    int s0 = csr[jj];
    int s1 = csr[jj + 1];
    int s2 = csr[jj + 2];
    int s3 = csr[jj + 3];
    half8 v0 = hz, v1 = hz, v2 = hz, v3 = hz;
    if (a0) v0 = *(const half8*)&xs[(long)s0 * 64 + sub * 8];
    if (a1) v1 = *(const half8*)&xs[(long)s1 * 64 + sub * 8];
    if (a2) v2 = *(const half8*)&xs[(long)s2 * 64 + sub * 8];
    if (a3) v3 = *(const half8*)&xs[(long)s3 * 64 + sub * 8];
    half8 v01 = v0 + v1;  // v_pk_add_f16; adding fp16 zero is exact
    half8 v23 = v2 + v3;
#pragma unroll
    for (int c = 0; c < 8; ++c) ac[c] += (float)v01[c] + (float)v23[c];
    jj += 4;
  }
  // agg -> wave-local LDS exchange (same wave writes & reads; no barrier)
  *(float4*)&ex[li][sub * 8] = make_float4(ac[0], ac[1], ac[2], ac[3]);
  *(float4*)&ex[li][sub * 8 + 4] = make_float4(ac[4], ac[5], ac[6], ac[7]);
  // y = agg @ W: each lane computes channels sub*8..sub*8+7 for its group's node
  float4 ylo = make_float4(0.f, 0.f, 0.f, 0.f);
  float4 yhi = make_float4(0.f, 0.f, 0.f, 0.f);
#pragma unroll
  for (int k4 = 0; k4 < 16; ++k4) {
    float4 rv = *(const float4*)&ex[li][k4 * 4];
#pragma unroll
    for (int kk = 0; kk < 4; ++kk) {
      float a = (&rv.x)[kk];
      float4 w0 = *(const float4*)&Wl[(k4 * 4 + kk) * 64 + sub * 8];
      float4 w1 = *(const float4*)&Wl[(k4 * 4 + kk) * 64 + sub * 8 + 4];
      ylo.x = fmaf(a, w0.x, ylo.x);
      ylo.y = fmaf(a, w0.y, ylo.y);
      ylo.z = fmaf(a, w0.z, ylo.z);
      ylo.w = fmaf(a, w0.w, ylo.w);
      yhi.x = fmaf(a, w1.x, yhi.x);
      yhi.y = fmaf(a, w1.y, yhi.y);
      yhi.z = fmaf(a, w1.z, yhi.z);
      yhi.w = fmaf(a, w1.w, yhi.w);
    }
  }
  if (vd) {
    float m = scale_out ? id : 1.f;
    half8 hv;
    hv[0] = (half_t)(fmaxf(fmaf(ylo.x, id, blo.x), 0.f) * m);
    hv[1] = (half_t)(fmaxf(fmaf(ylo.y, id, blo.y), 0.f) * m);
    hv[2] = (half_t)(fmaxf(fmaf(ylo.z, id, blo.z), 0.f) * m);
    hv[3] = (half_t)(fmaxf(fmaf(ylo.w, id, blo.w), 0.f) * m);
    hv[4] = (half_t)(fmaxf(fmaf(yhi.x, id, bhi.x), 0.f) * m);
    hv[5] = (half_t)(fmaxf(fmaf(yhi.y, id, bhi.y), 0.f) * m);
    hv[6] = (half_t)(fmaxf(fmaf(yhi.z, id, bhi.z), 0.f) * m);
    hv[7] = (half_t)(fmaxf(fmaf(yhi.w, id, bhi.w), 0.f) * m);
    *(half8*)&out[(long)d * 64 + sub * 8] = hv;
  }
}

// ---------------- graph segment offsets from sorted batch_idx ----------------
__global__ void seg_offsets(const int* __restrict__ batch, int* __restrict__ off, int N, int G) {
  int i = blockIdx.x * blockDim.x + threadIdx.x;
  if (i >= N) return;
  int b = batch[i];
  if (i == 0) {
    for (int g = 0; g <= b; ++g) off[g] = 0;
  } else {
    int pb = batch[i - 1];
    for (int g = pb + 1; g <= b; ++g) off[g] = i;
  }
  if (i == N - 1) {
    for (int g = b + 1; g <= G; ++g) off[g] = N;
  }
}

// ------- mean pool over fp16 rows: lane = half8 (16B), 8 row-parities/wave -------
__global__ void pool_mean(const half_t* __restrict__ e2, const int* __restrict__ off,
                          float* __restrict__ ge, int G) {
  int lane = threadIdx.x & 63;
  int wid = (blockIdx.x * blockDim.x + threadIdx.x) >> 6;
  int nw = (gridDim.x * blockDim.x) >> 6;
  int c8 = lane & 7;   // channel octet
  int rp = lane >> 3;  // row parity 0..7
  for (int g = wid; g < G; g += nw) {
    int s = off[g];
    int e = off[g + 1];
    float acc[8];
#pragma unroll
    for (int c = 0; c < 8; ++c) acc[c] = 0.f;
    for (int n = s + rp; n < e; n += 8) {
      half8 v = *(const half8*)&e2[(long)n * 64 + c8 * 8];
#pragma unroll
      for (int c = 0; c < 8; ++c) acc[c] += (float)v[c];
    }
#pragma unroll
    for (int c = 0; c < 8; ++c) {
      acc[c] += __shfl_xor(acc[c], 8, 64);
      acc[c] += __shfl_xor(acc[c], 16, 64);
      acc[c] += __shfl_xor(acc[c], 32, 64);
    }
    if (rp == 0) {
      float inv = 1.f / fmaxf((float)(e - s), 1.f);
      float4 lo = make_float4(acc[0] * inv, acc[1] * inv, acc[2] * inv, acc[3] * inv);
      float4 hi = make_float4(acc[4] * inv, acc[5] * inv, acc[6] * inv, acc[7] * inv);
      *(float4*)&ge[(long)g * 64 + c8 * 8] = lo;
      *(float4*)&ge[(long)g * 64 + c8 * 8 + 4] = hi;
    }
  }
}

// ---------------- pair MLP: thread = 4 hidden x 16 pairs, PPB=64 ----------------
#define PPB 64
__global__ __launch_bounds__(256) void pair_mlp(const float* __restrict__ ge,
                                                const int* __restrict__ dp,
                                                const float* __restrict__ Wr1,
                                                const float* __restrict__ br1,
                                                const float* __restrict__ Wr2,
                                                const float* __restrict__ br2,
                                                float* __restrict__ out, int P) {
  __shared__ float feat[PPB][128];
  __shared__ int pidx[2][PPB];
  int tid = threadIdx.x;
  int base = blockIdx.x * PPB;
  if (tid < PPB) {
    int p = base + tid;
    pidx[0][tid] = (p < P) ? dp[p] : 0;
    pidx[1][tid] = (p < P) ? dp[P + p] : 0;
  }
  __syncthreads();
  // load 64 pairs x 128 feat = 2048 float4s, 8 per thread
#pragma unroll
  for (int i = 0; i < 8; ++i) {
    int u = tid + i * 256;   // float4 index
    int p = u >> 5;          // 32 float4 per pair row
    int k = (u & 31) * 4;    // feature index 0..124
    int g = (k < 64) ? pidx[0][p] : pidx[1][p];
    *(float4*)&feat[p][k] = *(const float4*)&ge[(long)g * 64 + (k & 63)];
  }
  __syncthreads();
  int jg = tid & 63;   // hidden group -> hidden units j0..j0+3
  int j0 = jg * 4;
  int pg = tid >> 6;   // pair quarter -> pairs pg*16..pg*16+15
  int pb = pg * 16;
  float acc[16][4];
#pragma unroll
  for (int p = 0; p < 16; ++p)
#pragma unroll
    for (int j = 0; j < 4; ++j) acc[p][j] = 0.f;
  for (int k4 = 0; k4 < 32; ++k4) {
    float4 w0 = *(const float4*)&Wr1[(k4 * 4 + 0) * 256 + j0];
    float4 w1 = *(const float4*)&Wr1[(k4 * 4 + 1) * 256 + j0];
    float4 w2 = *(const float4*)&Wr1[(k4 * 4 + 2) * 256 + j0];
    float4 w3 = *(const float4*)&Wr1[(k4 * 4 + 3) * 256 + j0];
#pragma unroll
    for (int p = 0; p < 16; ++p) {
      float4 f = *(const float4*)&feat[pb + p][k4 * 4];
      acc[p][0] = fmaf(f.x, w0.x, acc[p][0]);
      acc[p][1] = fmaf(f.x, w0.y, acc[p][1]);
      acc[p][2] = fmaf(f.x, w0.z, acc[p][2]);
      acc[p][3] = fmaf(f.x, w0.w, acc[p][3]);
      acc[p][0] = fmaf(f.y, w1.x, acc[p][0]);
      acc[p][1] = fmaf(f.y, w1.y, acc[p][1]);
      acc[p][2] = fmaf(f.y, w1.z, acc[p][2]);
      acc[p][3] = fmaf(f.y, w1.w, acc[p][3]);
      acc[p][0] = fmaf(f.z, w2.x, acc[p][0]);
      acc[p][1] = fmaf(f.z, w2.y, acc[p][1]);
      acc[p][2] = fmaf(f.z, w2.z, acc[p][2]);
      acc[p][3] = fmaf(f.z, w2.w, acc[p][3]);
      acc[p][0] = fmaf(f.w, w3.x, acc[p][0]);
      acc[p][1] = fmaf(f.w, w3.y, acc[p][1]);
      acc[p][2] = fmaf(f.w, w3.z, acc[p][2]);
      acc[p][3] = fmaf(f.w, w3.w, acc[p][3]);
    }
  }
  float4 b1v = *(const float4*)&br1[j0];
  float4 w2v = *(const float4*)&Wr2[j0];
  float br2v = br2[0];
#pragma unroll
  for (int p = 0; p < 16; ++p) {
    float v = fmaxf(acc[p][0] + b1v.x, 0.f) * w2v.x;
    v = fmaf(fmaxf(acc[p][1] + b1v.y, 0.f), w2v.y, v);
    v = fmaf(fmaxf(acc[p][2] + b1v.z, 0.f), w2v.z, v);
    v = fmaf(fmaxf(acc[p][3] + b1v.w, 0.f), w2v.w, v);
    // reduce across the 64 hidden-group lanes (one wave)
    for (int o = 32; o > 0; o >>= 1) v += __shfl_down(v, o, 64);
    if (jg == 0) {
      int pp = base + pb + p;
      if (pp < P) out[pp] = v + br2v;
    }
  }
}

extern "C" void kernel_launch(void* const* d_in, const int* in_sizes, int n_in,
                              void* d_out, int out_size, void* d_ws, size_t ws_size,
                              hipStream_t stream) {
  const float* x = (const float*)d_in[0];
  const int* ei = (const int*)d_in[1];
  const int* batch = (const int*)d_in[2];
  const int* dp = (const int*)d_in[3];
  const float* W1 = (const float*)d_in[4];
  const float* b1 = (const float*)d_in[5];
  const float* W2 = (const float*)d_in[6];
  const float* b2 = (const float*)d_in[7];
  const float* Wr1 = (const float*)d_in[8];
  const float* br1 = (const float*)d_in[9];
  const float* Wr2 = (const float*)d_in[10];
  const float* br2 = (const float*)d_in[11];
  float* out = (float*)d_out;

  int N = in_sizes[0] / 64;
  int E = in_sizes[1] / 2;
  int P = in_sizes[3] / 2;
  int G = N_GRAPHS;
  const int* src = ei;
  const int* dstp = ei + E;

  int nbuck = (N + 1023) >> 10;  // <= 512
  long M = (long)nbuck * NBLK;

  char* ws = (char*)d_ws;
  size_t o = 0;
  auto alloc = [&](size_t bytes) {
    void* p = ws + o;
    o += (bytes + 255) & ~(size_t)255;
    return p;
  };
  float* isq = (float*)alloc((size_t)N * 4);
  int* rs = (int*)alloc((size_t)(N + 1) * 4);
  int* bsum = (int*)alloc(1024 * 4);
  int* goff = (int*)alloc((size_t)(G + 1) * 4);
  int* bcnt = (int*)alloc((size_t)(M + 1) * 4);
  int2* sed = (int2*)alloc((size_t)E * 8);
  int* csr = (int*)alloc((size_t)(E + 32) * 4);  // pad: gather overruns ≤16 ints
  half_t* xs1 = (half_t*)alloc((size_t)N * 64 * 2);
  half_t* xs2 = (half_t*)alloc((size_t)N * 64 * 2);
  half_t* abuf = (half_t*)alloc((size_t)N * 64 * 2);
  float* ge = (float*)alloc((size_t)G * 64 * 4);

  // --- CSR build, atomic-free at global scope ---
  bucket_hist<<<NBLK, 256, 0, stream>>>(dstp, bcnt, E, nbuck);
  int nbA = (int)((M + SCAN_CHUNK - 1) / SCAN_CHUNK);
  scan1<<<nbA, 256, 0, stream>>>(bcnt, bcnt, bsum, (int)M);  // in-place exclusive scan
  scan2<<<1, 256, 0, stream>>>(bsum, nbA);
  scan3<<<(int)((M + 1 + 255) / 256), 256, 0, stream>>>(bcnt, bsum, (int)(M + 1));
  bucket_scatter<<<NBLK, 256, 0, stream>>>(src, dstp, bcnt, sed, E, nbuck);
  node_csr<<<nbuck, 256, 0, stream>>>(sed, bcnt, rs, isq, csr, E, nbuck, N);
  seg_offsets<<<(N + 255) / 256, 256, 0, stream>>>(batch, goff, N, G);

  long nocts = (long)N * 8;
  int gblocks = (N + 31) / 32;  // 4 waves/block, 8 dst/wave
  // xs1 = x * isq (fp16)
  scale_cast<<<(int)((nocts + 255) / 256), 256, 0, stream>>>(x, isq, xs1, nocts);
  // conv1: gather xs1, @W1 epilogue, out xs2 = relu1*isq (fp16)
  gather_fused<<<gblocks, 256, 0, stream>>>(xs1, csr, rs, isq, W1, b1, xs2, N, 1);
  // conv2: gather xs2, @W2 epilogue, out abuf = relu2 (fp16)
  gather_fused<<<gblocks, 256, 0, stream>>>(xs2, csr, rs, isq, W2, b2, abuf, N, 0);
  // pool
  pool_mean<<<2048, 256, 0, stream>>>(abuf, goff, ge, G);
  // pair MLP
  pair_mlp<<<(P + PPB - 1) / PPB, 256, 0, stream>>>(ge, dp, Wr1, br1, Wr2, br2, out, P);
}

// Round 16
// 354.285 us; speedup vs baseline: 2.0357x; 1.0395x over previous
//
#include <hip/hip_runtime.h>
#include <cstdint>

#define N_GRAPHS 20000
#define SCAN_CHUNK 2048
#define NBLK 512  // blocks for bucket hist/scatter

typedef _Float16 half_t;
typedef __attribute__((ext_vector_type(4))) _Float16 half4;
typedef __attribute__((ext_vector_type(8))) _Float16 half8;

// ---------------- prefix scan (exclusive) of in[M] -> out[M+1] ----------------
__global__ __launch_bounds__(256) void scan1(const int* __restrict__ in, int* __restrict__ out,
                                             int* __restrict__ bsum, int M) {
  __shared__ int lds[256];
  int t = threadIdx.x;
  int base = blockIdx.x * SCAN_CHUNK + t * 8;
  int v[8];
  int s = 0;
#pragma unroll
  for (int i = 0; i < 8; ++i) {
    v[i] = (base + i < M) ? in[base + i] : 0;
    s += v[i];
  }
  lds[t] = s;
  __syncthreads();
  for (int off = 1; off < 256; off <<= 1) {
    int x = (t >= off) ? lds[t - off] : 0;
    __syncthreads();
    lds[t] += x;
    __syncthreads();
  }
  if (t == 255) bsum[blockIdx.x] = lds[255];
  int run = (t > 0) ? lds[t - 1] : 0;
#pragma unroll
  for (int i = 0; i < 8; ++i) {
    if (base + i <= M) out[base + i] = run;
    run += v[i];
  }
}

__global__ __launch_bounds__(256) void scan2(int* __restrict__ bsum, int nb) {
  __shared__ int lds[256];
  int t = threadIdx.x;
  lds[t] = (t < nb) ? bsum[t] : 0;
  __syncthreads();
  for (int off = 1; off < 256; off <<= 1) {
    int x = (t >= off) ? lds[t - off] : 0;
    __syncthreads();
    lds[t] += x;
    __syncthreads();
  }
  if (t < nb) bsum[t] = (t > 0) ? lds[t - 1] : 0;  // exclusive
}

__global__ void scan3(int* __restrict__ out, const int* __restrict__ bsum, int Mp1) {
  int i = blockIdx.x * blockDim.x + threadIdx.x;
  if (i < Mp1) out[i] += bsum[i / SCAN_CHUNK];
}

// ---------------- P1: per-block bucket histogram (bucket = dst >> 10) ----------------
__global__ __launch_bounds__(256) void bucket_hist(const int* __restrict__ dst,
                                                   int* __restrict__ bcnt, int E, int nbuck) {
  __shared__ int h[512];
  for (int i = threadIdx.x; i < 512; i += 256) h[i] = 0;
  __syncthreads();
  int per = (E + NBLK - 1) / NBLK;
  int s = blockIdx.x * per;
  int e = min(s + per, E);
  for (int i = s + threadIdx.x; i < e; i += 256) atomicAdd(&h[dst[i] >> 10], 1);
  __syncthreads();
  for (int b = threadIdx.x; b < nbuck; b += 256) bcnt[(long)b * NBLK + blockIdx.x] = h[b];
}

// ---------------- P2: scatter edges into bucket-ordered (dst,src) int2 array ----------------
__global__ __launch_bounds__(256) void bucket_scatter(const int* __restrict__ src,
                                                      const int* __restrict__ dst,
                                                      const int* __restrict__ bbase,
                                                      int2* __restrict__ sed, int E, int nbuck) {
  __shared__ int h[512];
  for (int b = threadIdx.x; b < nbuck; b += 256) h[b] = bbase[(long)b * NBLK + blockIdx.x];
  __syncthreads();
  int per = (E + NBLK - 1) / NBLK;
  int s = blockIdx.x * per;
  int e = min(s + per, E);
  for (int i = s + threadIdx.x; i < e; i += 256) {
    int d = dst[i];
    int pos = atomicAdd(&h[d >> 10], 1);
    sed[pos] = make_int2(d, src[i]);
  }
}

// ----- P3 fused: per-bucket node hist -> rsp (padded start/end) + isq, LDS-rank CSR write,
//       pad slots & sentinel region filled with node index N (zero row) -----
// Padded bucket base = bbase[b] + 3072*b (each bucket overallocated by 3*1024 slots).
__global__ __launch_bounds__(256) void node_csr(const int2* __restrict__ sed,
                                                const int* __restrict__ bbase,
                                                int2* __restrict__ rsp, float* __restrict__ isq,
                                                int* __restrict__ csr, int E, int nbuck, int N,
                                                int PARK) {
  __shared__ int h[1024];
  __shared__ int ws[256];
  __shared__ int cur[1024];
  int b = blockIdx.x;
  int n0 = b << 10;
  int nn = min(1024, N - n0);
  int t = threadIdx.x;
  for (int i = t; i < 1024; i += 256) h[i] = 0;
  __syncthreads();
  int s = bbase[(long)b * NBLK];
  int e = (b + 1 < nbuck) ? bbase[(long)(b + 1) * NBLK] : E;
  for (int i = s + t; i < e; i += 256) atomicAdd(&h[sed[i].x - n0], 1);
  __syncthreads();
  int v0 = h[4 * t], v1 = h[4 * t + 1], v2 = h[4 * t + 2], v3 = h[4 * t + 3];
  int p0 = (v0 + 3) & ~3, p1 = (v1 + 3) & ~3, p2 = (v2 + 3) & ~3, p3 = (v3 + 3) & ~3;
  ws[t] = p0 + p1 + p2 + p3;
  __syncthreads();
  for (int off = 1; off < 256; off <<= 1) {
    int x = (t >= off) ? ws[t - off] : 0;
    __syncthreads();
    ws[t] += x;
    __syncthreads();
  }
  int pbase = s + 3072 * b;
  int st0 = pbase + ((t > 0) ? ws[t - 1] : 0);
  int st1 = st0 + p0, st2 = st1 + p1, st3 = st2 + p2;
  int i0 = 4 * t;
  cur[i0] = st0;
  cur[i0 + 1] = st1;
  cur[i0 + 2] = st2;
  cur[i0 + 3] = st3;
  if (i0 < nn) { rsp[n0 + i0] = make_int2(st0, st0 + p0); isq[n0 + i0] = rsqrtf((float)(v0 + 1)); }
  if (i0 + 1 < nn) { rsp[n0 + i0 + 1] = make_int2(st1, st1 + p1); isq[n0 + i0 + 1] = rsqrtf((float)(v1 + 1)); }
  if (i0 + 2 < nn) { rsp[n0 + i0 + 2] = make_int2(st2, st2 + p2); isq[n0 + i0 + 2] = rsqrtf((float)(v2 + 1)); }
  if (i0 + 3 < nn) { rsp[n0 + i0 + 3] = make_int2(st3, st3 + p3); isq[n0 + i0 + 3] = rsqrtf((float)(v3 + 1)); }
  __syncthreads();
  // rank + write csr
  for (int i = s + t; i < e; i += 256) {
    int2 v = sed[i];
    int pos = atomicAdd(&cur[v.x - n0], 1);
    csr[pos] = v.y;
  }
  __syncthreads();
  // fill pad slots with sentinel N (zero row)
  for (int j = v0; j < p0; ++j) csr[st0 + j] = N;
  for (int j = v1; j < p1; ++j) csr[st1 + j] = N;
  for (int j = v2; j < p2; ++j) csr[st2 + j] = N;
  for (int j = v3; j < p3; ++j) csr[st3 + j] = N;
  if (b == 0 && t < 64) csr[PARK + t] = N;  // parking region
}

// ---------------- scale+cast: xs[n,:] = half(x[n,:] * isq[n]), half8 per thread -------------
__global__ __launch_bounds__(256) void scale_cast(const float* __restrict__ x,
                                                  const float* __restrict__ isq,
                                                  half_t* __restrict__ xs, long nocts) {
  long i = (long)blockIdx.x * 256 + threadIdx.x;
  if (i >= nocts) return;
  int node = (int)(i >> 3);
  float s = isq[node];
  float4 vlo = ((const float4*)x)[i * 2];
  float4 vhi = ((const float4*)x)[i * 2 + 1];
  half8 h;
  h[0] = (half_t)(vlo.x * s);
  h[1] = (half_t)(vlo.y * s);
  h[2] = (half_t)(vlo.z * s);
  h[3] = (half_t)(vlo.w * s);
  h[4] = (half_t)(vhi.x * s);
  h[5] = (half_t)(vhi.y * s);
  h[6] = (half_t)(vhi.z * s);
  h[7] = (half_t)(vhi.w * s);
  ((half8*)xs)[i] = h;
}

// ------- fused gather conv: agg = sum_{s in N(d)} xs[s] + xs[d]; y = agg @ W;
//         r = relu(y*isq[d] + b); out = half(scale_out ? r*isq[d] : r) -------
// Guard-free inner loop: per-node padded CSR (pad -> row N, zeroed) + group parking.
__global__ __launch_bounds__(256) void gather_fused(const half_t* __restrict__ xs,
                                                    const int* __restrict__ csr,
                                                    const int2* __restrict__ rsp,
                                                    const float* __restrict__ isq,
                                                    const float* __restrict__ W,
                                                    const float* __restrict__ bias,
                                                    half_t* __restrict__ out, int N,
                                                    int PARK, int scale_out) {
  __shared__ float Wl[64 * 64];   // [k][c]
  __shared__ float ex[32][68];    // per-block 32 nodes' agg vecs (pad 68)
  int tid = threadIdx.x;
#pragma unroll
  for (int v = 0; v < 4; ++v) {
    int u = tid + v * 256;
    *(float4*)&Wl[u * 4] = *(const float4*)&W[u * 4];
  }
  __syncthreads();  // all waves reach this before any divergence/return

  int lane = tid & 63;
  int sub = lane & 7;    // channel octet: channels sub*8..sub*8+7
  int grp = lane >> 3;   // dst group within wave (0..7)
  int li = tid >> 3;     // local node index 0..31
  int wid = (blockIdx.x * blockDim.x + tid) >> 6;
  long d0 = (long)wid * 8;
  if (d0 >= N) return;
  int d = (int)d0 + grp;
  bool vd = d < N;
  int dd = vd ? d : N - 1;
  int2 rr = rsp[dd];
  int jj = rr.x;
  int je = rr.y;
  float id = isq[dd];
  float4 blo = *(const float4*)&bias[sub * 8];
  float4 bhi = *(const float4*)&bias[sub * 8 + 4];
  const uint8_t* xb = (const uint8_t*)xs;
  uint32_t co = (uint32_t)sub << 4;   // channel byte offset within row
  float ac[8];
  {
    half8 sv = *(const half8*)(xb + (((uint32_t)dd << 7) + co));
#pragma unroll
    for (int c = 0; c < 8; ++c) ac[c] = (float)sv[c];
  }
  jj = (jj < je) ? jj : PARK;
  while (__any(jj != PARK)) {
    int s0 = csr[jj];
    int s1 = csr[jj + 1];
    int s2 = csr[jj + 2];
    int s3 = csr[jj + 3];
    half8 v0 = *(const half8*)(xb + (((uint32_t)s0 << 7) + co));
    half8 v1 = *(const half8*)(xb + (((uint32_t)s1 << 7) + co));
    half8 v2 = *(const half8*)(xb + (((uint32_t)s2 << 7) + co));
    half8 v3 = *(const half8*)(xb + (((uint32_t)s3 << 7) + co));
    half8 v01 = v0 + v1;  // exact when one side is the zero row
    half8 v23 = v2 + v3;
#pragma unroll
    for (int c = 0; c < 8; ++c) ac[c] += (float)v01[c] + (float)v23[c];
    jj += 4;
    jj = (jj < je) ? jj : PARK;
  }
  // agg -> wave-local LDS exchange (same wave writes & reads; no barrier)
  *(float4*)&ex[li][sub * 8] = make_float4(ac[0], ac[1], ac[2], ac[3]);
  *(float4*)&ex[li][sub * 8 + 4] = make_float4(ac[4], ac[5], ac[6], ac[7]);
  // y = agg @ W: each lane computes channels sub*8..sub*8+7 for its group's node
  float4 ylo = make_float4(0.f, 0.f, 0.f, 0.f);
  float4 yhi = make_float4(0.f, 0.f, 0.f, 0.f);
#pragma unroll
  for (int k4 = 0; k4 < 16; ++k4) {
    float4 rv = *(const float4*)&ex[li][k4 * 4];
#pragma unroll
    for (int kk = 0; kk < 4; ++kk) {
      float a = (&rv.x)[kk];
      float4 w0 = *(const float4*)&Wl[(k4 * 4 + kk) * 64 + sub * 8];
      float4 w1 = *(const float4*)&Wl[(k4 * 4 + kk) * 64 + sub * 8 + 4];
      ylo.x = fmaf(a, w0.x, ylo.x);
      ylo.y = fmaf(a, w0.y, ylo.y);
      ylo.z = fmaf(a, w0.z, ylo.z);
      ylo.w = fmaf(a, w0.w, ylo.w);
      yhi.x = fmaf(a, w1.x, yhi.x);
      yhi.y = fmaf(a, w1.y, yhi.y);
      yhi.z = fmaf(a, w1.z, yhi.z);
      yhi.w = fmaf(a, w1.w, yhi.w);
    }
  }
  if (vd) {
    float m = scale_out ? id : 1.f;
    half8 hv;
    hv[0] = (half_t)(fmaxf(fmaf(ylo.x, id, blo.x), 0.f) * m);
    hv[1] = (half_t)(fmaxf(fmaf(ylo.y, id, blo.y), 0.f) * m);
    hv[2] = (half_t)(fmaxf(fmaf(ylo.z, id, blo.z), 0.f) * m);
    hv[3] = (half_t)(fmaxf(fmaf(ylo.w, id, blo.w), 0.f) * m);
    hv[4] = (half_t)(fmaxf(fmaf(yhi.x, id, bhi.x), 0.f) * m);
    hv[5] = (half_t)(fmaxf(fmaf(yhi.y, id, bhi.y), 0.f) * m);
    hv[6] = (half_t)(fmaxf(fmaf(yhi.z, id, bhi.z), 0.f) * m);
    hv[7] = (half_t)(fmaxf(fmaf(yhi.w, id, bhi.w), 0.f) * m);
    *(half8*)&out[(long)d * 64 + sub * 8] = hv;
  }
}

// ---------------- graph segment offsets from sorted batch_idx ----------------
__global__ void seg_offsets(const int* __restrict__ batch, int* __restrict__ off, int N, int G) {
  int i = blockIdx.x * blockDim.x + threadIdx.x;
  if (i >= N) return;
  int b = batch[i];
  if (i == 0) {
    for (int g = 0; g <= b; ++g) off[g] = 0;
  } else {
    int pb = batch[i - 1];
    for (int g = pb + 1; g <= b; ++g) off[g] = i;
  }
  if (i == N - 1) {
    for (int g = b + 1; g <= G; ++g) off[g] = N;
  }
}

// ------- mean pool over fp16 rows: lane = half8 (16B), 8 row-parities/wave -------
__global__ void pool_mean(const half_t* __restrict__ e2, const int* __restrict__ off,
                          float* __restrict__ ge, int G) {
  int lane = threadIdx.x & 63;
  int wid = (blockIdx.x * blockDim.x + threadIdx.x) >> 6;
  int nw = (gridDim.x * blockDim.x) >> 6;
  int c8 = lane & 7;   // channel octet
  int rp = lane >> 3;  // row parity 0..7
  for (int g = wid; g < G; g += nw) {
    int s = off[g];
    int e = off[g + 1];
    float acc[8];
#pragma unroll
    for (int c = 0; c < 8; ++c) acc[c] = 0.f;
    for (int n = s + rp; n < e; n += 8) {
      half8 v = *(const half8*)&e2[(long)n * 64 + c8 * 8];
#pragma unroll
      for (int c = 0; c < 8; ++c) acc[c] += (float)v[c];
    }
#pragma unroll
    for (int c = 0; c < 8; ++c) {
      acc[c] += __shfl_xor(acc[c], 8, 64);
      acc[c] += __shfl_xor(acc[c], 16, 64);
      acc[c] += __shfl_xor(acc[c], 32, 64);
    }
    if (rp == 0) {
      float inv = 1.f / fmaxf((float)(e - s), 1.f);
      float4 lo = make_float4(acc[0] * inv, acc[1] * inv, acc[2] * inv, acc[3] * inv);
      float4 hi = make_float4(acc[4] * inv, acc[5] * inv, acc[6] * inv, acc[7] * inv);
      *(float4*)&ge[(long)g * 64 + c8 * 8] = lo;
      *(float4*)&ge[(long)g * 64 + c8 * 8 + 4] = hi;
    }
  }
}

// ---------------- pair MLP: thread = 4 hidden x 16 pairs, PPB=64 ----------------
#define PPB 64
__global__ __launch_bounds__(256) void pair_mlp(const float* __restrict__ ge,
                                                const int* __restrict__ dp,
                                                const float* __restrict__ Wr1,
                                                const float* __restrict__ br1,
                                                const float* __restrict__ Wr2,
                                                const float* __restrict__ br2,
                                                float* __restrict__ out, int P) {
  __shared__ float feat[PPB][128];
  __shared__ int pidx[2][PPB];
  int tid = threadIdx.x;
  int base = blockIdx.x * PPB;
  if (tid < PPB) {
    int p = base + tid;
    pidx[0][tid] = (p < P) ? dp[p] : 0;
    pidx[1][tid] = (p < P) ? dp[P + p] : 0;
  }
  __syncthreads();
#pragma unroll
  for (int i = 0; i < 8; ++i) {
    int u = tid + i * 256;   // float4 index
    int p = u >> 5;          // 32 float4 per pair row
    int k = (u & 31) * 4;    // feature index 0..124
    int g = (k < 64) ? pidx[0][p] : pidx[1][p];
    *(float4*)&feat[p][k] = *(const float4*)&ge[(long)g * 64 + (k & 63)];
  }
  __syncthreads();
  int jg = tid & 63;   // hidden group -> hidden units j0..j0+3
  int j0 = jg * 4;
  int pg = tid >> 6;   // pair quarter -> pairs pg*16..pg*16+15
  int pb = pg * 16;
  float acc[16][4];
#pragma unroll
  for (int p = 0; p < 16; ++p)
#pragma unroll
    for (int j = 0; j < 4; ++j) acc[p][j] = 0.f;
  for (int k4 = 0; k4 < 32; ++k4) {
    float4 w0 = *(const float4*)&Wr1[(k4 * 4 + 0) * 256 + j0];
    float4 w1 = *(const float4*)&Wr1[(k4 * 4 + 1) * 256 + j0];
    float4 w2 = *(const float4*)&Wr1[(k4 * 4 + 2) * 256 + j0];
    float4 w3 = *(const float4*)&Wr1[(k4 * 4 + 3) * 256 + j0];
#pragma unroll
    for (int p = 0; p < 16; ++p) {
      float4 f = *(const float4*)&feat[pb + p][k4 * 4];
      acc[p][0] = fmaf(f.x, w0.x, acc[p][0]);
      acc[p][1] = fmaf(f.x, w0.y, acc[p][1]);
      acc[p][2] = fmaf(f.x, w0.z, acc[p][2]);
      acc[p][3] = fmaf(f.x, w0.w, acc[p][3]);
      acc[p][0] = fmaf(f.y, w1.x, acc[p][0]);
      acc[p][1] = fmaf(f.y, w1.y, acc[p][1]);
      acc[p][2] = fmaf(f.y, w1.z, acc[p][2]);
      acc[p][3] = fmaf(f.y, w1.w, acc[p][3]);
      acc[p][0] = fmaf(f.z, w2.x, acc[p][0]);
      acc[p][1] = fmaf(f.z, w2.y, acc[p][1]);
      acc[p][2] = fmaf(f.z, w2.z, acc[p][2]);
      acc[p][3] = fmaf(f.z, w2.w, acc[p][3]);
      acc[p][0] = fmaf(f.w, w3.x, acc[p][0]);
      acc[p][1] = fmaf(f.w, w3.y, acc[p][1]);
      acc[p][2] = fmaf(f.w, w3.z, acc[p][2]);
      acc[p][3] = fmaf(f.w, w3.w, acc[p][3]);
    }
  }
  float4 b1v = *(const float4*)&br1[j0];
  float4 w2v = *(const float4*)&Wr2[j0];
  float br2v = br2[0];
#pragma unroll
  for (int p = 0; p < 16; ++p) {
    float v = fmaxf(acc[p][0] + b1v.x, 0.f) * w2v.x;
    v = fmaf(fmaxf(acc[p][1] + b1v.y, 0.f), w2v.y, v);
    v = fmaf(fmaxf(acc[p][2] + b1v.z, 0.f), w2v.z, v);
    v = fmaf(fmaxf(acc[p][3] + b1v.w, 0.f), w2v.w, v);
    for (int o = 32; o > 0; o >>= 1) v += __shfl_down(v, o, 64);
    if (jg == 0) {
      int pp = base + pb + p;
      if (pp < P) out[pp] = v + br2v;
    }
  }
}

extern "C" void kernel_launch(void* const* d_in, const int* in_sizes, int n_in,
                              void* d_out, int out_size, void* d_ws, size_t ws_size,
                              hipStream_t stream) {
  const float* x = (const float*)d_in[0];
  const int* ei = (const int*)d_in[1];
  const int* batch = (const int*)d_in[2];
  const int* dp = (const int*)d_in[3];
  const float* W1 = (const float*)d_in[4];
  const float* b1 = (const float*)d_in[5];
  const float* W2 = (const float*)d_in[6];
  const float* b2 = (const float*)d_in[7];
  const float* Wr1 = (const float*)d_in[8];
  const float* br1 = (const float*)d_in[9];
  const float* Wr2 = (const float*)d_in[10];
  const float* br2 = (const float*)d_in[11];
  float* out = (float*)d_out;

  int N = in_sizes[0] / 64;
  int E = in_sizes[1] / 2;
  int P = in_sizes[3] / 2;
  int G = N_GRAPHS;
  const int* src = ei;
  const int* dstp = ei + E;

  int nbuck = (N + 1023) >> 10;  // <= 512
  long M = (long)nbuck * NBLK;
  int PARK = E + 3072 * nbuck;   // start of parking region in padded csr space

  char* ws = (char*)d_ws;
  size_t o = 0;
  auto alloc = [&](size_t bytes) {
    void* p = ws + o;
    o += (bytes + 255) & ~(size_t)255;
    return p;
  };
  float* isq = (float*)alloc((size_t)N * 4);
  int2* rsp = (int2*)alloc((size_t)N * 8);
  int* bsum = (int*)alloc(1024 * 4);
  int* goff = (int*)alloc((size_t)(G + 1) * 4);
  int* bcnt = (int*)alloc((size_t)(M + 1) * 4);
  int2* sed = (int2*)alloc((size_t)E * 8);
  int* csr = (int*)alloc((size_t)(PARK + 80) * 4);
  half_t* xs1 = (half_t*)alloc((size_t)(N + 1) * 64 * 2);
  half_t* xs2 = (half_t*)alloc((size_t)(N + 1) * 64 * 2);
  half_t* abuf = (half_t*)alloc((size_t)N * 64 * 2);
  float* ge = (float*)alloc((size_t)G * 64 * 4);

  // zero sentinel rows (node index N)
  hipMemsetAsync(xs1 + (size_t)N * 64, 0, 64 * sizeof(half_t), stream);
  hipMemsetAsync(xs2 + (size_t)N * 64, 0, 64 * sizeof(half_t), stream);

  // --- CSR build, atomic-free at global scope ---
  bucket_hist<<<NBLK, 256, 0, stream>>>(dstp, bcnt, E, nbuck);
  int nbA = (int)((M + SCAN_CHUNK - 1) / SCAN_CHUNK);
  scan1<<<nbA, 256, 0, stream>>>(bcnt, bcnt, bsum, (int)M);  // in-place exclusive scan
  scan2<<<1, 256, 0, stream>>>(bsum, nbA);
  scan3<<<(int)((M + 1 + 255) / 256), 256, 0, stream>>>(bcnt, bsum, (int)(M + 1));
  bucket_scatter<<<NBLK, 256, 0, stream>>>(src, dstp, bcnt, sed, E, nbuck);
  node_csr<<<nbuck, 256, 0, stream>>>(sed, bcnt, rsp, isq, csr, E, nbuck, N, PARK);
  seg_offsets<<<(N + 255) / 256, 256, 0, stream>>>(batch, goff, N, G);

  long nocts = (long)N * 8;
  int gblocks = (N + 31) / 32;  // 4 waves/block, 8 dst/wave
  // xs1 = x * isq (fp16)
  scale_cast<<<(int)((nocts + 255) / 256), 256, 0, stream>>>(x, isq, xs1, nocts);
  // conv1: gather xs1, @W1 epilogue, out xs2 = relu1*isq (fp16)
  gather_fused<<<gblocks, 256, 0, stream>>>(xs1, csr, rsp, isq, W1, b1, xs2, N, PARK, 1);
  // conv2: gather xs2, @W2 epilogue, out abuf = relu2 (fp16)
  gather_fused<<<gblocks, 256, 0, stream>>>(xs2, csr, rsp, isq, W2, b2, abuf, N, PARK, 0);
  // pool
  pool_mean<<<2048, 256, 0, stream>>>(abuf, goff, ge, G);
  // pair MLP
  pair_mlp<<<(P + PPB - 1) / PPB, 256, 0, stream>>>(ge, dp, Wr1, br1, Wr2, br2, out, P);
}

// Round 17
// 345.408 us; speedup vs baseline: 2.0880x; 1.0257x over previous
//
#include <hip/hip_runtime.h>
#include <cstdint>

#define N_GRAPHS 20000
#define SCAN_CHUNK 2048
#define NBLK 512  // blocks for bucket hist/scatter
#define SRC_BITS 19  // N=500000 < 2^19; bucket-local dst uses 10 bits

typedef _Float16 half_t;
typedef __attribute__((ext_vector_type(4))) _Float16 half4;
typedef __attribute__((ext_vector_type(8))) _Float16 half8;

// ---------------- prefix scan (exclusive) of in[M] -> out[M+1] ----------------
__global__ __launch_bounds__(256) void scan1(const int* __restrict__ in, int* __restrict__ out,
                                             int* __restrict__ bsum, int M) {
  __shared__ int lds[256];
  int t = threadIdx.x;
  int base = blockIdx.x * SCAN_CHUNK + t * 8;
  int v[8];
  int s = 0;
#pragma unroll
  for (int i = 0; i < 8; ++i) {
    v[i] = (base + i < M) ? in[base + i] : 0;
    s += v[i];
  }
  lds[t] = s;
  __syncthreads();
  for (int off = 1; off < 256; off <<= 1) {
    int x = (t >= off) ? lds[t - off] : 0;
    __syncthreads();
    lds[t] += x;
    __syncthreads();
  }
  if (t == 255) bsum[blockIdx.x] = lds[255];
  int run = (t > 0) ? lds[t - 1] : 0;
#pragma unroll
  for (int i = 0; i < 8; ++i) {
    if (base + i <= M) out[base + i] = run;
    run += v[i];
  }
}

__global__ __launch_bounds__(256) void scan2(int* __restrict__ bsum, int nb) {
  __shared__ int lds[256];
  int t = threadIdx.x;
  lds[t] = (t < nb) ? bsum[t] : 0;
  __syncthreads();
  for (int off = 1; off < 256; off <<= 1) {
    int x = (t >= off) ? lds[t - off] : 0;
    __syncthreads();
    lds[t] += x;
    __syncthreads();
  }
  if (t < nb) bsum[t] = (t > 0) ? lds[t - 1] : 0;  // exclusive
}

__global__ void scan3(int* __restrict__ out, const int* __restrict__ bsum, int Mp1) {
  int i = blockIdx.x * blockDim.x + threadIdx.x;
  if (i < Mp1) out[i] += bsum[i / SCAN_CHUNK];
}

// ---------------- P1: per-block bucket histogram (bucket = dst >> 10) ----------------
__global__ __launch_bounds__(256) void bucket_hist(const int* __restrict__ dst,
                                                   int* __restrict__ bcnt, int E, int nbuck) {
  __shared__ int h[512];
  for (int i = threadIdx.x; i < 512; i += 256) h[i] = 0;
  __syncthreads();
  int per = (E + NBLK - 1) / NBLK;
  int s = blockIdx.x * per;
  int e = min(s + per, E);
  for (int i = s + threadIdx.x; i < e; i += 256) atomicAdd(&h[dst[i] >> 10], 1);
  __syncthreads();
  for (int b = threadIdx.x; b < nbuck; b += 256) bcnt[(long)b * NBLK + blockIdx.x] = h[b];
}

// ------- P2: scatter edges into bucket-ordered packed array: (dst&1023)<<19 | src -------
__global__ __launch_bounds__(256) void bucket_scatter(const int* __restrict__ src,
                                                      const int* __restrict__ dst,
                                                      const int* __restrict__ bbase,
                                                      int* __restrict__ sed, int E, int nbuck) {
  __shared__ int h[512];
  for (int b = threadIdx.x; b < nbuck; b += 256) h[b] = bbase[(long)b * NBLK + blockIdx.x];
  __syncthreads();
  int per = (E + NBLK - 1) / NBLK;
  int s = blockIdx.x * per;
  int e = min(s + per, E);
  for (int i = s + threadIdx.x; i < e; i += 256) {
    int d = dst[i];
    int pos = atomicAdd(&h[d >> 10], 1);
    sed[pos] = ((d & 1023) << SRC_BITS) | src[i];
  }
}

// ----- P3 fused: per-bucket node hist -> rsp (padded start/end) + isq, LDS-rank CSR write,
//       pad slots & sentinel region filled with node index N (zero row) -----
__global__ __launch_bounds__(256) void node_csr(const int* __restrict__ sed,
                                                const int* __restrict__ bbase,
                                                int2* __restrict__ rsp, float* __restrict__ isq,
                                                int* __restrict__ csr, int E, int nbuck, int N,
                                                int PARK) {
  __shared__ int h[1024];
  __shared__ int ws[256];
  __shared__ int cur[1024];
  int b = blockIdx.x;
  int n0 = b << 10;
  int nn = min(1024, N - n0);
  int t = threadIdx.x;
  for (int i = t; i < 1024; i += 256) h[i] = 0;
  __syncthreads();
  int s = bbase[(long)b * NBLK];
  int e = (b + 1 < nbuck) ? bbase[(long)(b + 1) * NBLK] : E;
  for (int i = s + t; i < e; i += 256) atomicAdd(&h[((unsigned)sed[i]) >> SRC_BITS], 1);
  __syncthreads();
  int v0 = h[4 * t], v1 = h[4 * t + 1], v2 = h[4 * t + 2], v3 = h[4 * t + 3];
  int p0 = (v0 + 3) & ~3, p1 = (v1 + 3) & ~3, p2 = (v2 + 3) & ~3, p3 = (v3 + 3) & ~3;
  ws[t] = p0 + p1 + p2 + p3;
  __syncthreads();
  for (int off = 1; off < 256; off <<= 1) {
    int x = (t >= off) ? ws[t - off] : 0;
    __syncthreads();
    ws[t] += x;
    __syncthreads();
  }
  int pbase = s + 3072 * b;
  int st0 = pbase + ((t > 0) ? ws[t - 1] : 0);
  int st1 = st0 + p0, st2 = st1 + p1, st3 = st2 + p2;
  int i0 = 4 * t;
  cur[i0] = st0;
  cur[i0 + 1] = st1;
  cur[i0 + 2] = st2;
  cur[i0 + 3] = st3;
  if (i0 < nn) { rsp[n0 + i0] = make_int2(st0, st0 + p0); isq[n0 + i0] = rsqrtf((float)(v0 + 1)); }
  if (i0 + 1 < nn) { rsp[n0 + i0 + 1] = make_int2(st1, st1 + p1); isq[n0 + i0 + 1] = rsqrtf((float)(v1 + 1)); }
  if (i0 + 2 < nn) { rsp[n0 + i0 + 2] = make_int2(st2, st2 + p2); isq[n0 + i0 + 2] = rsqrtf((float)(v2 + 1)); }
  if (i0 + 3 < nn) { rsp[n0 + i0 + 3] = make_int2(st3, st3 + p3); isq[n0 + i0 + 3] = rsqrtf((float)(v3 + 1)); }
  __syncthreads();
  // rank + write csr
  for (int i = s + t; i < e; i += 256) {
    int v = sed[i];
    int pos = atomicAdd(&cur[((unsigned)v) >> SRC_BITS], 1);
    csr[pos] = v & ((1 << SRC_BITS) - 1);
  }
  __syncthreads();
  // fill pad slots with sentinel N (zero row)
  for (int j = v0; j < p0; ++j) csr[st0 + j] = N;
  for (int j = v1; j < p1; ++j) csr[st1 + j] = N;
  for (int j = v2; j < p2; ++j) csr[st2 + j] = N;
  for (int j = v3; j < p3; ++j) csr[st3 + j] = N;
  if (b == 0 && t < 64) csr[PARK + t] = N;  // parking region
}

// ------- scale+cast: xs1[n,:] = half(x[n,:] * isq[n]); also zero sentinel rows -------
__global__ __launch_bounds__(256) void scale_cast(const float* __restrict__ x,
                                                  const float* __restrict__ isq,
                                                  half_t* __restrict__ xs1,
                                                  half_t* __restrict__ xs2,
                                                  long nocts, int N) {
  long i = (long)blockIdx.x * 256 + threadIdx.x;
  if (blockIdx.x == 0 && threadIdx.x < 16) {  // zero sentinel row N of both buffers
    const half8 z = {(half_t)0, (half_t)0, (half_t)0, (half_t)0,
                     (half_t)0, (half_t)0, (half_t)0, (half_t)0};
    half_t* base = (threadIdx.x < 8) ? xs1 : xs2;
    ((half8*)(base + (size_t)N * 64))[threadIdx.x & 7] = z;
  }
  if (i >= nocts) return;
  int node = (int)(i >> 3);
  float s = isq[node];
  float4 vlo = ((const float4*)x)[i * 2];
  float4 vhi = ((const float4*)x)[i * 2 + 1];
  half8 h;
  h[0] = (half_t)(vlo.x * s);
  h[1] = (half_t)(vlo.y * s);
  h[2] = (half_t)(vlo.z * s);
  h[3] = (half_t)(vlo.w * s);
  h[4] = (half_t)(vhi.x * s);
  h[5] = (half_t)(vhi.y * s);
  h[6] = (half_t)(vhi.z * s);
  h[7] = (half_t)(vhi.w * s);
  ((half8*)xs1)[i] = h;
}

// ------- fused gather conv: agg = sum_{s in N(d)} xs[s] + xs[d]; y = agg @ W;
//         r = relu(y*isq[d] + b); out = half(scale_out ? r*isq[d] : r) -------
// Guard-free loop (padded CSR + parking); fp16 pairwise tree (2 levels) then one
// 8-wide f32 convert+accumulate per batch.
__global__ __launch_bounds__(256) void gather_fused(const half_t* __restrict__ xs,
                                                    const int* __restrict__ csr,
                                                    const int2* __restrict__ rsp,
                                                    const float* __restrict__ isq,
                                                    const float* __restrict__ W,
                                                    const float* __restrict__ bias,
                                                    half_t* __restrict__ out, int N,
                                                    int PARK, int scale_out) {
  __shared__ float Wl[64 * 64];   // [k][c]
  __shared__ float ex[32][68];    // per-block 32 nodes' agg vecs (pad 68)
  int tid = threadIdx.x;
#pragma unroll
  for (int v = 0; v < 4; ++v) {
    int u = tid + v * 256;
    *(float4*)&Wl[u * 4] = *(const float4*)&W[u * 4];
  }
  __syncthreads();  // all waves reach this before any divergence/return

  int lane = tid & 63;
  int sub = lane & 7;    // channel octet: channels sub*8..sub*8+7
  int grp = lane >> 3;   // dst group within wave (0..7)
  int li = tid >> 3;     // local node index 0..31
  int wid = (blockIdx.x * blockDim.x + tid) >> 6;
  long d0 = (long)wid * 8;
  if (d0 >= N) return;
  int d = (int)d0 + grp;
  bool vd = d < N;
  int dd = vd ? d : N - 1;
  int2 rr = rsp[dd];
  int jj = rr.x;
  int je = rr.y;
  float id = isq[dd];
  float4 blo = *(const float4*)&bias[sub * 8];
  float4 bhi = *(const float4*)&bias[sub * 8 + 4];
  const uint8_t* xb = (const uint8_t*)xs;
  uint32_t co = (uint32_t)sub << 4;   // channel byte offset within row
  float ac[8];
  {
    half8 sv = *(const half8*)(xb + (((uint32_t)dd << 7) + co));
#pragma unroll
    for (int c = 0; c < 8; ++c) ac[c] = (float)sv[c];
  }
  jj = (jj < je) ? jj : PARK;
  while (__any(jj != PARK)) {
    int s0 = csr[jj];
    int s1 = csr[jj + 1];
    int s2 = csr[jj + 2];
    int s3 = csr[jj + 3];
    half8 v0 = *(const half8*)(xb + (((uint32_t)s0 << 7) + co));
    half8 v1 = *(const half8*)(xb + (((uint32_t)s1 << 7) + co));
    half8 v2 = *(const half8*)(xb + (((uint32_t)s2 << 7) + co));
    half8 v3 = *(const half8*)(xb + (((uint32_t)s3 << 7) + co));
    half8 sum = (v0 + v1) + (v2 + v3);  // fp16 tree; pads are exact zeros
#pragma unroll
    for (int c = 0; c < 8; ++c) ac[c] += (float)sum[c];
    jj += 4;
    jj = (jj < je) ? jj : PARK;
  }
  // agg -> wave-local LDS exchange (same wave writes & reads; no barrier)
  *(float4*)&ex[li][sub * 8] = make_float4(ac[0], ac[1], ac[2], ac[3]);
  *(float4*)&ex[li][sub * 8 + 4] = make_float4(ac[4], ac[5], ac[6], ac[7]);
  // y = agg @ W: each lane computes channels sub*8..sub*8+7 for its group's node
  float4 ylo = make_float4(0.f, 0.f, 0.f, 0.f);
  float4 yhi = make_float4(0.f, 0.f, 0.f, 0.f);
#pragma unroll
  for (int k4 = 0; k4 < 16; ++k4) {
    float4 rv = *(const float4*)&ex[li][k4 * 4];
#pragma unroll
    for (int kk = 0; kk < 4; ++kk) {
      float a = (&rv.x)[kk];
      float4 w0 = *(const float4*)&Wl[(k4 * 4 + kk) * 64 + sub * 8];
      float4 w1 = *(const float4*)&Wl[(k4 * 4 + kk) * 64 + sub * 8 + 4];
      ylo.x = fmaf(a, w0.x, ylo.x);
      ylo.y = fmaf(a, w0.y, ylo.y);
      ylo.z = fmaf(a, w0.z, ylo.z);
      ylo.w = fmaf(a, w0.w, ylo.w);
      yhi.x = fmaf(a, w1.x, yhi.x);
      yhi.y = fmaf(a, w1.y, yhi.y);
      yhi.z = fmaf(a, w1.z, yhi.z);
      yhi.w = fmaf(a, w1.w, yhi.w);
    }
  }
  if (vd) {
    float m = scale_out ? id : 1.f;
    half8 hv;
    hv[0] = (half_t)(fmaxf(fmaf(ylo.x, id, blo.x), 0.f) * m);
    hv[1] = (half_t)(fmaxf(fmaf(ylo.y, id, blo.y), 0.f) * m);
    hv[2] = (half_t)(fmaxf(fmaf(ylo.z, id, blo.z), 0.f) * m);
    hv[3] = (half_t)(fmaxf(fmaf(ylo.w, id, blo.w), 0.f) * m);
    hv[4] = (half_t)(fmaxf(fmaf(yhi.x, id, bhi.x), 0.f) * m);
    hv[5] = (half_t)(fmaxf(fmaf(yhi.y, id, bhi.y), 0.f) * m);
    hv[6] = (half_t)(fmaxf(fmaf(yhi.z, id, bhi.z), 0.f) * m);
    hv[7] = (half_t)(fmaxf(fmaf(yhi.w, id, bhi.w), 0.f) * m);
    *(half8*)&out[(long)d * 64 + sub * 8] = hv;
  }
}

// ---------------- graph segment offsets from sorted batch_idx ----------------
__global__ void seg_offsets(const int* __restrict__ batch, int* __restrict__ off, int N, int G) {
  int i = blockIdx.x * blockDim.x + threadIdx.x;
  if (i >= N) return;
  int b = batch[i];
  if (i == 0) {
    for (int g = 0; g <= b; ++g) off[g] = 0;
  } else {
    int pb = batch[i - 1];
    for (int g = pb + 1; g <= b; ++g) off[g] = i;
  }
  if (i == N - 1) {
    for (int g = b + 1; g <= G; ++g) off[g] = N;
  }
}

// ------- mean pool over fp16 rows: lane = half8 (16B), 8 row-parities/wave -------
__global__ void pool_mean(const half_t* __restrict__ e2, const int* __restrict__ off,
                          float* __restrict__ ge, int G) {
  int lane = threadIdx.x & 63;
  int wid = (blockIdx.x * blockDim.x + threadIdx.x) >> 6;
  int nw = (gridDim.x * blockDim.x) >> 6;
  int c8 = lane & 7;   // channel octet
  int rp = lane >> 3;  // row parity 0..7
  for (int g = wid; g < G; g += nw) {
    int s = off[g];
    int e = off[g + 1];
    float acc[8];
#pragma unroll
    for (int c = 0; c < 8; ++c) acc[c] = 0.f;
    for (int n = s + rp; n < e; n += 8) {
      half8 v = *(const half8*)&e2[(long)n * 64 + c8 * 8];
#pragma unroll
      for (int c = 0; c < 8; ++c) acc[c] += (float)v[c];
    }
#pragma unroll
    for (int c = 0; c < 8; ++c) {
      acc[c] += __shfl_xor(acc[c], 8, 64);
      acc[c] += __shfl_xor(acc[c], 16, 64);
      acc[c] += __shfl_xor(acc[c], 32, 64);
    }
    if (rp == 0) {
      float inv = 1.f / fmaxf((float)(e - s), 1.f);
      float4 lo = make_float4(acc[0] * inv, acc[1] * inv, acc[2] * inv, acc[3] * inv);
      float4 hi = make_float4(acc[4] * inv, acc[5] * inv, acc[6] * inv, acc[7] * inv);
      *(float4*)&ge[(long)g * 64 + c8 * 8] = lo;
      *(float4*)&ge[(long)g * 64 + c8 * 8 + 4] = hi;
    }
  }
}

// ---------------- pair MLP: thread = 4 hidden x 16 pairs, PPB=64 ----------------
#define PPB 64
__global__ __launch_bounds__(256) void pair_mlp(const float* __restrict__ ge,
                                                const int* __restrict__ dp,
                                                const float* __restrict__ Wr1,
                                                const float* __restrict__ br1,
                                                const float* __restrict__ Wr2,
                                                const float* __restrict__ br2,
                                                float* __restrict__ out, int P) {
  __shared__ float feat[PPB][128];
  __shared__ int pidx[2][PPB];
  int tid = threadIdx.x;
  int base = blockIdx.x * PPB;
  if (tid < PPB) {
    int p = base + tid;
    pidx[0][tid] = (p < P) ? dp[p] : 0;
    pidx[1][tid] = (p < P) ? dp[P + p] : 0;
  }
  __syncthreads();
#pragma unroll
  for (int i = 0; i < 8; ++i) {
    int u = tid + i * 256;   // float4 index
    int p = u >> 5;          // 32 float4 per pair row
    int k = (u & 31) * 4;    // feature index 0..124
    int g = (k < 64) ? pidx[0][p] : pidx[1][p];
    *(float4*)&feat[p][k] = *(const float4*)&ge[(long)g * 64 + (k & 63)];
  }
  __syncthreads();
  int jg = tid & 63;   // hidden group -> hidden units j0..j0+3
  int j0 = jg * 4;
  int pg = tid >> 6;   // pair quarter -> pairs pg*16..pg*16+15
  int pb = pg * 16;
  float acc[16][4];
#pragma unroll
  for (int p = 0; p < 16; ++p)
#pragma unroll
    for (int j = 0; j < 4; ++j) acc[p][j] = 0.f;
  for (int k4 = 0; k4 < 32; ++k4) {
    float4 w0 = *(const float4*)&Wr1[(k4 * 4 + 0) * 256 + j0];
    float4 w1 = *(const float4*)&Wr1[(k4 * 4 + 1) * 256 + j0];
    float4 w2 = *(const float4*)&Wr1[(k4 * 4 + 2) * 256 + j0];
    float4 w3 = *(const float4*)&Wr1[(k4 * 4 + 3) * 256 + j0];
#pragma unroll
    for (int p = 0; p < 16; ++p) {
      float4 f = *(const float4*)&feat[pb + p][k4 * 4];
      acc[p][0] = fmaf(f.x, w0.x, acc[p][0]);
      acc[p][1] = fmaf(f.x, w0.y, acc[p][1]);
      acc[p][2] = fmaf(f.x, w0.z, acc[p][2]);
      acc[p][3] = fmaf(f.x, w0.w, acc[p][3]);
      acc[p][0] = fmaf(f.y, w1.x, acc[p][0]);
      acc[p][1] = fmaf(f.y, w1.y, acc[p][1]);
      acc[p][2] = fmaf(f.y, w1.z, acc[p][2]);
      acc[p][3] = fmaf(f.y, w1.w, acc[p][3]);
      acc[p][0] = fmaf(f.z, w2.x, acc[p][0]);
      acc[p][1] = fmaf(f.z, w2.y, acc[p][1]);
      acc[p][2] = fmaf(f.z, w2.z, acc[p][2]);
      acc[p][3] = fmaf(f.z, w2.w, acc[p][3]);
      acc[p][0] = fmaf(f.w, w3.x, acc[p][0]);
      acc[p][1] = fmaf(f.w, w3.y, acc[p][1]);
      acc[p][2] = fmaf(f.w, w3.z, acc[p][2]);
      acc[p][3] = fmaf(f.w, w3.w, acc[p][3]);
    }
  }
  float4 b1v = *(const float4*)&br1[j0];
  float4 w2v = *(const float4*)&Wr2[j0];
  float br2v = br2[0];
#pragma unroll
  for (int p = 0; p < 16; ++p) {
    float v = fmaxf(acc[p][0] + b1v.x, 0.f) * w2v.x;
    v = fmaf(fmaxf(acc[p][1] + b1v.y, 0.f), w2v.y, v);
    v = fmaf(fmaxf(acc[p][2] + b1v.z, 0.f), w2v.z, v);
    v = fmaf(fmaxf(acc[p][3] + b1v.w, 0.f), w2v.w, v);
    for (int o = 32; o > 0; o >>= 1) v += __shfl_down(v, o, 64);
    if (jg == 0) {
      int pp = base + pb + p;
      if (pp < P) out[pp] = v + br2v;
    }
  }
}

extern "C" void kernel_launch(void* const* d_in, const int* in_sizes, int n_in,
                              void* d_out, int out_size, void* d_ws, size_t ws_size,
                              hipStream_t stream) {
  const float* x = (const float*)d_in[0];
  const int* ei = (const int*)d_in[1];
  const int* batch = (const int*)d_in[2];
  const int* dp = (const int*)d_in[3];
  const float* W1 = (const float*)d_in[4];
  const float* b1 = (const float*)d_in[5];
  const float* W2 = (const float*)d_in[6];
  const float* b2 = (const float*)d_in[7];
  const float* Wr1 = (const float*)d_in[8];
  const float* br1 = (const float*)d_in[9];
  const float* Wr2 = (const float*)d_in[10];
  const float* br2 = (const float*)d_in[11];
  float* out = (float*)d_out;

  int N = in_sizes[0] / 64;
  int E = in_sizes[1] / 2;
  int P = in_sizes[3] / 2;
  int G = N_GRAPHS;
  const int* src = ei;
  const int* dstp = ei + E;

  int nbuck = (N + 1023) >> 10;  // <= 512
  long M = (long)nbuck * NBLK;
  int PARK = E + 3072 * nbuck;   // start of parking region in padded csr space

  char* ws = (char*)d_ws;
  size_t o = 0;
  auto alloc = [&](size_t bytes) {
    void* p = ws + o;
    o += (bytes + 255) & ~(size_t)255;
    return p;
  };
  float* isq = (float*)alloc((size_t)N * 4);
  int2* rsp = (int2*)alloc((size_t)N * 8);
  int* bsum = (int*)alloc(1024 * 4);
  int* goff = (int*)alloc((size_t)(G + 1) * 4);
  int* bcnt = (int*)alloc((size_t)(M + 1) * 4);
  int* sed = (int*)alloc((size_t)E * 4);
  int* csr = (int*)alloc((size_t)(PARK + 80) * 4);
  half_t* xs1 = (half_t*)alloc((size_t)(N + 1) * 64 * 2);
  half_t* xs2 = (half_t*)alloc((size_t)(N + 1) * 64 * 2);
  half_t* abuf = (half_t*)alloc((size_t)N * 64 * 2);
  float* ge = (float*)alloc((size_t)G * 64 * 4);

  // --- CSR build, atomic-free at global scope ---
  bucket_hist<<<NBLK, 256, 0, stream>>>(dstp, bcnt, E, nbuck);
  int nbA = (int)((M + SCAN_CHUNK - 1) / SCAN_CHUNK);
  scan1<<<nbA, 256, 0, stream>>>(bcnt, bcnt, bsum, (int)M);  // in-place exclusive scan
  scan2<<<1, 256, 0, stream>>>(bsum, nbA);
  scan3<<<(int)((M + 1 + 255) / 256), 256, 0, stream>>>(bcnt, bsum, (int)(M + 1));
  bucket_scatter<<<NBLK, 256, 0, stream>>>(src, dstp, bcnt, sed, E, nbuck);
  node_csr<<<nbuck, 256, 0, stream>>>(sed, bcnt, rsp, isq, csr, E, nbuck, N, PARK);
  seg_offsets<<<(N + 255) / 256, 256, 0, stream>>>(batch, goff, N, G);

  long nocts = (long)N * 8;
  int gblocks = (N + 31) / 32;  // 4 waves/block, 8 dst/wave
  // xs1 = x * isq (fp16); also zeroes sentinel rows of xs1/xs2
  scale_cast<<<(int)((nocts + 255) / 256), 256, 0, stream>>>(x, isq, xs1, xs2, nocts, N);
  // conv1: gather xs1, @W1 epilogue, out xs2 = relu1*isq (fp16)
  gather_fused<<<gblocks, 256, 0, stream>>>(xs1, csr, rsp, isq, W1, b1, xs2, N, PARK, 1);
  // conv2: gather xs2, @W2 epilogue, out abuf = relu2 (fp16)
  gather_fused<<<gblocks, 256, 0, stream>>>(xs2, csr, rsp, isq, W2, b2, abuf, N, PARK, 0);
  // pool
  pool_mean<<<2048, 256, 0, stream>>>(abuf, goff, ge, G);
  // pair MLP
  pair_mlp<<<(P + PPB - 1) / PPB, 256, 0, stream>>>(ge, dp, Wr1, br1, Wr2, br2, out, P);
}

// Round 18
// 343.039 us; speedup vs baseline: 2.1024x; 1.0069x over previous
//
#include <hip/hip_runtime.h>
#include <cstdint>

#define N_GRAPHS 20000
#define SCAN_CHUNK 2048
#define NBLK 512  // blocks for bucket hist/scatter
#define SRC_BITS 19  // N=500000 < 2^19; bucket-local dst uses 10 bits

typedef _Float16 half_t;
typedef __attribute__((ext_vector_type(4))) _Float16 half4;
typedef __attribute__((ext_vector_type(8))) _Float16 half8;

// ---------------- prefix scan (exclusive) of in[M] -> out[M+1] ----------------
__global__ __launch_bounds__(256) void scan1(const int* __restrict__ in, int* __restrict__ out,
                                             int* __restrict__ bsum, int M) {
  __shared__ int lds[256];
  int t = threadIdx.x;
  int base = blockIdx.x * SCAN_CHUNK + t * 8;
  int v[8];
  int s = 0;
#pragma unroll
  for (int i = 0; i < 8; ++i) {
    v[i] = (base + i < M) ? in[base + i] : 0;
    s += v[i];
  }
  lds[t] = s;
  __syncthreads();
  for (int off = 1; off < 256; off <<= 1) {
    int x = (t >= off) ? lds[t - off] : 0;
    __syncthreads();
    lds[t] += x;
    __syncthreads();
  }
  if (t == 255) bsum[blockIdx.x] = lds[255];
  int run = (t > 0) ? lds[t - 1] : 0;
#pragma unroll
  for (int i = 0; i < 8; ++i) {
    if (base + i <= M) out[base + i] = run;
    run += v[i];
  }
}

__global__ __launch_bounds__(256) void scan2(int* __restrict__ bsum, int nb) {
  __shared__ int lds[256];
  int t = threadIdx.x;
  lds[t] = (t < nb) ? bsum[t] : 0;
  __syncthreads();
  for (int off = 1; off < 256; off <<= 1) {
    int x = (t >= off) ? lds[t - off] : 0;
    __syncthreads();
    lds[t] += x;
    __syncthreads();
  }
  if (t < nb) bsum[t] = (t > 0) ? lds[t - 1] : 0;  // exclusive
}

__global__ void scan3(int* __restrict__ out, const int* __restrict__ bsum, int Mp1) {
  int i = blockIdx.x * blockDim.x + threadIdx.x;
  if (i < Mp1) out[i] += bsum[i / SCAN_CHUNK];
}

// ---------------- P1: per-block bucket histogram (bucket = dst >> 10) ----------------
__global__ __launch_bounds__(256) void bucket_hist(const int* __restrict__ dst,
                                                   int* __restrict__ bcnt, int E, int nbuck) {
  __shared__ int h[512];
  for (int i = threadIdx.x; i < 512; i += 256) h[i] = 0;
  __syncthreads();
  int per = (E + NBLK - 1) / NBLK;
  int s = blockIdx.x * per;
  int e = min(s + per, E);
  for (int i = s + threadIdx.x; i < e; i += 256) atomicAdd(&h[dst[i] >> 10], 1);
  __syncthreads();
  for (int b = threadIdx.x; b < nbuck; b += 256) bcnt[(long)b * NBLK + blockIdx.x] = h[b];
}

// ------- P2: scatter edges into bucket-ordered packed array: (dst&1023)<<19 | src -------
__global__ __launch_bounds__(256) void bucket_scatter(const int* __restrict__ src,
                                                      const int* __restrict__ dst,
                                                      const int* __restrict__ bbase,
                                                      int* __restrict__ sed, int E, int nbuck) {
  __shared__ int h[512];
  for (int b = threadIdx.x; b < nbuck; b += 256) h[b] = bbase[(long)b * NBLK + blockIdx.x];
  __syncthreads();
  int per = (E + NBLK - 1) / NBLK;
  int s = blockIdx.x * per;
  int e = min(s + per, E);
  for (int i = s + threadIdx.x; i < e; i += 256) {
    int d = dst[i];
    int pos = atomicAdd(&h[d >> 10], 1);
    sed[pos] = ((d & 1023) << SRC_BITS) | src[i];
  }
}

// ----- P3 fused: per-bucket node hist -> rsp (padded start/end) + isq, LDS-rank CSR write,
//       pad slots & sentinel region filled with node index N (zero row) -----
__global__ __launch_bounds__(256) void node_csr(const int* __restrict__ sed,
                                                const int* __restrict__ bbase,
                                                int2* __restrict__ rsp, float* __restrict__ isq,
                                                int* __restrict__ csr, int E, int nbuck, int N,
                                                int PARK) {
  __shared__ int h[1024];
  __shared__ int ws[256];
  __shared__ int cur[1024];
  int b = blockIdx.x;
  int n0 = b << 10;
  int nn = min(1024, N - n0);
  int t = threadIdx.x;
  for (int i = t; i < 1024; i += 256) h[i] = 0;
  __syncthreads();
  int s = bbase[(long)b * NBLK];
  int e = (b + 1 < nbuck) ? bbase[(long)(b + 1) * NBLK] : E;
  for (int i = s + t; i < e; i += 256) atomicAdd(&h[((unsigned)sed[i]) >> SRC_BITS], 1);
  __syncthreads();
  int v0 = h[4 * t], v1 = h[4 * t + 1], v2 = h[4 * t + 2], v3 = h[4 * t + 3];
  int p0 = (v0 + 3) & ~3, p1 = (v1 + 3) & ~3, p2 = (v2 + 3) & ~3, p3 = (v3 + 3) & ~3;
  ws[t] = p0 + p1 + p2 + p3;
  __syncthreads();
  for (int off = 1; off < 256; off <<= 1) {
    int x = (t >= off) ? ws[t - off] : 0;
    __syncthreads();
    ws[t] += x;
    __syncthreads();
  }
  int pbase = s + 3072 * b;
  int st0 = pbase + ((t > 0) ? ws[t - 1] : 0);
  int st1 = st0 + p0, st2 = st1 + p1, st3 = st2 + p2;
  int i0 = 4 * t;
  cur[i0] = st0;
  cur[i0 + 1] = st1;
  cur[i0 + 2] = st2;
  cur[i0 + 3] = st3;
  if (i0 < nn) { rsp[n0 + i0] = make_int2(st0, st0 + p0); isq[n0 + i0] = rsqrtf((float)(v0 + 1)); }
  if (i0 + 1 < nn) { rsp[n0 + i0 + 1] = make_int2(st1, st1 + p1); isq[n0 + i0 + 1] = rsqrtf((float)(v1 + 1)); }
  if (i0 + 2 < nn) { rsp[n0 + i0 + 2] = make_int2(st2, st2 + p2); isq[n0 + i0 + 2] = rsqrtf((float)(v2 + 1)); }
  if (i0 + 3 < nn) { rsp[n0 + i0 + 3] = make_int2(st3, st3 + p3); isq[n0 + i0 + 3] = rsqrtf((float)(v3 + 1)); }
  __syncthreads();
  // rank + write csr
  for (int i = s + t; i < e; i += 256) {
    int v = sed[i];
    int pos = atomicAdd(&cur[((unsigned)v) >> SRC_BITS], 1);
    csr[pos] = v & ((1 << SRC_BITS) - 1);
  }
  __syncthreads();
  // fill pad slots with sentinel N (zero row)
  for (int j = v0; j < p0; ++j) csr[st0 + j] = N;
  for (int j = v1; j < p1; ++j) csr[st1 + j] = N;
  for (int j = v2; j < p2; ++j) csr[st2 + j] = N;
  for (int j = v3; j < p3; ++j) csr[st3 + j] = N;
  if (b == 0 && t < 64) csr[PARK + t] = N;  // parking region
}

// ------- scale+cast: xs1[n,:] = half(x[n,:] * isq[n]); also zero sentinel rows -------
__global__ __launch_bounds__(256) void scale_cast(const float* __restrict__ x,
                                                  const float* __restrict__ isq,
                                                  half_t* __restrict__ xs1,
                                                  half_t* __restrict__ xs2,
                                                  long nocts, int N) {
  long i = (long)blockIdx.x * 256 + threadIdx.x;
  if (blockIdx.x == 0 && threadIdx.x < 16) {  // zero sentinel row N of both buffers
    const half8 z = {(half_t)0, (half_t)0, (half_t)0, (half_t)0,
                     (half_t)0, (half_t)0, (half_t)0, (half_t)0};
    half_t* base = (threadIdx.x < 8) ? xs1 : xs2;
    ((half8*)(base + (size_t)N * 64))[threadIdx.x & 7] = z;
  }
  if (i >= nocts) return;
  int node = (int)(i >> 3);
  float s = isq[node];
  float4 vlo = ((const float4*)x)[i * 2];
  float4 vhi = ((const float4*)x)[i * 2 + 1];
  half8 h;
  h[0] = (half_t)(vlo.x * s);
  h[1] = (half_t)(vlo.y * s);
  h[2] = (half_t)(vlo.z * s);
  h[3] = (half_t)(vlo.w * s);
  h[4] = (half_t)(vhi.x * s);
  h[5] = (half_t)(vhi.y * s);
  h[6] = (half_t)(vhi.z * s);
  h[7] = (half_t)(vhi.w * s);
  ((half8*)xs1)[i] = h;
}

// ------- fused gather conv: agg = sum_{s in N(d)} xs[s] + xs[d]; y = agg @ W;
//         r = relu(y*isq[d] + b); out = half(scale_out ? r*isq[d] : r) -------
// Guard-free loop (padded CSR + parking). W staged in LDS as fp16 (8KB) so
// total LDS ~16.7KB -> 8 blocks/CU (full 32-wave occupancy) for latency hiding.
__global__ __launch_bounds__(256) void gather_fused(const half_t* __restrict__ xs,
                                                    const int* __restrict__ csr,
                                                    const int2* __restrict__ rsp,
                                                    const float* __restrict__ isq,
                                                    const float* __restrict__ W,
                                                    const float* __restrict__ bias,
                                                    half_t* __restrict__ out, int N,
                                                    int PARK, int scale_out) {
  __shared__ half_t Wl[64 * 64];  // [k][c] fp16 (8KB)
  __shared__ float ex[32][68];    // per-block 32 nodes' agg vecs (pad 68)
  int tid = threadIdx.x;
  // stage W -> fp16 LDS: each thread converts 16 elements
  {
    int u = tid * 16;
    float4 a0 = *(const float4*)&W[u];
    float4 a1 = *(const float4*)&W[u + 4];
    float4 a2 = *(const float4*)&W[u + 8];
    float4 a3 = *(const float4*)&W[u + 12];
    half8 h0, h1;
    h0[0] = (half_t)a0.x; h0[1] = (half_t)a0.y; h0[2] = (half_t)a0.z; h0[3] = (half_t)a0.w;
    h0[4] = (half_t)a1.x; h0[5] = (half_t)a1.y; h0[6] = (half_t)a1.z; h0[7] = (half_t)a1.w;
    h1[0] = (half_t)a2.x; h1[1] = (half_t)a2.y; h1[2] = (half_t)a2.z; h1[3] = (half_t)a2.w;
    h1[4] = (half_t)a3.x; h1[5] = (half_t)a3.y; h1[6] = (half_t)a3.z; h1[7] = (half_t)a3.w;
    *(half8*)&Wl[u] = h0;
    *(half8*)&Wl[u + 8] = h1;
  }
  __syncthreads();  // all waves reach this before any divergence/return

  int lane = tid & 63;
  int sub = lane & 7;    // channel octet: channels sub*8..sub*8+7
  int grp = lane >> 3;   // dst group within wave (0..7)
  int li = tid >> 3;     // local node index 0..31
  int wid = (blockIdx.x * blockDim.x + tid) >> 6;
  long d0 = (long)wid * 8;
  if (d0 >= N) return;
  int d = (int)d0 + grp;
  bool vd = d < N;
  int dd = vd ? d : N - 1;
  int2 rr = rsp[dd];
  int jj = rr.x;
  int je = rr.y;
  float id = isq[dd];
  float4 blo = *(const float4*)&bias[sub * 8];
  float4 bhi = *(const float4*)&bias[sub * 8 + 4];
  const uint8_t* xb = (const uint8_t*)xs;
  uint32_t co = (uint32_t)sub << 4;   // channel byte offset within row
  float ac[8];
  {
    half8 sv = *(const half8*)(xb + (((uint32_t)dd << 7) + co));
#pragma unroll
    for (int c = 0; c < 8; ++c) ac[c] = (float)sv[c];
  }
  jj = (jj < je) ? jj : PARK;
  while (__any(jj != PARK)) {
    int s0 = csr[jj];
    int s1 = csr[jj + 1];
    int s2 = csr[jj + 2];
    int s3 = csr[jj + 3];
    half8 v0 = *(const half8*)(xb + (((uint32_t)s0 << 7) + co));
    half8 v1 = *(const half8*)(xb + (((uint32_t)s1 << 7) + co));
    half8 v2 = *(const half8*)(xb + (((uint32_t)s2 << 7) + co));
    half8 v3 = *(const half8*)(xb + (((uint32_t)s3 << 7) + co));
    half8 sum = (v0 + v1) + (v2 + v3);  // fp16 tree; pads are exact zeros
#pragma unroll
    for (int c = 0; c < 8; ++c) ac[c] += (float)sum[c];
    jj += 4;
    jj = (jj < je) ? jj : PARK;
  }
  // agg -> wave-local LDS exchange (same wave writes & reads; no barrier)
  *(float4*)&ex[li][sub * 8] = make_float4(ac[0], ac[1], ac[2], ac[3]);
  *(float4*)&ex[li][sub * 8 + 4] = make_float4(ac[4], ac[5], ac[6], ac[7]);
  // y = agg @ W: each lane computes channels sub*8..sub*8+7 for its group's node
  float y[8];
#pragma unroll
  for (int c = 0; c < 8; ++c) y[c] = 0.f;
#pragma unroll
  for (int k4 = 0; k4 < 16; ++k4) {
    float4 rv = *(const float4*)&ex[li][k4 * 4];
#pragma unroll
    for (int kk = 0; kk < 4; ++kk) {
      float a = (&rv.x)[kk];
      half8 wh = *(const half8*)&Wl[(k4 * 4 + kk) * 64 + sub * 8];
#pragma unroll
      for (int c = 0; c < 8; ++c) y[c] = fmaf(a, (float)wh[c], y[c]);
    }
  }
  if (vd) {
    float m = scale_out ? id : 1.f;
    half8 hv;
    hv[0] = (half_t)(fmaxf(fmaf(y[0], id, blo.x), 0.f) * m);
    hv[1] = (half_t)(fmaxf(fmaf(y[1], id, blo.y), 0.f) * m);
    hv[2] = (half_t)(fmaxf(fmaf(y[2], id, blo.z), 0.f) * m);
    hv[3] = (half_t)(fmaxf(fmaf(y[3], id, blo.w), 0.f) * m);
    hv[4] = (half_t)(fmaxf(fmaf(y[4], id, bhi.x), 0.f) * m);
    hv[5] = (half_t)(fmaxf(fmaf(y[5], id, bhi.y), 0.f) * m);
    hv[6] = (half_t)(fmaxf(fmaf(y[6], id, bhi.z), 0.f) * m);
    hv[7] = (half_t)(fmaxf(fmaf(y[7], id, bhi.w), 0.f) * m);
    *(half8*)&out[(long)d * 64 + sub * 8] = hv;
  }
}

// ---------------- graph segment offsets from sorted batch_idx ----------------
__global__ void seg_offsets(const int* __restrict__ batch, int* __restrict__ off, int N, int G) {
  int i = blockIdx.x * blockDim.x + threadIdx.x;
  if (i >= N) return;
  int b = batch[i];
  if (i == 0) {
    for (int g = 0; g <= b; ++g) off[g] = 0;
  } else {
    int pb = batch[i - 1];
    for (int g = pb + 1; g <= b; ++g) off[g] = i;
  }
  if (i == N - 1) {
    for (int g = b + 1; g <= G; ++g) off[g] = N;
  }
}

// ------- mean pool over fp16 rows: lane = half8 (16B), 8 row-parities/wave -------
__global__ void pool_mean(const half_t* __restrict__ e2, const int* __restrict__ off,
                          float* __restrict__ ge, int G) {
  int lane = threadIdx.x & 63;
  int wid = (blockIdx.x * blockDim.x + threadIdx.x) >> 6;
  int nw = (gridDim.x * blockDim.x) >> 6;
  int c8 = lane & 7;   // channel octet
  int rp = lane >> 3;  // row parity 0..7
  for (int g = wid; g < G; g += nw) {
    int s = off[g];
    int e = off[g + 1];
    float acc[8];
#pragma unroll
    for (int c = 0; c < 8; ++c) acc[c] = 0.f;
    for (int n = s + rp; n < e; n += 8) {
      half8 v = *(const half8*)&e2[(long)n * 64 + c8 * 8];
#pragma unroll
      for (int c = 0; c < 8; ++c) acc[c] += (float)v[c];
    }
#pragma unroll
    for (int c = 0; c < 8; ++c) {
      acc[c] += __shfl_xor(acc[c], 8, 64);
      acc[c] += __shfl_xor(acc[c], 16, 64);
      acc[c] += __shfl_xor(acc[c], 32, 64);
    }
    if (rp == 0) {
      float inv = 1.f / fmaxf((float)(e - s), 1.f);
      float4 lo = make_float4(acc[0] * inv, acc[1] * inv, acc[2] * inv, acc[3] * inv);
      float4 hi = make_float4(acc[4] * inv, acc[5] * inv, acc[6] * inv, acc[7] * inv);
      *(float4*)&ge[(long)g * 64 + c8 * 8] = lo;
      *(float4*)&ge[(long)g * 64 + c8 * 8 + 4] = hi;
    }
  }
}

// ---------------- pair MLP: thread = 4 hidden x 16 pairs, PPB=64 ----------------
#define PPB 64
__global__ __launch_bounds__(256) void pair_mlp(const float* __restrict__ ge,
                                                const int* __restrict__ dp,
                                                const float* __restrict__ Wr1,
                                                const float* __restrict__ br1,
                                                const float* __restrict__ Wr2,
                                                const float* __restrict__ br2,
                                                float* __restrict__ out, int P) {
  __shared__ float feat[PPB][128];
  __shared__ int pidx[2][PPB];
  int tid = threadIdx.x;
  int base = blockIdx.x * PPB;
  if (tid < PPB) {
    int p = base + tid;
    pidx[0][tid] = (p < P) ? dp[p] : 0;
    pidx[1][tid] = (p < P) ? dp[P + p] : 0;
  }
  __syncthreads();
#pragma unroll
  for (int i = 0; i < 8; ++i) {
    int u = tid + i * 256;   // float4 index
    int p = u >> 5;          // 32 float4 per pair row
    int k = (u & 31) * 4;    // feature index 0..124
    int g = (k < 64) ? pidx[0][p] : pidx[1][p];
    *(float4*)&feat[p][k] = *(const float4*)&ge[(long)g * 64 + (k & 63)];
  }
  __syncthreads();
  int jg = tid & 63;   // hidden group -> hidden units j0..j0+3
  int j0 = jg * 4;
  int pg = tid >> 6;   // pair quarter -> pairs pg*16..pg*16+15
  int pb = pg * 16;
  float acc[16][4];
#pragma unroll
  for (int p = 0; p < 16; ++p)
#pragma unroll
    for (int j = 0; j < 4; ++j) acc[p][j] = 0.f;
  for (int k4 = 0; k4 < 32; ++k4) {
    float4 w0 = *(const float4*)&Wr1[(k4 * 4 + 0) * 256 + j0];
    float4 w1 = *(const float4*)&Wr1[(k4 * 4 + 1) * 256 + j0];
    float4 w2 = *(const float4*)&Wr1[(k4 * 4 + 2) * 256 + j0];
    float4 w3 = *(const float4*)&Wr1[(k4 * 4 + 3) * 256 + j0];
#pragma unroll
    for (int p = 0; p < 16; ++p) {
      float4 f = *(const float4*)&feat[pb + p][k4 * 4];
      acc[p][0] = fmaf(f.x, w0.x, acc[p][0]);
      acc[p][1] = fmaf(f.x, w0.y, acc[p][1]);
      acc[p][2] = fmaf(f.x, w0.z, acc[p][2]);
      acc[p][3] = fmaf(f.x, w0.w, acc[p][3]);
      acc[p][0] = fmaf(f.y, w1.x, acc[p][0]);
      acc[p][1] = fmaf(f.y, w1.y, acc[p][1]);
      acc[p][2] = fmaf(f.y, w1.z, acc[p][2]);
      acc[p][3] = fmaf(f.y, w1.w, acc[p][3]);
      acc[p][0] = fmaf(f.z, w2.x, acc[p][0]);
      acc[p][1] = fmaf(f.z, w2.y, acc[p][1]);
      acc[p][2] = fmaf(f.z, w2.z, acc[p][2]);
      acc[p][3] = fmaf(f.z, w2.w, acc[p][3]);
      acc[p][0] = fmaf(f.w, w3.x, acc[p][0]);
      acc[p][1] = fmaf(f.w, w3.y, acc[p][1]);
      acc[p][2] = fmaf(f.w, w3.z, acc[p][2]);
      acc[p][3] = fmaf(f.w, w3.w, acc[p][3]);
    }
  }
  float4 b1v = *(const float4*)&br1[j0];
  float4 w2v = *(const float4*)&Wr2[j0];
  float br2v = br2[0];
#pragma unroll
  for (int p = 0; p < 16; ++p) {
    float v = fmaxf(acc[p][0] + b1v.x, 0.f) * w2v.x;
    v = fmaf(fmaxf(acc[p][1] + b1v.y, 0.f), w2v.y, v);
    v = fmaf(fmaxf(acc[p][2] + b1v.z, 0.f), w2v.z, v);
    v = fmaf(fmaxf(acc[p][3] + b1v.w, 0.f), w2v.w, v);
    for (int o = 32; o > 0; o >>= 1) v += __shfl_down(v, o, 64);
    if (jg == 0) {
      int pp = base + pb + p;
      if (pp < P) out[pp] = v + br2v;
    }
  }
}

extern "C" void kernel_launch(void* const* d_in, const int* in_sizes, int n_in,
                              void* d_out, int out_size, void* d_ws, size_t ws_size,
                              hipStream_t stream) {
  const float* x = (const float*)d_in[0];
  const int* ei = (const int*)d_in[1];
  const int* batch = (const int*)d_in[2];
  const int* dp = (const int*)d_in[3];
  const float* W1 = (const float*)d_in[4];
  const float* b1 = (const float*)d_in[5];
  const float* W2 = (const float*)d_in[6];
  const float* b2 = (const float*)d_in[7];
  const float* Wr1 = (const float*)d_in[8];
  const float* br1 = (const float*)d_in[9];
  const float* Wr2 = (const float*)d_in[10];
  const float* br2 = (const float*)d_in[11];
  float* out = (float*)d_out;

  int N = in_sizes[0] / 64;
  int E = in_sizes[1] / 2;
  int P = in_sizes[3] / 2;
  int G = N_GRAPHS;
  const int* src = ei;
  const int* dstp = ei + E;

  int nbuck = (N + 1023) >> 10;  // <= 512
  long M = (long)nbuck * NBLK;
  int PARK = E + 3072 * nbuck;   // start of parking region in padded csr space

  char* ws = (char*)d_ws;
  size_t o = 0;
  auto alloc = [&](size_t bytes) {
    void* p = ws + o;
    o += (bytes + 255) & ~(size_t)255;
    return p;
  };
  float* isq = (float*)alloc((size_t)N * 4);
  int2* rsp = (int2*)alloc((size_t)N * 8);
  int* bsum = (int*)alloc(1024 * 4);
  int* goff = (int*)alloc((size_t)(G + 1) * 4);
  int* bcnt = (int*)alloc((size_t)(M + 1) * 4);
  int* sed = (int*)alloc((size_t)E * 4);
  int* csr = (int*)alloc((size_t)(PARK + 80) * 4);
  half_t* xs1 = (half_t*)alloc((size_t)(N + 1) * 64 * 2);
  half_t* xs2 = (half_t*)alloc((size_t)(N + 1) * 64 * 2);
  half_t* abuf = (half_t*)alloc((size_t)N * 64 * 2);
  float* ge = (float*)alloc((size_t)G * 64 * 4);

  // --- CSR build, atomic-free at global scope ---
  bucket_hist<<<NBLK, 256, 0, stream>>>(dstp, bcnt, E, nbuck);
  int nbA = (int)((M + SCAN_CHUNK - 1) / SCAN_CHUNK);
  scan1<<<nbA, 256, 0, stream>>>(bcnt, bcnt, bsum, (int)M);  // in-place exclusive scan
  scan2<<<1, 256, 0, stream>>>(bsum, nbA);
  scan3<<<(int)((M + 1 + 255) / 256), 256, 0, stream>>>(bcnt, bsum, (int)(M + 1));
  bucket_scatter<<<NBLK, 256, 0, stream>>>(src, dstp, bcnt, sed, E, nbuck);
  node_csr<<<nbuck, 256, 0, stream>>>(sed, bcnt, rsp, isq, csr, E, nbuck, N, PARK);
  seg_offsets<<<(N + 255) / 256, 256, 0, stream>>>(batch, goff, N, G);

  long nocts = (long)N * 8;
  int gblocks = (N + 31) / 32;  // 4 waves/block, 8 dst/wave
  // xs1 = x * isq (fp16); also zeroes sentinel rows of xs1/xs2
  scale_cast<<<(int)((nocts + 255) / 256), 256, 0, stream>>>(x, isq, xs1, xs2, nocts, N);
  // conv1: gather xs1, @W1 epilogue, out xs2 = relu1*isq (fp16)
  gather_fused<<<gblocks, 256, 0, stream>>>(xs1, csr, rsp, isq, W1, b1, xs2, N, PARK, 1);
  // conv2: gather xs2, @W2 epilogue, out abuf = relu2 (fp16)
  gather_fused<<<gblocks, 256, 0, stream>>>(xs2, csr, rsp, isq, W2, b2, abuf, N, PARK, 0);
  // pool
  pool_mean<<<2048, 256, 0, stream>>>(abuf, goff, ge, G);
  // pair MLP
  pair_mlp<<<(P + PPB - 1) / PPB, 256, 0, stream>>>(ge, dp, Wr1, br1, Wr2, br2, out, P);
}

// Round 19
// 309.871 us; speedup vs baseline: 2.3274x; 1.1070x over previous
//
#include <hip/hip_runtime.h>
#include <cstdint>

#define N_GRAPHS 20000
#define SCAN_CHUNK 2048
#define NBLK 512  // blocks for bucket hist/scatter
#define SRC_BITS 19  // N=500000 < 2^19; bucket-local dst uses 10 bits

typedef _Float16 half_t;
typedef __attribute__((ext_vector_type(4))) _Float16 half4;
typedef __attribute__((ext_vector_type(8))) _Float16 half8;
typedef __attribute__((ext_vector_type(4))) float f32x4;

// ---------------- prefix scan (exclusive) of in[M] -> out[M+1] ----------------
__global__ __launch_bounds__(256) void scan1(const int* __restrict__ in, int* __restrict__ out,
                                             int* __restrict__ bsum, int M) {
  __shared__ int lds[256];
  int t = threadIdx.x;
  int base = blockIdx.x * SCAN_CHUNK + t * 8;
  int v[8];
  int s = 0;
#pragma unroll
  for (int i = 0; i < 8; ++i) {
    v[i] = (base + i < M) ? in[base + i] : 0;
    s += v[i];
  }
  lds[t] = s;
  __syncthreads();
  for (int off = 1; off < 256; off <<= 1) {
    int x = (t >= off) ? lds[t - off] : 0;
    __syncthreads();
    lds[t] += x;
    __syncthreads();
  }
  if (t == 255) bsum[blockIdx.x] = lds[255];
  int run = (t > 0) ? lds[t - 1] : 0;
#pragma unroll
  for (int i = 0; i < 8; ++i) {
    if (base + i <= M) out[base + i] = run;
    run += v[i];
  }
}

__global__ __launch_bounds__(256) void scan2(int* __restrict__ bsum, int nb) {
  __shared__ int lds[256];
  int t = threadIdx.x;
  lds[t] = (t < nb) ? bsum[t] : 0;
  __syncthreads();
  for (int off = 1; off < 256; off <<= 1) {
    int x = (t >= off) ? lds[t - off] : 0;
    __syncthreads();
    lds[t] += x;
    __syncthreads();
  }
  if (t < nb) bsum[t] = (t > 0) ? lds[t - 1] : 0;  // exclusive
}

__global__ void scan3(int* __restrict__ out, const int* __restrict__ bsum, int Mp1) {
  int i = blockIdx.x * blockDim.x + threadIdx.x;
  if (i < Mp1) out[i] += bsum[i / SCAN_CHUNK];
}

// ---------------- P1: per-block bucket histogram (bucket = dst >> 10) ----------------
__global__ __launch_bounds__(256) void bucket_hist(const int* __restrict__ dst,
                                                   int* __restrict__ bcnt, int E, int nbuck) {
  __shared__ int h[512];
  for (int i = threadIdx.x; i < 512; i += 256) h[i] = 0;
  __syncthreads();
  int per = (E + NBLK - 1) / NBLK;
  int s = blockIdx.x * per;
  int e = min(s + per, E);
  for (int i = s + threadIdx.x; i < e; i += 256) atomicAdd(&h[dst[i] >> 10], 1);
  __syncthreads();
  for (int b = threadIdx.x; b < nbuck; b += 256) bcnt[(long)b * NBLK + blockIdx.x] = h[b];
}

// ------- P2: scatter edges into bucket-ordered packed array: (dst&1023)<<19 | src -------
__global__ __launch_bounds__(256) void bucket_scatter(const int* __restrict__ src,
                                                      const int* __restrict__ dst,
                                                      const int* __restrict__ bbase,
                                                      int* __restrict__ sed, int E, int nbuck) {
  __shared__ int h[512];
  for (int b = threadIdx.x; b < nbuck; b += 256) h[b] = bbase[(long)b * NBLK + blockIdx.x];
  __syncthreads();
  int per = (E + NBLK - 1) / NBLK;
  int s = blockIdx.x * per;
  int e = min(s + per, E);
  for (int i = s + threadIdx.x; i < e; i += 256) {
    int d = dst[i];
    int pos = atomicAdd(&h[d >> 10], 1);
    sed[pos] = ((d & 1023) << SRC_BITS) | src[i];
  }
}

// ----- P3 fused: per-bucket node hist -> rsp (padded start/end) + isq, LDS-rank CSR write,
//       pad slots & sentinel region filled with node index N (zero row) -----
__global__ __launch_bounds__(256) void node_csr(const int* __restrict__ sed,
                                                const int* __restrict__ bbase,
                                                int2* __restrict__ rsp, float* __restrict__ isq,
                                                int* __restrict__ csr, int E, int nbuck, int N,
                                                int PARK) {
  __shared__ int h[1024];
  __shared__ int ws[256];
  __shared__ int cur[1024];
  int b = blockIdx.x;
  int n0 = b << 10;
  int nn = min(1024, N - n0);
  int t = threadIdx.x;
  for (int i = t; i < 1024; i += 256) h[i] = 0;
  __syncthreads();
  int s = bbase[(long)b * NBLK];
  int e = (b + 1 < nbuck) ? bbase[(long)(b + 1) * NBLK] : E;
  for (int i = s + t; i < e; i += 256) atomicAdd(&h[((unsigned)sed[i]) >> SRC_BITS], 1);
  __syncthreads();
  int v0 = h[4 * t], v1 = h[4 * t + 1], v2 = h[4 * t + 2], v3 = h[4 * t + 3];
  int p0 = (v0 + 3) & ~3, p1 = (v1 + 3) & ~3, p2 = (v2 + 3) & ~3, p3 = (v3 + 3) & ~3;
  ws[t] = p0 + p1 + p2 + p3;
  __syncthreads();
  for (int off = 1; off < 256; off <<= 1) {
    int x = (t >= off) ? ws[t - off] : 0;
    __syncthreads();
    ws[t] += x;
    __syncthreads();
  }
  int pbase = s + 3072 * b;
  int st0 = pbase + ((t > 0) ? ws[t - 1] : 0);
  int st1 = st0 + p0, st2 = st1 + p1, st3 = st2 + p2;
  int i0 = 4 * t;
  cur[i0] = st0;
  cur[i0 + 1] = st1;
  cur[i0 + 2] = st2;
  cur[i0 + 3] = st3;
  if (i0 < nn) { rsp[n0 + i0] = make_int2(st0, st0 + p0); isq[n0 + i0] = rsqrtf((float)(v0 + 1)); }
  if (i0 + 1 < nn) { rsp[n0 + i0 + 1] = make_int2(st1, st1 + p1); isq[n0 + i0 + 1] = rsqrtf((float)(v1 + 1)); }
  if (i0 + 2 < nn) { rsp[n0 + i0 + 2] = make_int2(st2, st2 + p2); isq[n0 + i0 + 2] = rsqrtf((float)(v2 + 1)); }
  if (i0 + 3 < nn) { rsp[n0 + i0 + 3] = make_int2(st3, st3 + p3); isq[n0 + i0 + 3] = rsqrtf((float)(v3 + 1)); }
  __syncthreads();
  // rank + write csr
  for (int i = s + t; i < e; i += 256) {
    int v = sed[i];
    int pos = atomicAdd(&cur[((unsigned)v) >> SRC_BITS], 1);
    csr[pos] = v & ((1 << SRC_BITS) - 1);
  }
  __syncthreads();
  // fill pad slots with sentinel N (zero row)
  for (int j = v0; j < p0; ++j) csr[st0 + j] = N;
  for (int j = v1; j < p1; ++j) csr[st1 + j] = N;
  for (int j = v2; j < p2; ++j) csr[st2 + j] = N;
  for (int j = v3; j < p3; ++j) csr[st3 + j] = N;
  if (b == 0 && t < 64) csr[PARK + t] = N;  // parking region
}

// ------- scale+cast: xs1[n,:] = half(x[n,:] * isq[n]); also zero sentinel rows -------
__global__ __launch_bounds__(256) void scale_cast(const float* __restrict__ x,
                                                  const float* __restrict__ isq,
                                                  half_t* __restrict__ xs1,
                                                  half_t* __restrict__ xs2,
                                                  long nocts, int N) {
  long i = (long)blockIdx.x * 256 + threadIdx.x;
  if (blockIdx.x == 0 && threadIdx.x < 16) {  // zero sentinel row N of both buffers
    const half8 z = {(half_t)0, (half_t)0, (half_t)0, (half_t)0,
                     (half_t)0, (half_t)0, (half_t)0, (half_t)0};
    half_t* base = (threadIdx.x < 8) ? xs1 : xs2;
    ((half8*)(base + (size_t)N * 64))[threadIdx.x & 7] = z;
  }
  if (i >= nocts) return;
  int node = (int)(i >> 3);
  float s = isq[node];
  float4 vlo = ((const float4*)x)[i * 2];
  float4 vhi = ((const float4*)x)[i * 2 + 1];
  half8 h;
  h[0] = (half_t)(vlo.x * s);
  h[1] = (half_t)(vlo.y * s);
  h[2] = (half_t)(vlo.z * s);
  h[3] = (half_t)(vlo.w * s);
  h[4] = (half_t)(vhi.x * s);
  h[5] = (half_t)(vhi.y * s);
  h[6] = (half_t)(vhi.z * s);
  h[7] = (half_t)(vhi.w * s);
  ((half8*)xs1)[i] = h;
}

// ------- fused gather conv with MFMA epilogue -------
// agg = sum_{s in N(d)} xs[s] + xs[d]  (gather, guard-free padded CSR)
// y = agg @ W via mfma_f32_16x16x32_f16 (32x64 block tile, 8 16x16 tiles, 4 waves)
// r = relu(y*isq[d] + b); out = half(scale_out ? r*isq[d] : r)
__global__ __launch_bounds__(256) void gather_fused(const half_t* __restrict__ xs,
                                                    const int* __restrict__ csr,
                                                    const int2* __restrict__ rsp,
                                                    const float* __restrict__ isq,
                                                    const float* __restrict__ W,
                                                    const float* __restrict__ bias,
                                                    half_t* __restrict__ out, int N,
                                                    int PARK, int scale_out) {
  __shared__ half_t Wt[64][72];   // [c][k] fp16 transposed (B-fragment contiguous)
  __shared__ half_t exh[32][72];  // [node][k] fp16 agg (A-fragment contiguous)
  __shared__ float idv[32];
  int tid = threadIdx.x;
  // stage W transposed -> fp16 LDS: thread t covers col c=t&63, k rows (t>>6)*16..+16
  {
    int c = tid & 63;
    int kb = (tid >> 6) * 16;
#pragma unroll
    for (int i = 0; i < 16; ++i) Wt[c][kb + i] = (half_t)W[(kb + i) * 64 + c];
  }

  int lane = tid & 63;
  int sub = lane & 7;    // channel octet: channels sub*8..sub*8+7
  int grp = lane >> 3;   // dst group within wave (0..7)
  int li = tid >> 3;     // local node index 0..31
  int wid = (blockIdx.x * blockDim.x + tid) >> 6;
  long d0 = (long)wid * 8;
  int d = (int)d0 + grp;
  bool vd = (d0 < N) && (d < N);
  int dd = vd ? d : N - 1;
  int2 rr = rsp[dd];
  int jj = vd ? rr.x : PARK;
  int je = vd ? rr.y : PARK;
  float id = isq[dd];
  const uint8_t* xb = (const uint8_t*)xs;
  uint32_t co = (uint32_t)sub << 4;   // channel byte offset within row
  float ac[8];
  {
    half8 sv = *(const half8*)(xb + (((uint32_t)dd << 7) + co));
#pragma unroll
    for (int c = 0; c < 8; ++c) ac[c] = (float)sv[c];
  }
  jj = (jj < je) ? jj : PARK;
  while (__any(jj != PARK)) {
    int s0 = csr[jj];
    int s1 = csr[jj + 1];
    int s2 = csr[jj + 2];
    int s3 = csr[jj + 3];
    half8 v0 = *(const half8*)(xb + (((uint32_t)s0 << 7) + co));
    half8 v1 = *(const half8*)(xb + (((uint32_t)s1 << 7) + co));
    half8 v2 = *(const half8*)(xb + (((uint32_t)s2 << 7) + co));
    half8 v3 = *(const half8*)(xb + (((uint32_t)s3 << 7) + co));
    half8 sum = (v0 + v1) + (v2 + v3);  // fp16 tree; pads are exact zeros
#pragma unroll
    for (int c = 0; c < 8; ++c) ac[c] += (float)sum[c];
    jj += 4;
    jj = (jj < je) ? jj : PARK;
  }
  // agg -> fp16 LDS tile for MFMA A-fragments
  {
    half8 ah;
#pragma unroll
    for (int c = 0; c < 8; ++c) ah[c] = (half_t)ac[c];
    *(half8*)&exh[li][sub * 8] = ah;
    if (sub == 0) idv[li] = id;
  }
  __syncthreads();

  // MFMA phase: 8 tiles (mt 0..1 x nt 0..3), wave w does tiles 2w, 2w+1
  int w = tid >> 6;
  int lr = lane & 15;  // A row / B col / D col within tile
  int lk = lane >> 4;  // k-group (8 halves each)
  long d0b = (long)blockIdx.x * 32;
#pragma unroll
  for (int t2 = 0; t2 < 2; ++t2) {
    int tile = w * 2 + t2;
    int mt = tile >> 2;
    int nt = tile & 3;
    f32x4 acc = {0.f, 0.f, 0.f, 0.f};
#pragma unroll
    for (int ks = 0; ks < 2; ++ks) {
      half8 a = *(const half8*)&exh[mt * 16 + lr][ks * 32 + lk * 8];
      half8 b = *(const half8*)&Wt[nt * 16 + lr][ks * 32 + lk * 8];
      acc = __builtin_amdgcn_mfma_f32_16x16x32_f16(a, b, acc, 0, 0, 0);
    }
    float bv = bias[nt * 16 + lr];
#pragma unroll
    for (int j = 0; j < 4; ++j) {
      int nl = mt * 16 + lk * 4 + j;  // D row = (lane>>4)*4 + reg (m89 layout)
      long dn = d0b + nl;
      if (dn < N) {
        float id2 = idv[nl];
        float m = scale_out ? id2 : 1.f;
        float r = fmaxf(fmaf(acc[j], id2, bv), 0.f) * m;
        out[dn * 64 + nt * 16 + lr] = (half_t)r;
      }
    }
  }
}

// ---------------- graph segment offsets from sorted batch_idx ----------------
__global__ void seg_offsets(const int* __restrict__ batch, int* __restrict__ off, int N, int G) {
  int i = blockIdx.x * blockDim.x + threadIdx.x;
  if (i >= N) return;
  int b = batch[i];
  if (i == 0) {
    for (int g = 0; g <= b; ++g) off[g] = 0;
  } else {
    int pb = batch[i - 1];
    for (int g = pb + 1; g <= b; ++g) off[g] = i;
  }
  if (i == N - 1) {
    for (int g = b + 1; g <= G; ++g) off[g] = N;
  }
}

// ------- mean pool over fp16 rows: lane = half8 (16B), 8 row-parities/wave -------
__global__ void pool_mean(const half_t* __restrict__ e2, const int* __restrict__ off,
                          float* __restrict__ ge, int G) {
  int lane = threadIdx.x & 63;
  int wid = (blockIdx.x * blockDim.x + threadIdx.x) >> 6;
  int nw = (gridDim.x * blockDim.x) >> 6;
  int c8 = lane & 7;   // channel octet
  int rp = lane >> 3;  // row parity 0..7
  for (int g = wid; g < G; g += nw) {
    int s = off[g];
    int e = off[g + 1];
    float acc[8];
#pragma unroll
    for (int c = 0; c < 8; ++c) acc[c] = 0.f;
    for (int n = s + rp; n < e; n += 8) {
      half8 v = *(const half8*)&e2[(long)n * 64 + c8 * 8];
#pragma unroll
      for (int c = 0; c < 8; ++c) acc[c] += (float)v[c];
    }
#pragma unroll
    for (int c = 0; c < 8; ++c) {
      acc[c] += __shfl_xor(acc[c], 8, 64);
      acc[c] += __shfl_xor(acc[c], 16, 64);
      acc[c] += __shfl_xor(acc[c], 32, 64);
    }
    if (rp == 0) {
      float inv = 1.f / fmaxf((float)(e - s), 1.f);
      float4 lo = make_float4(acc[0] * inv, acc[1] * inv, acc[2] * inv, acc[3] * inv);
      float4 hi = make_float4(acc[4] * inv, acc[5] * inv, acc[6] * inv, acc[7] * inv);
      *(float4*)&ge[(long)g * 64 + c8 * 8] = lo;
      *(float4*)&ge[(long)g * 64 + c8 * 8 + 4] = hi;
    }
  }
}

// ---------------- pair MLP: thread = 4 hidden x 16 pairs, PPB=64 ----------------
#define PPB 64
__global__ __launch_bounds__(256) void pair_mlp(const float* __restrict__ ge,
                                                const int* __restrict__ dp,
                                                const float* __restrict__ Wr1,
                                                const float* __restrict__ br1,
                                                const float* __restrict__ Wr2,
                                                const float* __restrict__ br2,
                                                float* __restrict__ out, int P) {
  __shared__ float feat[PPB][128];
  __shared__ int pidx[2][PPB];
  int tid = threadIdx.x;
  int base = blockIdx.x * PPB;
  if (tid < PPB) {
    int p = base + tid;
    pidx[0][tid] = (p < P) ? dp[p] : 0;
    pidx[1][tid] = (p < P) ? dp[P + p] : 0;
  }
  __syncthreads();
#pragma unroll
  for (int i = 0; i < 8; ++i) {
    int u = tid + i * 256;   // float4 index
    int p = u >> 5;          // 32 float4 per pair row
    int k = (u & 31) * 4;    // feature index 0..124
    int g = (k < 64) ? pidx[0][p] : pidx[1][p];
    *(float4*)&feat[p][k] = *(const float4*)&ge[(long)g * 64 + (k & 63)];
  }
  __syncthreads();
  int jg = tid & 63;   // hidden group -> hidden units j0..j0+3
  int j0 = jg * 4;
  int pg = tid >> 6;   // pair quarter -> pairs pg*16..pg*16+15
  int pb = pg * 16;
  float acc[16][4];
#pragma unroll
  for (int p = 0; p < 16; ++p)
#pragma unroll
    for (int j = 0; j < 4; ++j) acc[p][j] = 0.f;
  for (int k4 = 0; k4 < 32; ++k4) {
    float4 w0 = *(const float4*)&Wr1[(k4 * 4 + 0) * 256 + j0];
    float4 w1 = *(const float4*)&Wr1[(k4 * 4 + 1) * 256 + j0];
    float4 w2 = *(const float4*)&Wr1[(k4 * 4 + 2) * 256 + j0];
    float4 w3 = *(const float4*)&Wr1[(k4 * 4 + 3) * 256 + j0];
#pragma unroll
    for (int p = 0; p < 16; ++p) {
      float4 f = *(const float4*)&feat[pb + p][k4 * 4];
      acc[p][0] = fmaf(f.x, w0.x, acc[p][0]);
      acc[p][1] = fmaf(f.x, w0.y, acc[p][1]);
      acc[p][2] = fmaf(f.x, w0.z, acc[p][2]);
      acc[p][3] = fmaf(f.x, w0.w, acc[p][3]);
      acc[p][0] = fmaf(f.y, w1.x, acc[p][0]);
      acc[p][1] = fmaf(f.y, w1.y, acc[p][1]);
      acc[p][2] = fmaf(f.y, w1.z, acc[p][2]);
      acc[p][3] = fmaf(f.y, w1.w, acc[p][3]);
      acc[p][0] = fmaf(f.z, w2.x, acc[p][0]);
      acc[p][1] = fmaf(f.z, w2.y, acc[p][1]);
      acc[p][2] = fmaf(f.z, w2.z, acc[p][2]);
      acc[p][3] = fmaf(f.z, w2.w, acc[p][3]);
      acc[p][0] = fmaf(f.w, w3.x, acc[p][0]);
      acc[p][1] = fmaf(f.w, w3.y, acc[p][1]);
      acc[p][2] = fmaf(f.w, w3.z, acc[p][2]);
      acc[p][3] = fmaf(f.w, w3.w, acc[p][3]);
    }
  }
  float4 b1v = *(const float4*)&br1[j0];
  float4 w2v = *(const float4*)&Wr2[j0];
  float br2v = br2[0];
#pragma unroll
  for (int p = 0; p < 16; ++p) {
    float v = fmaxf(acc[p][0] + b1v.x, 0.f) * w2v.x;
    v = fmaf(fmaxf(acc[p][1] + b1v.y, 0.f), w2v.y, v);
    v = fmaf(fmaxf(acc[p][2] + b1v.z, 0.f), w2v.z, v);
    v = fmaf(fmaxf(acc[p][3] + b1v.w, 0.f), w2v.w, v);
    for (int o = 32; o > 0; o >>= 1) v += __shfl_down(v, o, 64);
    if (jg == 0) {
      int pp = base + pb + p;
      if (pp < P) out[pp] = v + br2v;
    }
  }
}

extern "C" void kernel_launch(void* const* d_in, const int* in_sizes, int n_in,
                              void* d_out, int out_size, void* d_ws, size_t ws_size,
                              hipStream_t stream) {
  const float* x = (const float*)d_in[0];
  const int* ei = (const int*)d_in[1];
  const int* batch = (const int*)d_in[2];
  const int* dp = (const int*)d_in[3];
  const float* W1 = (const float*)d_in[4];
  const float* b1 = (const float*)d_in[5];
  const float* W2 = (const float*)d_in[6];
  const float* b2 = (const float*)d_in[7];
  const float* Wr1 = (const float*)d_in[8];
  const float* br1 = (const float*)d_in[9];
  const float* Wr2 = (const float*)d_in[10];
  const float* br2 = (const float*)d_in[11];
  float* out = (float*)d_out;

  int N = in_sizes[0] / 64;
  int E = in_sizes[1] / 2;
  int P = in_sizes[3] / 2;
  int G = N_GRAPHS;
  const int* src = ei;
  const int* dstp = ei + E;

  int nbuck = (N + 1023) >> 10;  // <= 512
  long M = (long)nbuck * NBLK;
  int PARK = E + 3072 * nbuck;   // start of parking region in padded csr space

  char* ws = (char*)d_ws;
  size_t o = 0;
  auto alloc = [&](size_t bytes) {
    void* p = ws + o;
    o += (bytes + 255) & ~(size_t)255;
    return p;
  };
  float* isq = (float*)alloc((size_t)N * 4);
  int2* rsp = (int2*)alloc((size_t)N * 8);
  int* bsum = (int*)alloc(1024 * 4);
  int* goff = (int*)alloc((size_t)(G + 1) * 4);
  int* bcnt = (int*)alloc((size_t)(M + 1) * 4);
  int* sed = (int*)alloc((size_t)E * 4);
  int* csr = (int*)alloc((size_t)(PARK + 80) * 4);
  half_t* xs1 = (half_t*)alloc((size_t)(N + 1) * 64 * 2);
  half_t* xs2 = (half_t*)alloc((size_t)(N + 1) * 64 * 2);
  half_t* abuf = (half_t*)alloc((size_t)N * 64 * 2);
  float* ge = (float*)alloc((size_t)G * 64 * 4);

  // --- CSR build, atomic-free at global scope ---
  bucket_hist<<<NBLK, 256, 0, stream>>>(dstp, bcnt, E, nbuck);
  int nbA = (int)((M + SCAN_CHUNK - 1) / SCAN_CHUNK);
  scan1<<<nbA, 256, 0, stream>>>(bcnt, bcnt, bsum, (int)M);  // in-place exclusive scan
  scan2<<<1, 256, 0, stream>>>(bsum, nbA);
  scan3<<<(int)((M + 1 + 255) / 256), 256, 0, stream>>>(bcnt, bsum, (int)(M + 1));
  bucket_scatter<<<NBLK, 256, 0, stream>>>(src, dstp, bcnt, sed, E, nbuck);
  node_csr<<<nbuck, 256, 0, stream>>>(sed, bcnt, rsp, isq, csr, E, nbuck, N, PARK);
  seg_offsets<<<(N + 255) / 256, 256, 0, stream>>>(batch, goff, N, G);

  long nocts = (long)N * 8;
  int gblocks = (N + 31) / 32;  // 4 waves/block, 8 dst/wave, 32 nodes/block
  // xs1 = x * isq (fp16); also zeroes sentinel rows of xs1/xs2
  scale_cast<<<(int)((nocts + 255) / 256), 256, 0, stream>>>(x, isq, xs1, xs2, nocts, N);
  // conv1: gather xs1, MFMA @W1 epilogue, out xs2 = relu1*isq (fp16)
  gather_fused<<<gblocks, 256, 0, stream>>>(xs1, csr, rsp, isq, W1, b1, xs2, N, PARK, 1);
  // conv2: gather xs2, MFMA @W2 epilogue, out abuf = relu2 (fp16)
  gather_fused<<<gblocks, 256, 0, stream>>>(xs2, csr, rsp, isq, W2, b2, abuf, N, PARK, 0);
  // pool
  pool_mean<<<2048, 256, 0, stream>>>(abuf, goff, ge, G);
  // pair MLP
  pair_mlp<<<(P + PPB - 1) / PPB, 256, 0, stream>>>(ge, dp, Wr1, br1, Wr2, br2, out, P);
}

// Round 20
// 275.081 us; speedup vs baseline: 2.6218x; 1.1265x over previous
//
#include <hip/hip_runtime.h>
#include <cstdint>

#define N_GRAPHS 20000
#define SCAN_CHUNK 2048
#define NBLK 512  // blocks for bucket hist/scatter
#define SRC_BITS 19  // N=500000 < 2^19; bucket-local dst uses 10 bits

typedef _Float16 half_t;
typedef __attribute__((ext_vector_type(4))) _Float16 half4;
typedef __attribute__((ext_vector_type(8))) _Float16 half8;
typedef __attribute__((ext_vector_type(4))) float f32x4;

// ---------------- prefix scan (exclusive) of in[M] -> out[M+1] ----------------
__global__ __launch_bounds__(256) void scan1(const int* __restrict__ in, int* __restrict__ out,
                                             int* __restrict__ bsum, int M) {
  __shared__ int lds[256];
  int t = threadIdx.x;
  int base = blockIdx.x * SCAN_CHUNK + t * 8;
  int v[8];
  int s = 0;
#pragma unroll
  for (int i = 0; i < 8; ++i) {
    v[i] = (base + i < M) ? in[base + i] : 0;
    s += v[i];
  }
  lds[t] = s;
  __syncthreads();
  for (int off = 1; off < 256; off <<= 1) {
    int x = (t >= off) ? lds[t - off] : 0;
    __syncthreads();
    lds[t] += x;
    __syncthreads();
  }
  if (t == 255) bsum[blockIdx.x] = lds[255];
  int run = (t > 0) ? lds[t - 1] : 0;
#pragma unroll
  for (int i = 0; i < 8; ++i) {
    if (base + i <= M) out[base + i] = run;
    run += v[i];
  }
}

__global__ __launch_bounds__(256) void scan2(int* __restrict__ bsum, int nb) {
  __shared__ int lds[256];
  int t = threadIdx.x;
  lds[t] = (t < nb) ? bsum[t] : 0;
  __syncthreads();
  for (int off = 1; off < 256; off <<= 1) {
    int x = (t >= off) ? lds[t - off] : 0;
    __syncthreads();
    lds[t] += x;
    __syncthreads();
  }
  if (t < nb) bsum[t] = (t > 0) ? lds[t - 1] : 0;  // exclusive
}

__global__ void scan3(int* __restrict__ out, const int* __restrict__ bsum, int Mp1) {
  int i = blockIdx.x * blockDim.x + threadIdx.x;
  if (i < Mp1) out[i] += bsum[i / SCAN_CHUNK];
}

// ---------------- P1: per-block bucket histogram (bucket = dst >> 10) ----------------
__global__ __launch_bounds__(256) void bucket_hist(const int* __restrict__ dst,
                                                   int* __restrict__ bcnt, int E, int nbuck) {
  __shared__ int h[512];
  for (int i = threadIdx.x; i < 512; i += 256) h[i] = 0;
  __syncthreads();
  int per = (E + NBLK - 1) / NBLK;
  int s = blockIdx.x * per;
  int e = min(s + per, E);
  for (int i = s + threadIdx.x; i < e; i += 256) atomicAdd(&h[dst[i] >> 10], 1);
  __syncthreads();
  for (int b = threadIdx.x; b < nbuck; b += 256) bcnt[(long)b * NBLK + blockIdx.x] = h[b];
}

// ------- P2: scatter edges into bucket-ordered packed array: (dst&1023)<<19 | src -------
__global__ __launch_bounds__(256) void bucket_scatter(const int* __restrict__ src,
                                                      const int* __restrict__ dst,
                                                      const int* __restrict__ bbase,
                                                      int* __restrict__ sed, int E, int nbuck) {
  __shared__ int h[512];
  for (int b = threadIdx.x; b < nbuck; b += 256) h[b] = bbase[(long)b * NBLK + blockIdx.x];
  __syncthreads();
  int per = (E + NBLK - 1) / NBLK;
  int s = blockIdx.x * per;
  int e = min(s + per, E);
  for (int i = s + threadIdx.x; i < e; i += 256) {
    int d = dst[i];
    int pos = atomicAdd(&h[d >> 10], 1);
    sed[pos] = ((d & 1023) << SRC_BITS) | src[i];
  }
}

// ----- P3 fused: per-bucket node hist -> rsp (padded start/end) + isq, LDS-rank CSR write,
//       pad slots & sentinel region filled with node index N (zero row) -----
__global__ __launch_bounds__(256) void node_csr(const int* __restrict__ sed,
                                                const int* __restrict__ bbase,
                                                int2* __restrict__ rsp, float* __restrict__ isq,
                                                int* __restrict__ csr, int E, int nbuck, int N,
                                                int PARK) {
  __shared__ int h[1024];
  __shared__ int ws[256];
  __shared__ int cur[1024];
  int b = blockIdx.x;
  int n0 = b << 10;
  int nn = min(1024, N - n0);
  int t = threadIdx.x;
  for (int i = t; i < 1024; i += 256) h[i] = 0;
  __syncthreads();
  int s = bbase[(long)b * NBLK];
  int e = (b + 1 < nbuck) ? bbase[(long)(b + 1) * NBLK] : E;
  for (int i = s + t; i < e; i += 256) atomicAdd(&h[((unsigned)sed[i]) >> SRC_BITS], 1);
  __syncthreads();
  int v0 = h[4 * t], v1 = h[4 * t + 1], v2 = h[4 * t + 2], v3 = h[4 * t + 3];
  int p0 = (v0 + 3) & ~3, p1 = (v1 + 3) & ~3, p2 = (v2 + 3) & ~3, p3 = (v3 + 3) & ~3;
  ws[t] = p0 + p1 + p2 + p3;
  __syncthreads();
  for (int off = 1; off < 256; off <<= 1) {
    int x = (t >= off) ? ws[t - off] : 0;
    __syncthreads();
    ws[t] += x;
    __syncthreads();
  }
  int pbase = s + 3072 * b;
  int st0 = pbase + ((t > 0) ? ws[t - 1] : 0);
  int st1 = st0 + p0, st2 = st1 + p1, st3 = st2 + p2;
  int i0 = 4 * t;
  cur[i0] = st0;
  cur[i0 + 1] = st1;
  cur[i0 + 2] = st2;
  cur[i0 + 3] = st3;
  if (i0 < nn) { rsp[n0 + i0] = make_int2(st0, st0 + p0); isq[n0 + i0] = rsqrtf((float)(v0 + 1)); }
  if (i0 + 1 < nn) { rsp[n0 + i0 + 1] = make_int2(st1, st1 + p1); isq[n0 + i0 + 1] = rsqrtf((float)(v1 + 1)); }
  if (i0 + 2 < nn) { rsp[n0 + i0 + 2] = make_int2(st2, st2 + p2); isq[n0 + i0 + 2] = rsqrtf((float)(v2 + 1)); }
  if (i0 + 3 < nn) { rsp[n0 + i0 + 3] = make_int2(st3, st3 + p3); isq[n0 + i0 + 3] = rsqrtf((float)(v3 + 1)); }
  __syncthreads();
  // rank + write csr
  for (int i = s + t; i < e; i += 256) {
    int v = sed[i];
    int pos = atomicAdd(&cur[((unsigned)v) >> SRC_BITS], 1);
    csr[pos] = v & ((1 << SRC_BITS) - 1);
  }
  __syncthreads();
  // fill pad slots with sentinel N (zero row)
  for (int j = v0; j < p0; ++j) csr[st0 + j] = N;
  for (int j = v1; j < p1; ++j) csr[st1 + j] = N;
  for (int j = v2; j < p2; ++j) csr[st2 + j] = N;
  for (int j = v3; j < p3; ++j) csr[st3 + j] = N;
  if (b == 0 && t < 64) csr[PARK + t] = N;  // parking region
}

// ------- scale+cast: xs1[n,:] = half(x[n,:] * isq[n]); also zero sentinel rows -------
__global__ __launch_bounds__(256) void scale_cast(const float* __restrict__ x,
                                                  const float* __restrict__ isq,
                                                  half_t* __restrict__ xs1,
                                                  half_t* __restrict__ xs2,
                                                  long nocts, int N) {
  long i = (long)blockIdx.x * 256 + threadIdx.x;
  if (blockIdx.x == 0 && threadIdx.x < 16) {  // zero sentinel row N of both buffers
    const half8 z = {(half_t)0, (half_t)0, (half_t)0, (half_t)0,
                     (half_t)0, (half_t)0, (half_t)0, (half_t)0};
    half_t* base = (threadIdx.x < 8) ? xs1 : xs2;
    ((half8*)(base + (size_t)N * 64))[threadIdx.x & 7] = z;
  }
  if (i >= nocts) return;
  int node = (int)(i >> 3);
  float s = isq[node];
  float4 vlo = ((const float4*)x)[i * 2];
  float4 vhi = ((const float4*)x)[i * 2 + 1];
  half8 h;
  h[0] = (half_t)(vlo.x * s);
  h[1] = (half_t)(vlo.y * s);
  h[2] = (half_t)(vlo.z * s);
  h[3] = (half_t)(vlo.w * s);
  h[4] = (half_t)(vhi.x * s);
  h[5] = (half_t)(vhi.y * s);
  h[6] = (half_t)(vhi.z * s);
  h[7] = (half_t)(vhi.w * s);
  ((half8*)xs1)[i] = h;
}

// ------- fused gather conv with MFMA epilogue -------
__global__ __launch_bounds__(256) void gather_fused(const half_t* __restrict__ xs,
                                                    const int* __restrict__ csr,
                                                    const int2* __restrict__ rsp,
                                                    const float* __restrict__ isq,
                                                    const float* __restrict__ W,
                                                    const float* __restrict__ bias,
                                                    half_t* __restrict__ out, int N,
                                                    int PARK, int scale_out) {
  __shared__ half_t Wt[64][72];   // [c][k] fp16 transposed (B-fragment contiguous)
  __shared__ half_t exh[32][72];  // [node][k] fp16 agg (A-fragment contiguous)
  __shared__ float idv[32];
  int tid = threadIdx.x;
  {
    int c = tid & 63;
    int kb = (tid >> 6) * 16;
#pragma unroll
    for (int i = 0; i < 16; ++i) Wt[c][kb + i] = (half_t)W[(kb + i) * 64 + c];
  }

  int lane = tid & 63;
  int sub = lane & 7;
  int grp = lane >> 3;
  int li = tid >> 3;
  int wid = (blockIdx.x * blockDim.x + tid) >> 6;
  long d0 = (long)wid * 8;
  int d = (int)d0 + grp;
  bool vd = (d0 < N) && (d < N);
  int dd = vd ? d : N - 1;
  int2 rr = rsp[dd];
  int jj = vd ? rr.x : PARK;
  int je = vd ? rr.y : PARK;
  float id = isq[dd];
  const uint8_t* xb = (const uint8_t*)xs;
  uint32_t co = (uint32_t)sub << 4;
  float ac[8];
  {
    half8 sv = *(const half8*)(xb + (((uint32_t)dd << 7) + co));
#pragma unroll
    for (int c = 0; c < 8; ++c) ac[c] = (float)sv[c];
  }
  jj = (jj < je) ? jj : PARK;
  while (__any(jj != PARK)) {
    int s0 = csr[jj];
    int s1 = csr[jj + 1];
    int s2 = csr[jj + 2];
    int s3 = csr[jj + 3];
    half8 v0 = *(const half8*)(xb + (((uint32_t)s0 << 7) + co));
    half8 v1 = *(const half8*)(xb + (((uint32_t)s1 << 7) + co));
    half8 v2 = *(const half8*)(xb + (((uint32_t)s2 << 7) + co));
    half8 v3 = *(const half8*)(xb + (((uint32_t)s3 << 7) + co));
    half8 sum = (v0 + v1) + (v2 + v3);
#pragma unroll
    for (int c = 0; c < 8; ++c) ac[c] += (float)sum[c];
    jj += 4;
    jj = (jj < je) ? jj : PARK;
  }
  {
    half8 ah;
#pragma unroll
    for (int c = 0; c < 8; ++c) ah[c] = (half_t)ac[c];
    *(half8*)&exh[li][sub * 8] = ah;
    if (sub == 0) idv[li] = id;
  }
  __syncthreads();

  int w = tid >> 6;
  int lr = lane & 15;
  int lk = lane >> 4;
  long d0b = (long)blockIdx.x * 32;
#pragma unroll
  for (int t2 = 0; t2 < 2; ++t2) {
    int tile = w * 2 + t2;
    int mt = tile >> 2;
    int nt = tile & 3;
    f32x4 acc = {0.f, 0.f, 0.f, 0.f};
#pragma unroll
    for (int ks = 0; ks < 2; ++ks) {
      half8 a = *(const half8*)&exh[mt * 16 + lr][ks * 32 + lk * 8];
      half8 b = *(const half8*)&Wt[nt * 16 + lr][ks * 32 + lk * 8];
      acc = __builtin_amdgcn_mfma_f32_16x16x32_f16(a, b, acc, 0, 0, 0);
    }
    float bv = bias[nt * 16 + lr];
#pragma unroll
    for (int j = 0; j < 4; ++j) {
      int nl = mt * 16 + lk * 4 + j;
      long dn = d0b + nl;
      if (dn < N) {
        float id2 = idv[nl];
        float m = scale_out ? id2 : 1.f;
        float r = fmaxf(fmaf(acc[j], id2, bv), 0.f) * m;
        out[dn * 64 + nt * 16 + lr] = (half_t)r;
      }
    }
  }
}

// ---------------- graph segment offsets from sorted batch_idx ----------------
__global__ void seg_offsets(const int* __restrict__ batch, int* __restrict__ off, int N, int G) {
  int i = blockIdx.x * blockDim.x + threadIdx.x;
  if (i >= N) return;
  int b = batch[i];
  if (i == 0) {
    for (int g = 0; g <= b; ++g) off[g] = 0;
  } else {
    int pb = batch[i - 1];
    for (int g = pb + 1; g <= b; ++g) off[g] = i;
  }
  if (i == N - 1) {
    for (int g = b + 1; g <= G; ++g) off[g] = N;
  }
}

// ------- mean pool over fp16 rows: lane = half8 (16B), 8 row-parities/wave -------
__global__ void pool_mean(const half_t* __restrict__ e2, const int* __restrict__ off,
                          float* __restrict__ ge, int G) {
  int lane = threadIdx.x & 63;
  int wid = (blockIdx.x * blockDim.x + threadIdx.x) >> 6;
  int nw = (gridDim.x * blockDim.x) >> 6;
  int c8 = lane & 7;
  int rp = lane >> 3;
  for (int g = wid; g < G; g += nw) {
    int s = off[g];
    int e = off[g + 1];
    float acc[8];
#pragma unroll
    for (int c = 0; c < 8; ++c) acc[c] = 0.f;
    for (int n = s + rp; n < e; n += 8) {
      half8 v = *(const half8*)&e2[(long)n * 64 + c8 * 8];
#pragma unroll
      for (int c = 0; c < 8; ++c) acc[c] += (float)v[c];
    }
#pragma unroll
    for (int c = 0; c < 8; ++c) {
      acc[c] += __shfl_xor(acc[c], 8, 64);
      acc[c] += __shfl_xor(acc[c], 16, 64);
      acc[c] += __shfl_xor(acc[c], 32, 64);
    }
    if (rp == 0) {
      float inv = 1.f / fmaxf((float)(e - s), 1.f);
      float4 lo = make_float4(acc[0] * inv, acc[1] * inv, acc[2] * inv, acc[3] * inv);
      float4 hi = make_float4(acc[4] * inv, acc[5] * inv, acc[6] * inv, acc[7] * inv);
      *(float4*)&ge[(long)g * 64 + c8 * 8] = lo;
      *(float4*)&ge[(long)g * 64 + c8 * 8 + 4] = hi;
    }
  }
}

// ------- pair MLP via MFMA: 256 pairs/block; feat & Wr1^T staged fp16 in LDS -------
#define PPB 256
__global__ __launch_bounds__(256) void pair_mlp(const float* __restrict__ ge,
                                                const int* __restrict__ dp,
                                                const float* __restrict__ Wr1,
                                                const float* __restrict__ br1,
                                                const float* __restrict__ Wr2,
                                                const float* __restrict__ br2,
                                                float* __restrict__ out, int P) {
  __shared__ half_t Wt[256][136];  // [hidden j][k] fp16 (~69.6 KB)
  __shared__ half_t ft[PPB][136];  // [pair][k] fp16 (~69.6 KB)
  int tid = threadIdx.x;
  // stage Wr1 transposed -> fp16
  for (int idx = tid; idx < 128 * 256; idx += 256) {
    int k = idx >> 8;
    int j = idx & 255;
    Wt[j][k] = (half_t)Wr1[idx];
  }
  // stage features: thread t handles pair t
  int base = blockIdx.x * PPB;
  {
    int pp = base + tid;
    bool v = pp < P;
    int ga = v ? dp[pp] : 0;
    int gb = v ? dp[P + pp] : 0;
#pragma unroll
    for (int h = 0; h < 8; ++h) {
      const float* srow = (h < 4) ? &ge[(long)ga * 64 + h * 16] : &ge[(long)gb * 64 + (h - 4) * 16];
      float4 a0 = *(const float4*)&srow[0];
      float4 a1 = *(const float4*)&srow[4];
      float4 a2 = *(const float4*)&srow[8];
      float4 a3 = *(const float4*)&srow[12];
      half8 h0, h1;
      h0[0] = (half_t)a0.x; h0[1] = (half_t)a0.y; h0[2] = (half_t)a0.z; h0[3] = (half_t)a0.w;
      h0[4] = (half_t)a1.x; h0[5] = (half_t)a1.y; h0[6] = (half_t)a1.z; h0[7] = (half_t)a1.w;
      h1[0] = (half_t)a2.x; h1[1] = (half_t)a2.y; h1[2] = (half_t)a2.z; h1[3] = (half_t)a2.w;
      h1[4] = (half_t)a3.x; h1[5] = (half_t)a3.y; h1[6] = (half_t)a3.z; h1[7] = (half_t)a3.w;
      *(half8*)&ft[tid][h * 16] = h0;
      *(half8*)&ft[tid][h * 16 + 8] = h1;
    }
  }
  __syncthreads();

  int w = tid >> 6;
  int lane = tid & 63;
  int lr = lane & 15;
  int lk = lane >> 4;
  float b1v[16], w2v[16];
#pragma unroll
  for (int nt = 0; nt < 16; ++nt) {
    b1v[nt] = br1[nt * 16 + lr];
    w2v[nt] = Wr2[nt * 16 + lr];
  }
  float br2v = br2[0];
#pragma unroll
  for (int m4 = 0; m4 < 4; ++m4) {
    int mt = w * 4 + m4;
    float ps0 = 0.f, ps1 = 0.f, ps2 = 0.f, ps3 = 0.f;
#pragma unroll
    for (int nt = 0; nt < 16; ++nt) {
      f32x4 acc = {0.f, 0.f, 0.f, 0.f};
#pragma unroll
      for (int ks = 0; ks < 4; ++ks) {
        half8 a = *(const half8*)&ft[mt * 16 + lr][ks * 32 + lk * 8];
        half8 b = *(const half8*)&Wt[nt * 16 + lr][ks * 32 + lk * 8];
        acc = __builtin_amdgcn_mfma_f32_16x16x32_f16(a, b, acc, 0, 0, 0);
      }
      ps0 += fmaxf(acc[0] + b1v[nt], 0.f) * w2v[nt];
      ps1 += fmaxf(acc[1] + b1v[nt], 0.f) * w2v[nt];
      ps2 += fmaxf(acc[2] + b1v[nt], 0.f) * w2v[nt];
      ps3 += fmaxf(acc[3] + b1v[nt], 0.f) * w2v[nt];
    }
    // reduce across the 16 column-lanes (same lk group)
#pragma unroll
    for (int o = 1; o < 16; o <<= 1) {
      ps0 += __shfl_xor(ps0, o, 64);
      ps1 += __shfl_xor(ps1, o, 64);
      ps2 += __shfl_xor(ps2, o, 64);
      ps3 += __shfl_xor(ps3, o, 64);
    }
    if (lr == 0) {
      int prow = mt * 16 + lk * 4;  // D row = (lane>>4)*4 + reg
      int pp = base + prow;
      if (pp + 0 < P) out[pp + 0] = ps0 + br2v;
      if (pp + 1 < P) out[pp + 1] = ps1 + br2v;
      if (pp + 2 < P) out[pp + 2] = ps2 + br2v;
      if (pp + 3 < P) out[pp + 3] = ps3 + br2v;
    }
  }
}

extern "C" void kernel_launch(void* const* d_in, const int* in_sizes, int n_in,
                              void* d_out, int out_size, void* d_ws, size_t ws_size,
                              hipStream_t stream) {
  const float* x = (const float*)d_in[0];
  const int* ei = (const int*)d_in[1];
  const int* batch = (const int*)d_in[2];
  const int* dp = (const int*)d_in[3];
  const float* W1 = (const float*)d_in[4];
  const float* b1 = (const float*)d_in[5];
  const float* W2 = (const float*)d_in[6];
  const float* b2 = (const float*)d_in[7];
  const float* Wr1 = (const float*)d_in[8];
  const float* br1 = (const float*)d_in[9];
  const float* Wr2 = (const float*)d_in[10];
  const float* br2 = (const float*)d_in[11];
  float* out = (float*)d_out;

  int N = in_sizes[0] / 64;
  int E = in_sizes[1] / 2;
  int P = in_sizes[3] / 2;
  int G = N_GRAPHS;
  const int* src = ei;
  const int* dstp = ei + E;

  int nbuck = (N + 1023) >> 10;  // <= 512
  long M = (long)nbuck * NBLK;
  int PARK = E + 3072 * nbuck;   // start of parking region in padded csr space

  char* ws = (char*)d_ws;
  size_t o = 0;
  auto alloc = [&](size_t bytes) {
    void* p = ws + o;
    o += (bytes + 255) & ~(size_t)255;
    return p;
  };
  float* isq = (float*)alloc((size_t)N * 4);
  int2* rsp = (int2*)alloc((size_t)N * 8);
  int* bsum = (int*)alloc(1024 * 4);
  int* goff = (int*)alloc((size_t)(G + 1) * 4);
  int* bcnt = (int*)alloc((size_t)(M + 1) * 4);
  int* sed = (int*)alloc((size_t)E * 4);
  int* csr = (int*)alloc((size_t)(PARK + 80) * 4);
  half_t* xs1 = (half_t*)alloc((size_t)(N + 1) * 64 * 2);
  half_t* xs2 = (half_t*)alloc((size_t)(N + 1) * 64 * 2);
  half_t* abuf = (half_t*)alloc((size_t)N * 64 * 2);
  float* ge = (float*)alloc((size_t)G * 64 * 4);

  // --- CSR build, atomic-free at global scope ---
  bucket_hist<<<NBLK, 256, 0, stream>>>(dstp, bcnt, E, nbuck);
  int nbA = (int)((M + SCAN_CHUNK - 1) / SCAN_CHUNK);
  scan1<<<nbA, 256, 0, stream>>>(bcnt, bcnt, bsum, (int)M);  // in-place exclusive scan
  scan2<<<1, 256, 0, stream>>>(bsum, nbA);
  scan3<<<(int)((M + 1 + 255) / 256), 256, 0, stream>>>(bcnt, bsum, (int)(M + 1));
  bucket_scatter<<<NBLK, 256, 0, stream>>>(src, dstp, bcnt, sed, E, nbuck);
  node_csr<<<nbuck, 256, 0, stream>>>(sed, bcnt, rsp, isq, csr, E, nbuck, N, PARK);
  seg_offsets<<<(N + 255) / 256, 256, 0, stream>>>(batch, goff, N, G);

  long nocts = (long)N * 8;
  int gblocks = (N + 31) / 32;  // 4 waves/block, 8 dst/wave, 32 nodes/block
  // xs1 = x * isq (fp16); also zeroes sentinel rows of xs1/xs2
  scale_cast<<<(int)((nocts + 255) / 256), 256, 0, stream>>>(x, isq, xs1, xs2, nocts, N);
  // conv1: gather xs1, MFMA @W1 epilogue, out xs2 = relu1*isq (fp16)
  gather_fused<<<gblocks, 256, 0, stream>>>(xs1, csr, rsp, isq, W1, b1, xs2, N, PARK, 1);
  // conv2: gather xs2, MFMA @W2 epilogue, out abuf = relu2 (fp16)
  gather_fused<<<gblocks, 256, 0, stream>>>(xs2, csr, rsp, isq, W2, b2, abuf, N, PARK, 0);
  // pool
  pool_mean<<<2048, 256, 0, stream>>>(abuf, goff, ge, G);
  // pair MLP (MFMA)
  pair_mlp<<<(P + PPB - 1) / PPB, 256, 0, stream>>>(ge, dp, Wr1, br1, Wr2, br2, out, P);
}